// Round 10
// baseline (425.359 us; speedup 1.0000x reference)
//
#include <hip/hip_runtime.h>
#include <stdint.h>

#define B_  8
#define S_  1024
#define D_  768
#define H_  12
#define HD_ 64
#define FF_ 3072
#define M_  (B_*S_)   // 8192 tokens
#define R_  16
#define QLD 2304      // packed QKV row stride
#define KBLK 128

typedef unsigned short u16;
typedef short s16x8 __attribute__((ext_vector_type(8)));   // 8 bf16 (4 VGPRs)
typedef float fx4  __attribute__((ext_vector_type(4)));    // 4 fp32 acc

__device__ __forceinline__ float b2f(u16 u) {
  union { unsigned int i; float f; } c; c.i = ((unsigned int)u) << 16; return c.f;
}
__device__ __forceinline__ u16 f2b(float f) {   // RNE f32->bf16
  union { float f; unsigned int i; } c; c.f = f;
  unsigned int x = c.i;
  x += 0x7FFFu + ((x >> 16) & 1u);
  return (u16)(x >> 16);
}
__device__ __forceinline__ float gelu_f(float x) {  // jax.nn.gelu approximate=True (tanh)
  float u = 0.7978845608028654f * (x + 0.044715f * x * x * x);
  float e = __expf(2.f * u);
  float t = 1.f - 2.f / (e + 1.f);
  return 0.5f * x * (1.f + t);
}
__device__ __forceinline__ void gload16(const u16* gsrc, u16* ldst) {
  __builtin_amdgcn_global_load_lds(
      (__attribute__((address_space(1))) void*)(gsrc),
      (__attribute__((address_space(3))) void*)(ldst), 16, 0, 0);
}

// ---------------- weights f32->bf16 + all small preps, ONE kernel ----------------
__global__ __launch_bounds__(256)
void cvt_prep(const float* __restrict__ q_w, const float* __restrict__ k_w,
              const float* __restrict__ v_w, const float* __restrict__ o_w,
              const float* __restrict__ fc1_w, const float* __restrict__ fc2_w,
              u16* __restrict__ wqkv, u16* __restrict__ wo,
              u16* __restrict__ wfc1, u16* __restrict__ wfc2,
              const float* __restrict__ q_bv, const float* __restrict__ k_bv,
              const float* __restrict__ v_bv, float* __restrict__ qkvb,
              const float* __restrict__ lora1B, const float* __restrict__ vera1B,
              const float* __restrict__ e1b, u16* __restrict__ up1L, u16* __restrict__ up1V,
              const float* __restrict__ lora2B, const float* __restrict__ vera2B,
              const float* __restrict__ e2b, u16* __restrict__ up2L, u16* __restrict__ up2V,
              const float* __restrict__ lora2A, const float* __restrict__ vera2A,
              u16* __restrict__ a2tL, u16* __restrict__ a2tV)
{
  const int i = blockIdx.x * 256 + threadIdx.x;   // quad index
  const int q1  = D_ * D_ / 4;
  const int fd4 = FF_ * D_ / 4;
  {
    const float* s; u16* d; int j;
    if      (i <     q1)       { s = q_w;   d = wqkv;            j = i; }
    else if (i < 2 * q1)       { s = k_w;   d = wqkv + D_*D_;    j = i - q1; }
    else if (i < 3 * q1)       { s = v_w;   d = wqkv + 2*D_*D_;  j = i - 2*q1; }
    else if (i < 4 * q1)       { s = o_w;   d = wo;              j = i - 3*q1; }
    else if (i < 4 * q1 + fd4) { s = fc1_w; d = wfc1;            j = i - 4*q1; }
    else                       { s = fc2_w; d = wfc2;            j = i - 4*q1 - fd4; }
    const float4 f = ((const float4*)s)[j];
    ushort4 o4; o4.x = f2b(f.x); o4.y = f2b(f.y); o4.z = f2b(f.z); o4.w = f2b(f.w);
    ((ushort4*)d)[j] = o4;
  }
  if (i < FF_) {
    const int f = i;
    if (f < QLD)
      qkvb[f] = (f < D_) ? q_bv[f] : (f < 2 * D_) ? k_bv[f - D_] : v_bv[f - 2 * D_];
    {
      const float ev = e1b[f];
      #pragma unroll
      for (int r = 0; r < 16; ++r) {
        up1L[(size_t)f * 32 + r] = f2b(lora1B[(size_t)r * FF_ + f]);
        up1V[(size_t)f * 32 + r] = f2b(vera1B[(size_t)r * FF_ + f] * ev);
        up1L[(size_t)f * 32 + 16 + r] = 0;
        up1V[(size_t)f * 32 + 16 + r] = 0;
      }
    }
    {
      const float4* apl = (const float4*)(lora2A + (size_t)f * 16);
      const float4* apv = (const float4*)(vera2A + (size_t)f * 16);
      #pragma unroll
      for (int q4 = 0; q4 < 4; ++q4) {
        const float4 l4 = apl[q4], v4 = apv[q4];
        a2tL[(size_t)(q4*4+0) * FF_ + f] = f2b(l4.x);
        a2tL[(size_t)(q4*4+1) * FF_ + f] = f2b(l4.y);
        a2tL[(size_t)(q4*4+2) * FF_ + f] = f2b(l4.z);
        a2tL[(size_t)(q4*4+3) * FF_ + f] = f2b(l4.w);
        a2tV[(size_t)(q4*4+0) * FF_ + f] = f2b(v4.x);
        a2tV[(size_t)(q4*4+1) * FF_ + f] = f2b(v4.y);
        a2tV[(size_t)(q4*4+2) * FF_ + f] = f2b(v4.z);
        a2tV[(size_t)(q4*4+3) * FF_ + f] = f2b(v4.w);
      }
    }
    if (f < D_) {
      const float ev = e2b[f];
      #pragma unroll
      for (int r = 0; r < 16; ++r) {
        up2L[(size_t)f * 32 + r] = f2b(lora2B[(size_t)r * D_ + f]);
        up2V[(size_t)f * 32 + r] = f2b(vera2B[(size_t)r * D_ + f] * ev);
        up2L[(size_t)f * 32 + 16 + r] = 0;
        up2V[(size_t)f * 32 + 16 + r] = 0;
      }
    }
  }
}

// ---------------- LayerNorm (+residual add, + fused rank-16 down-projection) ----------------
template<bool ADD>
__global__ __launch_bounds__(256)
void ln_k(const float* __restrict__ x, const u16* __restrict__ add,
          const float* __restrict__ g, const float* __restrict__ beta,
          u16* __restrict__ outb, float* __restrict__ xsum,
          const float* __restrict__ Alora, const float* __restrict__ Avera,
          const float* __restrict__ dvec, u16* __restrict__ tmp1b,
          const int* __restrict__ nbp)
{
  const int row = blockIdx.x;
  const size_t base = (size_t)row * D_;
  float v0[3]; float s = 0.f, sq = 0.f;
  #pragma unroll
  for (int i = 0; i < 3; ++i) {
    const int d = threadIdx.x + i * 256;
    float val = x[base + d];
    if (ADD) { val += b2f(add[base + d]); xsum[base + d] = val; }
    v0[i] = val; s += val; sq += val * val;
  }
  #pragma unroll
  for (int mm = 32; mm >= 1; mm >>= 1) { s += __shfl_xor(s, mm); sq += __shfl_xor(sq, mm); }
  __shared__ float ss[4], s2[4];
  if ((threadIdx.x & 63) == 0) { ss[threadIdx.x >> 6] = s; s2[threadIdx.x >> 6] = sq; }
  __syncthreads();
  s  = ss[0] + ss[1] + ss[2] + ss[3];
  sq = s2[0] + s2[1] + s2[2] + s2[3];
  const float mean = s * (1.f / D_);
  const float var  = sq * (1.f / D_) - mean * mean;
  const float rs   = rsqrtf(var + 1e-6f);
  float nv[3];
  #pragma unroll
  for (int i = 0; i < 3; ++i) {
    const int d = threadIdx.x + i * 256;
    nv[i] = (v0[i] - mean) * rs * g[d] + beta[d];
    outb[base + d] = f2b(nv[i]);
  }

  if (ADD) {
    const int nb = *nbp;
    const bool ex = (row % S_) >= nb;
    const float* Am = ex ? Avera : Alora;
    float p[16];
    #pragma unroll
    for (int r = 0; r < 16; ++r) p[r] = 0.f;
    #pragma unroll
    for (int i = 0; i < 3; ++i) {
      const int d = threadIdx.x + i * 256;
      const float4* ap = (const float4*)(Am + (size_t)d * R_);
      const float4 a0 = ap[0], a1 = ap[1], a2 = ap[2], a3 = ap[3];
      const float vv = nv[i];
      p[0]  += vv * a0.x; p[1]  += vv * a0.y; p[2]  += vv * a0.z; p[3]  += vv * a0.w;
      p[4]  += vv * a1.x; p[5]  += vv * a1.y; p[6]  += vv * a1.z; p[7]  += vv * a1.w;
      p[8]  += vv * a2.x; p[9]  += vv * a2.y; p[10] += vv * a2.z; p[11] += vv * a2.w;
      p[12] += vv * a3.x; p[13] += vv * a3.y; p[14] += vv * a3.z; p[15] += vv * a3.w;
    }
    #pragma unroll
    for (int st = 1; st < 16; st <<= 1)
      #pragma unroll
      for (int r = 0; r < 16; ++r) p[r] += __shfl_xor(p[r], st);
    __shared__ float sred[16][16];
    const int grp = threadIdx.x >> 4;
    if ((threadIdx.x & 15) == 0) {
      #pragma unroll
      for (int r = 0; r < 16; ++r) sred[grp][r] = p[r];
    }
    __syncthreads();
    if (threadIdx.x < 16) {
      float v = 0.f;
      #pragma unroll
      for (int gg = 0; gg < 16; ++gg) v += sred[gg][threadIdx.x];
      if (ex) v *= dvec[threadIdx.x];
      tmp1b[(size_t)row * 32 + threadIdx.x] = f2b(v);
      tmp1b[(size_t)row * 32 + 16 + threadIdx.x] = 0;
    }
  }
}

// ---------------- bf16 MFMA GEMM, 2-phase double-buffered pipeline ----------------
template<int MODE>
__global__ __launch_bounds__(256)
void gemm_bt(const u16* __restrict__ A, const u16* __restrict__ W,
             const float* __restrict__ bias, u16* __restrict__ Cb,
             float* __restrict__ Cf, const float* __restrict__ resid,
             const u16* __restrict__ Aad, const u16* __restrict__ BadL,
             const u16* __restrict__ BadV, const int* __restrict__ nbp,
             int M, int N, int K)
{
  __shared__ u16 As[2][128 * 32];
  __shared__ u16 Bs[2][128 * 32];
  const int tid   = threadIdx.x;
  const int lane  = tid & 63;
  const int wid   = tid >> 6;
  const int wr    = wid >> 1;
  const int wc    = wid & 1;
  const int lr    = lane & 15;
  const int lk    = (lane >> 4) << 3;
  const int gn    = N >> 7;
  const int nwg   = (M >> 7) * gn;
  const int chunk = nwg >> 3;
  const int lin   = blockIdx.x;
  const int swz   = (lin & 7) * chunk + (lin >> 3);
  const int m0    = (swz / gn) * 128;
  const int n0    = (swz % gn) * 128;
  const int kg    = (tid & 3) * 8;
  const int row_a = tid >> 2;

  const int nst = K >> 5;
  const int tot = (MODE >= 1) ? nst + 1 : nst;
  const u16* Bad = nullptr;
  if (MODE >= 1) Bad = ((m0 % S_) >= *nbp) ? BadV : BadL;

  const u16* arow = A + (size_t)(m0 + row_a) * K + kg;
  const u16* wrow = W + (size_t)(n0 + row_a) * K + kg;
  const size_t half_a = (size_t)64 * K;

  fx4 acc[4][4];
  const fx4 zero = {0.f, 0.f, 0.f, 0.f};
  #pragma unroll
  for (int i = 0; i < 4; ++i)
    #pragma unroll
    for (int j = 0; j < 4; ++j) acc[i][j] = zero;

  gload16(arow,          &As[0][tid * 8]);
  gload16(arow + half_a, &As[0][(256 + tid) * 8]);
  gload16(wrow,          &Bs[0][tid * 8]);
  gload16(wrow + half_a, &Bs[0][(256 + tid) * 8]);
  __syncthreads();

  for (int t = 0; t < tot; ++t) {
    const int cur = t & 1;
    if (t + 1 < tot) {
      const int nxt = cur ^ 1;
      if (MODE >= 1 && t + 1 == nst) {
        gload16(Aad + (size_t)(m0 + row_a) * 32 + kg,      &As[nxt][tid * 8]);
        gload16(Aad + (size_t)(m0 + 64 + row_a) * 32 + kg, &As[nxt][(256 + tid) * 8]);
        gload16(Bad + (size_t)(n0 + row_a) * 32 + kg,      &Bs[nxt][tid * 8]);
        gload16(Bad + (size_t)(n0 + 64 + row_a) * 32 + kg, &Bs[nxt][(256 + tid) * 8]);
      } else {
        const size_t ko = (size_t)(t + 1) * 32;
        gload16(arow + ko,          &As[nxt][tid * 8]);
        gload16(arow + ko + half_a, &As[nxt][(256 + tid) * 8]);
        gload16(wrow + ko,          &Bs[nxt][tid * 8]);
        gload16(wrow + ko + half_a, &Bs[nxt][(256 + tid) * 8]);
      }
    }
    s16x8 av[4], bv[4];
    #pragma unroll
    for (int i = 0; i < 4; ++i)
      av[i] = *(const s16x8*)&As[cur][(wr * 64 + i * 16 + lr) * 32 + lk];
    #pragma unroll
    for (int j = 0; j < 4; ++j)
      bv[j] = *(const s16x8*)&Bs[cur][(wc * 64 + j * 16 + lr) * 32 + lk];
    __builtin_amdgcn_s_setprio(1);
    #pragma unroll
    for (int i = 0; i < 4; ++i)
      #pragma unroll
      for (int j = 0; j < 4; ++j)
        acc[i][j] = __builtin_amdgcn_mfma_f32_16x16x32_bf16(av[i], bv[j], acc[i][j], 0, 0, 0);
    __builtin_amdgcn_s_setprio(0);
    __syncthreads();
  }

  const int rb = (lane >> 4) * 4;
  #pragma unroll
  for (int j = 0; j < 4; ++j) {
    const int col = n0 + wc * 64 + j * 16 + lr;
    const float bj = bias ? bias[col] : 0.f;
    #pragma unroll
    for (int i = 0; i < 4; ++i) {
      const int row = m0 + wr * 64 + i * 16 + rb;
      #pragma unroll
      for (int r = 0; r < 4; ++r) {
        const float val = acc[i][j][r] + bj;
        const size_t idx = (size_t)(row + r) * N + col;
        if (MODE == 1)      Cb[idx] = f2b(gelu_f(val));
        else if (MODE == 2) Cf[idx] = resid[idx] + val;
        else                Cb[idx] = f2b(val);
      }
    }
  }
}

// ---------------- skinny down-projection (2-phase dbuf): part[ks][M][16] ----------------
__global__ __launch_bounds__(256)
void downproj(const u16* __restrict__ hid, const u16* __restrict__ A2tL,
              const u16* __restrict__ A2tV, float* __restrict__ part,
              const int* __restrict__ nbp)
{
  __shared__ u16 As[2][128 * 32];
  __shared__ u16 Bs[2][16 * 32];
  const int tid  = threadIdx.x;
  const int lane = tid & 63;
  const int w    = tid >> 6;
  const int lr   = lane & 15;
  const int lk   = (lane >> 4) << 3;
  const int m0   = blockIdx.x * 128;
  const int kb   = blockIdx.y * (FF_ / 8);
  const int nb   = *nbp;
  const u16* A2t = ((m0 % S_) >= nb) ? A2tV : A2tL;
  const int kg    = (tid & 3) * 8;
  const int row_a = tid >> 2;

  const u16* hrow = hid + (size_t)(m0 + row_a) * FF_ + kb + kg;
  const size_t half_h = (size_t)64 * FF_;
  const u16* brow = A2t + (size_t)(tid >> 2) * FF_ + kb + kg;

  const fx4 zero = {0.f, 0.f, 0.f, 0.f};
  fx4 acc[2]; acc[0] = zero; acc[1] = zero;

  const int nst = (FF_ / 8) >> 5;   // 12
  gload16(hrow,          &As[0][tid * 8]);
  gload16(hrow + half_h, &As[0][(256 + tid) * 8]);
  if (tid < 64) gload16(brow, &Bs[0][tid * 8]);
  __syncthreads();

  for (int t = 0; t < nst; ++t) {
    const int cur = t & 1;
    if (t + 1 < nst) {
      const int nxt = cur ^ 1;
      const size_t ko = (size_t)(t + 1) * 32;
      gload16(hrow + ko,          &As[nxt][tid * 8]);
      gload16(hrow + ko + half_h, &As[nxt][(256 + tid) * 8]);
      if (tid < 64) gload16(brow + ko, &Bs[nxt][tid * 8]);
    }
    s16x8 bv = *(const s16x8*)&Bs[cur][lr * 32 + lk];
    #pragma unroll
    for (int i = 0; i < 2; ++i) {
      s16x8 av = *(const s16x8*)&As[cur][(w * 32 + i * 16 + lr) * 32 + lk];
      acc[i] = __builtin_amdgcn_mfma_f32_16x16x32_bf16(av, bv, acc[i], 0, 0, 0);
    }
    __syncthreads();
  }

  const int rb = (lane >> 4) * 4;
  #pragma unroll
  for (int i = 0; i < 2; ++i)
    #pragma unroll
    for (int r = 0; r < 4; ++r)
      part[(size_t)blockIdx.y * M_ * 16 +
           (size_t)(m0 + w * 32 + i * 16 + rb + r) * 16 + lr] = acc[i][r];
}

// ---------------- reduce partials -> tmp2b bf16 [M,32] ----------------
__global__ __launch_bounds__(256)
void reduce_dp(const float* __restrict__ part, const float* __restrict__ d2,
               u16* __restrict__ tmp2b, const int* __restrict__ nbp)
{
  const int idx = blockIdx.x * 256 + threadIdx.x;   // m*16 + r
  const int m = idx >> 4, r = idx & 15;
  const int nb = *nbp;
  float s = 0.f;
  #pragma unroll
  for (int ks = 0; ks < 8; ++ks) s += part[(size_t)ks * M_ * 16 + idx];
  if ((m % S_) >= nb) s *= d2[r];
  tmp2b[(size_t)m * 32 + r] = f2b(s);
  tmp2b[(size_t)m * 32 + 16 + r] = 0;
}

// ---------------- MFMA flash attention: K/Q direct-from-global (L2-resident), V-only LDS ----------------
// Swapped QK^T (q lane-local). Q frag + K frags are contiguous 16B in row-major
// qkv -> per-lane b128 global loads (no LDS staging; K/V L2-fits per XCD, lesson m169).
// LDS = Vt dbuf 32K + Pl 16K = 48KB -> 3 blocks/CU (12 waves). T13 defer-max.
__global__ __launch_bounds__(256)
void attn_mfma(const u16* __restrict__ qkv, const float* __restrict__ mask,
               u16* __restrict__ o)
{
  __shared__ u16 Vt[2][64 * KBLK];  // row d, col k, swz k^(((d&7)^((d>>3)&7))<<3)
  __shared__ uint32_t Pl[4][1024];  // per-wave P rows [16][64 u32]

  const int tid  = threadIdx.x;
  const int lane = tid & 63;
  const int wq   = tid >> 6;
  const int lr   = lane & 15;
  const int hi   = lane >> 4;
  // XCD swizzle (bijective: 1536 = 8*192); one (b,h)'s q-blocks share an XCD
  const int lin = blockIdx.x;
  const int vsw = (lin & 7) * 192 + (lin >> 3);
  const int qb  = vsw & 15;
  const int bh  = vsw >> 4;
  const int b    = bh / H_;
  const int h    = bh % H_;
  const size_t tok0 = (size_t)b * S_ + (size_t)qb * 64;
  const size_t colh = (size_t)h * HD_;

  const int va  = tid >> 3;          // V staging: k-rows 4*va..+3
  const int vc8 = (tid & 7) * 8;     // V staging: d cols vc8..+7

  // ---- Q fragment: direct per-lane global load (contiguous 16B) ----
  s16x8 qa[2];
  {
    const u16* qrow = qkv + (tok0 + wq * 16 + lr) * QLD + colh;
    qa[0] = *(const s16x8*)(qrow + hi * 8);
    qa[1] = *(const s16x8*)(qrow + 32 + hi * 8);
  }

  // ---- prologue: V0 -> regs -> Vt[0] ----
  {
    const size_t ktok = (size_t)b * S_;
    const u16* vp = qkv + (ktok + 4 * va) * QLD + 2 * D_ + colh + vc8;
    s16x8 w0 = *(const s16x8*)vp;
    s16x8 w1 = *(const s16x8*)(vp + QLD);
    s16x8 w2 = *(const s16x8*)(vp + 2 * QLD);
    s16x8 w3 = *(const s16x8*)(vp + 3 * QLD);
    #pragma unroll
    for (int jj = 0; jj < 8; ++jj) {
      const int d  = vc8 + jj;
      const int sw = ((d & 7) ^ ((d >> 3) & 7)) << 3;
      const int cp = (4 * va) ^ sw;
      *(uint32_t*)&Vt[0][d * KBLK + cp] =
          (uint32_t)(u16)w0[jj] | ((uint32_t)(u16)w1[jj] << 16);
      *(uint32_t*)&Vt[0][d * KBLK + cp + 2] =
          (uint32_t)(u16)w2[jj] | ((uint32_t)(u16)w3[jj] << 16);
    }
  }
  __syncthreads();   // V0 visible

  const fx4 zero = {0.f, 0.f, 0.f, 0.f};
  fx4 oacc[4];
  #pragma unroll
  for (int dj = 0; dj < 4; ++dj) oacc[dj] = zero;
  float mreg = -3.0e38f, lreg = 0.f;   // per-lane: q-row = wq*16 + lr

  const int NT = S_ / KBLK;   // 8
  for (int kt = 0; kt < NT; ++kt) {
    const int cur = kt & 1;
    const int nxt = cur ^ 1;

    // ---- issue next-tile V reg loads early (latency hides under QK/softmax) ----
    s16x8 w0, w1, w2, w3;
    if (kt + 1 < NT) {
      const u16* vp = qkv + ((size_t)b * S_ + (size_t)(kt + 1) * KBLK + 4 * va) * QLD
                    + 2 * D_ + colh + vc8;
      w0 = *(const s16x8*)vp;
      w1 = *(const s16x8*)(vp + QLD);
      w2 = *(const s16x8*)(vp + 2 * QLD);
      w3 = *(const s16x8*)(vp + 3 * QLD);
    }

    // ---- QK^T SWAPPED, K frags direct from global ----
    const size_t ktok = (size_t)b * S_ + (size_t)kt * KBLK;
    float val[8][4];
    #pragma unroll
    for (int jh = 0; jh < 2; ++jh) {
      s16x8 kb2[4][2];
      #pragma unroll
      for (int j = 0; j < 4; ++j) {
        const u16* krow = qkv + (ktok + (jh * 4 + j) * 16 + lr) * QLD + D_ + colh;
        kb2[j][0] = *(const s16x8*)(krow + hi * 8);
        kb2[j][1] = *(const s16x8*)(krow + 32 + hi * 8);
      }
      fx4 m4[4];
      {
        const float* mp = mask + (size_t)(qb * 64 + wq * 16 + lr) * S_
                        + (size_t)kt * KBLK + jh * 64 + 4 * hi;
        #pragma unroll
        for (int j = 0; j < 4; ++j)
          m4[j] = *(const fx4*)(mp + j * 16);
      }
      fx4 sf[4];
      #pragma unroll
      for (int j = 0; j < 4; ++j) sf[j] = zero;
      __builtin_amdgcn_s_setprio(1);
      #pragma unroll
      for (int ks = 0; ks < 2; ++ks)
        #pragma unroll
        for (int j = 0; j < 4; ++j)
          sf[j] = __builtin_amdgcn_mfma_f32_16x16x32_bf16(kb2[j][ks], qa[ks], sf[j], 0, 0, 0);
      __builtin_amdgcn_s_setprio(0);
      #pragma unroll
      for (int j = 0; j < 4; ++j)
        #pragma unroll
        for (int r = 0; r < 4; ++r)
          val[jh * 4 + j][r] = sf[j][r] * 0.125f + m4[j][r];
    }

    // ---- online softmax (lane-local rows) + T13 defer-max ----
    {
      float mk[8];
      #pragma unroll
      for (int kg = 0; kg < 8; ++kg)
        mk[kg] = fmaxf(fmaxf(val[kg][0], val[kg][1]), fmaxf(val[kg][2], val[kg][3]));
      float mx = fmaxf(fmaxf(fmaxf(mk[0], mk[1]), fmaxf(mk[2], mk[3])),
                       fmaxf(fmaxf(mk[4], mk[5]), fmaxf(mk[6], mk[7])));
      mx = fmaxf(mx, __shfl_xor(mx, 16));
      mx = fmaxf(mx, __shfl_xor(mx, 32));
      const bool noresc = (bool)__all(mx <= mreg + 8.f);
      float fac = 1.f;
      if (!noresc) {
        const float mn = fmaxf(mreg, mx);
        fac = __expf(mreg - mn);
        mreg = mn;
      }
      float sk[8];
      #pragma unroll
      for (int kg = 0; kg < 8; ++kg) {
        #pragma unroll
        for (int r = 0; r < 4; ++r) val[kg][r] = __expf(val[kg][r] - mreg);
        sk[kg] = (val[kg][0] + val[kg][1]) + (val[kg][2] + val[kg][3]);
      }
      float rs = ((sk[0] + sk[1]) + (sk[2] + sk[3])) + ((sk[4] + sk[5]) + (sk[6] + sk[7]));
      rs += __shfl_xor(rs, 16);
      rs += __shfl_xor(rs, 32);
      lreg = lreg * fac + rs;
      if (!noresc) {
        float facr[4];
        #pragma unroll
        for (int r = 0; r < 4; ++r) facr[r] = __shfl(fac, hi * 4 + r);
        #pragma unroll
        for (int dj = 0; dj < 4; ++dj)
          #pragma unroll
          for (int r = 0; r < 4; ++r) oacc[dj][r] *= facr[r];
      }
    }

    // ---- P pack (v_perm trunc) -> wave-private swizzled LDS, 8x b64 ----
    {
      uint32_t* prow = &Pl[wq][lr * 64];
      #pragma unroll
      for (int kg = 0; kg < 8; ++kg) {
        const uint32_t p0 = __builtin_amdgcn_perm(
            __float_as_uint(val[kg][1]), __float_as_uint(val[kg][0]), 0x07060302u);
        const uint32_t p1 = __builtin_amdgcn_perm(
            __float_as_uint(val[kg][3]), __float_as_uint(val[kg][2]), 0x07060302u);
        const int i0 = (8 * kg + 2 * hi) ^ ((lr & 7) << 3);
        uint2 pk; pk.x = p0; pk.y = p1;
        *(uint2*)&prow[i0] = pk;
      }
    }

    // ---- write next-tile V (regs -> LDS, opposite buffer) ----
    if (kt + 1 < NT) {
      #pragma unroll
      for (int jj = 0; jj < 8; ++jj) {
        const int d  = vc8 + jj;
        const int sw = ((d & 7) ^ ((d >> 3) & 7)) << 3;
        const int cp = (4 * va) ^ sw;
        *(uint32_t*)&Vt[nxt][d * KBLK + cp] =
            (uint32_t)(u16)w0[jj] | ((uint32_t)(u16)w1[jj] << 16);
        *(uint32_t*)&Vt[nxt][d * KBLK + cp + 2] =
            (uint32_t)(u16)w2[jj] | ((uint32_t)(u16)w3[jj] << 16);
      }
    }

    // ---- PV from Vt[cur]: 4 K-slices of 32 ----
    #pragma unroll
    for (int ks = 0; ks < 4; ++ks) {
      const int pbase = (16 * ks + 4 * hi) ^ ((lr & 7) << 3);
      s16x8 pa = *(const s16x8*)&Pl[wq][lr * 64 + pbase];
      s16x8 bv2[4];
      #pragma unroll
      for (int dj = 0; dj < 4; ++dj) {
        const int n  = dj * 16 + lr;
        const int sw = ((n & 7) ^ ((n >> 3) & 7)) << 3;
        bv2[dj] = *(const s16x8*)&Vt[cur][n * KBLK + ((ks * 32 + hi * 8) ^ sw)];
      }
      __builtin_amdgcn_s_setprio(1);
      #pragma unroll
      for (int dj = 0; dj < 4; ++dj)
        oacc[dj] = __builtin_amdgcn_mfma_f32_16x16x32_bf16(pa, bv2[dj], oacc[dj], 0, 0, 0);
      __builtin_amdgcn_s_setprio(0);
    }

    __syncthreads();   // Vt[nxt] writes visible; Vt[cur] reads done before next overwrite
  }

  // ---- epilogue: O /= l (per-row inv redistributed), write ----
  {
    const float linv = 1.f / lreg;
    float invr[4];
    #pragma unroll
    for (int r = 0; r < 4; ++r) invr[r] = __shfl(linv, hi * 4 + r);
    #pragma unroll
    for (int r = 0; r < 4; ++r) {
      const size_t grow = (tok0 + wq * 16 + hi * 4 + r) * D_ + colh;
      #pragma unroll
      for (int dj = 0; dj < 4; ++dj)
        o[grow + dj * 16 + lr] = f2b(oacc[dj][r] * invr[r]);
    }
  }
}

extern "C" void kernel_launch(void* const* d_in, const int* in_sizes, int n_in,
                              void* d_out, int out_size, void* d_ws, size_t ws_size,
                              hipStream_t stream)
{
  const float* x      = (const float*)d_in[0];
  const float* mask   = (const float*)d_in[1];
  const float* n1g    = (const float*)d_in[2];
  const float* n1b    = (const float*)d_in[3];
  const float* q_w    = (const float*)d_in[4];
  const float* q_bv   = (const float*)d_in[5];
  const float* k_w    = (const float*)d_in[6];
  const float* k_bv   = (const float*)d_in[7];
  const float* v_w    = (const float*)d_in[8];
  const float* v_bv   = (const float*)d_in[9];
  const float* o_w    = (const float*)d_in[10];
  const float* o_bv   = (const float*)d_in[11];
  const float* n2g    = (const float*)d_in[12];
  const float* n2b    = (const float*)d_in[13];
  const float* fc1_w  = (const float*)d_in[14];
  const float* fc1_bv = (const float*)d_in[15];
  const float* fc2_w  = (const float*)d_in[16];
  const float* fc2_bv = (const float*)d_in[17];
  const float* lora1A = (const float*)d_in[18];
  const float* lora1B = (const float*)d_in[19];
  const float* lora2A = (const float*)d_in[20];
  const float* lora2B = (const float*)d_in[21];
  const float* vera1A = (const float*)d_in[22];
  const float* vera1B = (const float*)d_in[23];
  const float* vera2A = (const float*)d_in[24];
  const float* vera2B = (const float*)d_in[25];
  const float* e1d    = (const float*)d_in[26];
  const float* e1b    = (const float*)d_in[27];
  const float* e2d    = (const float*)d_in[28];
  const float* e2b    = (const float*)d_in[29];
  const int*   nbp    = (const int*)d_in[30];

  char* wsb = (char*)d_ws;
  u16* h1    = (u16*)wsb; wsb += (size_t)M_ * D_ * 2;       // 12.6 MB
  u16* qkv   = (u16*)wsb; wsb += (size_t)M_ * QLD * 2;      // 37.7 MB
  u16* attno = (u16*)wsb; wsb += (size_t)M_ * D_ * 2;
  u16* oproj = (u16*)wsb; wsb += (size_t)M_ * D_ * 2;
  u16* n2    = (u16*)wsb; wsb += (size_t)M_ * D_ * 2;
  u16* wqkv  = (u16*)wsb; wsb += (size_t)QLD * D_ * 2;
  u16* wo    = (u16*)wsb; wsb += (size_t)D_ * D_ * 2;
  u16* wfc1  = (u16*)wsb; wsb += (size_t)FF_ * D_ * 2;
  u16* wfc2  = (u16*)wsb; wsb += (size_t)D_ * FF_ * 2;
  u16* tmp1b = (u16*)wsb; wsb += (size_t)M_ * 32 * 2;
  u16* tmp2b = (u16*)wsb; wsb += (size_t)M_ * 32 * 2;
  u16* up1L  = (u16*)wsb; wsb += (size_t)FF_ * 32 * 2;
  u16* up1V  = (u16*)wsb; wsb += (size_t)FF_ * 32 * 2;
  u16* up2L  = (u16*)wsb; wsb += (size_t)D_ * 32 * 2;
  u16* up2V  = (u16*)wsb; wsb += (size_t)D_ * 32 * 2;
  u16* a2tL  = (u16*)wsb; wsb += (size_t)16 * FF_ * 2;
  u16* a2tV  = (u16*)wsb; wsb += (size_t)16 * FF_ * 2;
  float* qkvb = (float*)wsb; wsb += (size_t)QLD * 4;
  float* part = (float*)wsb; wsb += (size_t)8 * M_ * 16 * 4; // 4 MB
  u16* hidb = h1;   // [M,FF] bf16 aliases h1+qkv (both dead by fc1)

  const int totq = (4 * D_ * D_ + 2 * FF_ * D_) / 4;
  cvt_prep<<<totq / 256, 256, 0, stream>>>(q_w, k_w, v_w, o_w, fc1_w, fc2_w,
                                           wqkv, wo, wfc1, wfc2,
                                           q_bv, k_bv, v_bv, qkvb,
                                           lora1B, vera1B, e1b, up1L, up1V,
                                           lora2B, vera2B, e2b, up2L, up2V,
                                           lora2A, vera2A, a2tL, a2tV);

  ln_k<false><<<M_, 256, 0, stream>>>(x, nullptr, n1g, n1b, h1, nullptr,
                                      nullptr, nullptr, nullptr, nullptr, nullptr);
  gemm_bt<0><<<(M_/128) * (QLD/128), 256, 0, stream>>>(
      h1, wqkv, qkvb, qkv, nullptr, nullptr, nullptr, nullptr, nullptr, nullptr,
      M_, QLD, D_);
  attn_mfma<<<(S_/64) * (B_*H_), 256, 0, stream>>>(qkv, mask, attno);
  gemm_bt<0><<<(M_/128) * (D_/128), 256, 0, stream>>>(
      attno, wo, o_bv, oproj, nullptr, nullptr, nullptr, nullptr, nullptr, nullptr,
      M_, D_, D_);

  ln_k<true><<<M_, 256, 0, stream>>>(x, oproj, n2g, n2b, n2, (float*)d_out,
                                     lora1A, vera1A, e1d, tmp1b, nbp);

  gemm_bt<1><<<(M_/128) * (FF_/128), 256, 0, stream>>>(
      n2, wfc1, fc1_bv, hidb, nullptr, nullptr, tmp1b, up1L, up1V, nbp,
      M_, FF_, D_);

  downproj<<<dim3(M_/128, 8), 256, 0, stream>>>(hidb, a2tL, a2tV, part, nbp);
  reduce_dp<<<M_*16/256, 256, 0, stream>>>(part, e2d, tmp2b, nbp);

  gemm_bt<2><<<(M_/128) * (D_/128), 256, 0, stream>>>(
      hidb, wfc2, fc2_bv, nullptr, (float*)d_out, (const float*)d_out,
      tmp2b, up2L, up2V, nbp, M_, D_, FF_);
}

// Round 11
// 364.797 us; speedup vs baseline: 1.1660x; 1.1660x over previous
//
#include <hip/hip_runtime.h>
#include <stdint.h>

#define B_  8
#define S_  1024
#define D_  768
#define H_  12
#define HD_ 64
#define FF_ 3072
#define M_  (B_*S_)   // 8192 tokens
#define R_  16
#define QLD 2304      // packed QKV row stride
#define KBLK 128

typedef unsigned short u16;
typedef short s16x8 __attribute__((ext_vector_type(8)));   // 8 bf16 (4 VGPRs)
typedef float fx4  __attribute__((ext_vector_type(4)));    // 4 fp32 acc

__device__ __forceinline__ float b2f(u16 u) {
  union { unsigned int i; float f; } c; c.i = ((unsigned int)u) << 16; return c.f;
}
__device__ __forceinline__ u16 f2b(float f) {   // RNE f32->bf16
  union { float f; unsigned int i; } c; c.f = f;
  unsigned int x = c.i;
  x += 0x7FFFu + ((x >> 16) & 1u);
  return (u16)(x >> 16);
}
__device__ __forceinline__ float gelu_f(float x) {  // jax.nn.gelu approximate=True (tanh)
  float u = 0.7978845608028654f * (x + 0.044715f * x * x * x);
  float e = __expf(2.f * u);
  float t = 1.f - 2.f / (e + 1.f);
  return 0.5f * x * (1.f + t);
}
__device__ __forceinline__ void gload16(const u16* gsrc, u16* ldst) {
  __builtin_amdgcn_global_load_lds(
      (__attribute__((address_space(1))) void*)(gsrc),
      (__attribute__((address_space(3))) void*)(ldst), 16, 0, 0);
}

// ---------------- weights f32->bf16 + all small preps, ONE kernel ----------------
__global__ __launch_bounds__(256)
void cvt_prep(const float* __restrict__ q_w, const float* __restrict__ k_w,
              const float* __restrict__ v_w, const float* __restrict__ o_w,
              const float* __restrict__ fc1_w, const float* __restrict__ fc2_w,
              u16* __restrict__ wqkv, u16* __restrict__ wo,
              u16* __restrict__ wfc1, u16* __restrict__ wfc2,
              const float* __restrict__ q_bv, const float* __restrict__ k_bv,
              const float* __restrict__ v_bv, float* __restrict__ qkvb,
              const float* __restrict__ lora1B, const float* __restrict__ vera1B,
              const float* __restrict__ e1b, u16* __restrict__ up1L, u16* __restrict__ up1V,
              const float* __restrict__ lora2B, const float* __restrict__ vera2B,
              const float* __restrict__ e2b, u16* __restrict__ up2L, u16* __restrict__ up2V,
              const float* __restrict__ lora2A, const float* __restrict__ vera2A,
              u16* __restrict__ a2tL, u16* __restrict__ a2tV)
{
  const int i = blockIdx.x * 256 + threadIdx.x;   // quad index
  const int q1  = D_ * D_ / 4;
  const int fd4 = FF_ * D_ / 4;
  {
    const float* s; u16* d; int j;
    if      (i <     q1)       { s = q_w;   d = wqkv;            j = i; }
    else if (i < 2 * q1)       { s = k_w;   d = wqkv + D_*D_;    j = i - q1; }
    else if (i < 3 * q1)       { s = v_w;   d = wqkv + 2*D_*D_;  j = i - 2*q1; }
    else if (i < 4 * q1)       { s = o_w;   d = wo;              j = i - 3*q1; }
    else if (i < 4 * q1 + fd4) { s = fc1_w; d = wfc1;            j = i - 4*q1; }
    else                       { s = fc2_w; d = wfc2;            j = i - 4*q1 - fd4; }
    const float4 f = ((const float4*)s)[j];
    ushort4 o4; o4.x = f2b(f.x); o4.y = f2b(f.y); o4.z = f2b(f.z); o4.w = f2b(f.w);
    ((ushort4*)d)[j] = o4;
  }
  if (i < FF_) {
    const int f = i;
    if (f < QLD)
      qkvb[f] = (f < D_) ? q_bv[f] : (f < 2 * D_) ? k_bv[f - D_] : v_bv[f - 2 * D_];
    {
      const float ev = e1b[f];
      #pragma unroll
      for (int r = 0; r < 16; ++r) {
        up1L[(size_t)f * 32 + r] = f2b(lora1B[(size_t)r * FF_ + f]);
        up1V[(size_t)f * 32 + r] = f2b(vera1B[(size_t)r * FF_ + f] * ev);
        up1L[(size_t)f * 32 + 16 + r] = 0;
        up1V[(size_t)f * 32 + 16 + r] = 0;
      }
    }
    {
      const float4* apl = (const float4*)(lora2A + (size_t)f * 16);
      const float4* apv = (const float4*)(vera2A + (size_t)f * 16);
      #pragma unroll
      for (int q4 = 0; q4 < 4; ++q4) {
        const float4 l4 = apl[q4], v4 = apv[q4];
        a2tL[(size_t)(q4*4+0) * FF_ + f] = f2b(l4.x);
        a2tL[(size_t)(q4*4+1) * FF_ + f] = f2b(l4.y);
        a2tL[(size_t)(q4*4+2) * FF_ + f] = f2b(l4.z);
        a2tL[(size_t)(q4*4+3) * FF_ + f] = f2b(l4.w);
        a2tV[(size_t)(q4*4+0) * FF_ + f] = f2b(v4.x);
        a2tV[(size_t)(q4*4+1) * FF_ + f] = f2b(v4.y);
        a2tV[(size_t)(q4*4+2) * FF_ + f] = f2b(v4.z);
        a2tV[(size_t)(q4*4+3) * FF_ + f] = f2b(v4.w);
      }
    }
    if (f < D_) {
      const float ev = e2b[f];
      #pragma unroll
      for (int r = 0; r < 16; ++r) {
        up2L[(size_t)f * 32 + r] = f2b(lora2B[(size_t)r * D_ + f]);
        up2V[(size_t)f * 32 + r] = f2b(vera2B[(size_t)r * D_ + f] * ev);
        up2L[(size_t)f * 32 + 16 + r] = 0;
        up2V[(size_t)f * 32 + 16 + r] = 0;
      }
    }
  }
}

// ---------------- LayerNorm (+residual add, + fused rank-16 down-projection) ----------------
template<bool ADD>
__global__ __launch_bounds__(256)
void ln_k(const float* __restrict__ x, const u16* __restrict__ add,
          const float* __restrict__ g, const float* __restrict__ beta,
          u16* __restrict__ outb, float* __restrict__ xsum,
          const float* __restrict__ Alora, const float* __restrict__ Avera,
          const float* __restrict__ dvec, u16* __restrict__ tmp1b,
          const int* __restrict__ nbp)
{
  const int row = blockIdx.x;
  const size_t base = (size_t)row * D_;
  float v0[3]; float s = 0.f, sq = 0.f;
  #pragma unroll
  for (int i = 0; i < 3; ++i) {
    const int d = threadIdx.x + i * 256;
    float val = x[base + d];
    if (ADD) { val += b2f(add[base + d]); xsum[base + d] = val; }
    v0[i] = val; s += val; sq += val * val;
  }
  #pragma unroll
  for (int mm = 32; mm >= 1; mm >>= 1) { s += __shfl_xor(s, mm); sq += __shfl_xor(sq, mm); }
  __shared__ float ss[4], s2[4];
  if ((threadIdx.x & 63) == 0) { ss[threadIdx.x >> 6] = s; s2[threadIdx.x >> 6] = sq; }
  __syncthreads();
  s  = ss[0] + ss[1] + ss[2] + ss[3];
  sq = s2[0] + s2[1] + s2[2] + s2[3];
  const float mean = s * (1.f / D_);
  const float var  = sq * (1.f / D_) - mean * mean;
  const float rs   = rsqrtf(var + 1e-6f);
  float nv[3];
  #pragma unroll
  for (int i = 0; i < 3; ++i) {
    const int d = threadIdx.x + i * 256;
    nv[i] = (v0[i] - mean) * rs * g[d] + beta[d];
    outb[base + d] = f2b(nv[i]);
  }

  if (ADD) {
    const int nb = *nbp;
    const bool ex = (row % S_) >= nb;
    const float* Am = ex ? Avera : Alora;
    float p[16];
    #pragma unroll
    for (int r = 0; r < 16; ++r) p[r] = 0.f;
    #pragma unroll
    for (int i = 0; i < 3; ++i) {
      const int d = threadIdx.x + i * 256;
      const float4* ap = (const float4*)(Am + (size_t)d * R_);
      const float4 a0 = ap[0], a1 = ap[1], a2 = ap[2], a3 = ap[3];
      const float vv = nv[i];
      p[0]  += vv * a0.x; p[1]  += vv * a0.y; p[2]  += vv * a0.z; p[3]  += vv * a0.w;
      p[4]  += vv * a1.x; p[5]  += vv * a1.y; p[6]  += vv * a1.z; p[7]  += vv * a1.w;
      p[8]  += vv * a2.x; p[9]  += vv * a2.y; p[10] += vv * a2.z; p[11] += vv * a2.w;
      p[12] += vv * a3.x; p[13] += vv * a3.y; p[14] += vv * a3.z; p[15] += vv * a3.w;
    }
    #pragma unroll
    for (int st = 1; st < 16; st <<= 1)
      #pragma unroll
      for (int r = 0; r < 16; ++r) p[r] += __shfl_xor(p[r], st);
    __shared__ float sred[16][16];
    const int grp = threadIdx.x >> 4;
    if ((threadIdx.x & 15) == 0) {
      #pragma unroll
      for (int r = 0; r < 16; ++r) sred[grp][r] = p[r];
    }
    __syncthreads();
    if (threadIdx.x < 16) {
      float v = 0.f;
      #pragma unroll
      for (int gg = 0; gg < 16; ++gg) v += sred[gg][threadIdx.x];
      if (ex) v *= dvec[threadIdx.x];
      tmp1b[(size_t)row * 32 + threadIdx.x] = f2b(v);
      tmp1b[(size_t)row * 32 + 16 + threadIdx.x] = 0;
    }
  }
}

// ---------------- bf16 MFMA GEMM, 2-phase double-buffered pipeline ----------------
template<int MODE>
__global__ __launch_bounds__(256)
void gemm_bt(const u16* __restrict__ A, const u16* __restrict__ W,
             const float* __restrict__ bias, u16* __restrict__ Cb,
             float* __restrict__ Cf, const float* __restrict__ resid,
             const u16* __restrict__ Aad, const u16* __restrict__ BadL,
             const u16* __restrict__ BadV, const int* __restrict__ nbp,
             int M, int N, int K)
{
  __shared__ u16 As[2][128 * 32];
  __shared__ u16 Bs[2][128 * 32];
  const int tid   = threadIdx.x;
  const int lane  = tid & 63;
  const int wid   = tid >> 6;
  const int wr    = wid >> 1;
  const int wc    = wid & 1;
  const int lr    = lane & 15;
  const int lk    = (lane >> 4) << 3;
  const int gn    = N >> 7;
  const int nwg   = (M >> 7) * gn;
  const int chunk = nwg >> 3;
  const int lin   = blockIdx.x;
  const int swz   = (lin & 7) * chunk + (lin >> 3);
  const int m0    = (swz / gn) * 128;
  const int n0    = (swz % gn) * 128;
  const int kg    = (tid & 3) * 8;
  const int row_a = tid >> 2;

  const int nst = K >> 5;
  const int tot = (MODE >= 1) ? nst + 1 : nst;
  const u16* Bad = nullptr;
  if (MODE >= 1) Bad = ((m0 % S_) >= *nbp) ? BadV : BadL;

  const u16* arow = A + (size_t)(m0 + row_a) * K + kg;
  const u16* wrow = W + (size_t)(n0 + row_a) * K + kg;
  const size_t half_a = (size_t)64 * K;

  fx4 acc[4][4];
  const fx4 zero = {0.f, 0.f, 0.f, 0.f};
  #pragma unroll
  for (int i = 0; i < 4; ++i)
    #pragma unroll
    for (int j = 0; j < 4; ++j) acc[i][j] = zero;

  gload16(arow,          &As[0][tid * 8]);
  gload16(arow + half_a, &As[0][(256 + tid) * 8]);
  gload16(wrow,          &Bs[0][tid * 8]);
  gload16(wrow + half_a, &Bs[0][(256 + tid) * 8]);
  __syncthreads();

  for (int t = 0; t < tot; ++t) {
    const int cur = t & 1;
    if (t + 1 < tot) {
      const int nxt = cur ^ 1;
      if (MODE >= 1 && t + 1 == nst) {
        gload16(Aad + (size_t)(m0 + row_a) * 32 + kg,      &As[nxt][tid * 8]);
        gload16(Aad + (size_t)(m0 + 64 + row_a) * 32 + kg, &As[nxt][(256 + tid) * 8]);
        gload16(Bad + (size_t)(n0 + row_a) * 32 + kg,      &Bs[nxt][tid * 8]);
        gload16(Bad + (size_t)(n0 + 64 + row_a) * 32 + kg, &Bs[nxt][(256 + tid) * 8]);
      } else {
        const size_t ko = (size_t)(t + 1) * 32;
        gload16(arow + ko,          &As[nxt][tid * 8]);
        gload16(arow + ko + half_a, &As[nxt][(256 + tid) * 8]);
        gload16(wrow + ko,          &Bs[nxt][tid * 8]);
        gload16(wrow + ko + half_a, &Bs[nxt][(256 + tid) * 8]);
      }
    }
    s16x8 av[4], bv[4];
    #pragma unroll
    for (int i = 0; i < 4; ++i)
      av[i] = *(const s16x8*)&As[cur][(wr * 64 + i * 16 + lr) * 32 + lk];
    #pragma unroll
    for (int j = 0; j < 4; ++j)
      bv[j] = *(const s16x8*)&Bs[cur][(wc * 64 + j * 16 + lr) * 32 + lk];
    __builtin_amdgcn_s_setprio(1);
    #pragma unroll
    for (int i = 0; i < 4; ++i)
      #pragma unroll
      for (int j = 0; j < 4; ++j)
        acc[i][j] = __builtin_amdgcn_mfma_f32_16x16x32_bf16(av[i], bv[j], acc[i][j], 0, 0, 0);
    __builtin_amdgcn_s_setprio(0);
    __syncthreads();
  }

  const int rb = (lane >> 4) * 4;
  #pragma unroll
  for (int j = 0; j < 4; ++j) {
    const int col = n0 + wc * 64 + j * 16 + lr;
    const float bj = bias ? bias[col] : 0.f;
    #pragma unroll
    for (int i = 0; i < 4; ++i) {
      const int row = m0 + wr * 64 + i * 16 + rb;
      #pragma unroll
      for (int r = 0; r < 4; ++r) {
        const float val = acc[i][j][r] + bj;
        const size_t idx = (size_t)(row + r) * N + col;
        if (MODE == 1)      Cb[idx] = f2b(gelu_f(val));
        else if (MODE == 2) Cf[idx] = resid[idx] + val;
        else                Cb[idx] = f2b(val);
      }
    }
  }
}

// ---------------- skinny down-projection (2-phase dbuf): part[ks][M][16] ----------------
__global__ __launch_bounds__(256)
void downproj(const u16* __restrict__ hid, const u16* __restrict__ A2tL,
              const u16* __restrict__ A2tV, float* __restrict__ part,
              const int* __restrict__ nbp)
{
  __shared__ u16 As[2][128 * 32];
  __shared__ u16 Bs[2][16 * 32];
  const int tid  = threadIdx.x;
  const int lane = tid & 63;
  const int w    = tid >> 6;
  const int lr   = lane & 15;
  const int lk   = (lane >> 4) << 3;
  const int m0   = blockIdx.x * 128;
  const int kb   = blockIdx.y * (FF_ / 8);
  const int nb   = *nbp;
  const u16* A2t = ((m0 % S_) >= nb) ? A2tV : A2tL;
  const int kg    = (tid & 3) * 8;
  const int row_a = tid >> 2;

  const u16* hrow = hid + (size_t)(m0 + row_a) * FF_ + kb + kg;
  const size_t half_h = (size_t)64 * FF_;
  const u16* brow = A2t + (size_t)(tid >> 2) * FF_ + kb + kg;

  const fx4 zero = {0.f, 0.f, 0.f, 0.f};
  fx4 acc[2]; acc[0] = zero; acc[1] = zero;

  const int nst = (FF_ / 8) >> 5;   // 12
  gload16(hrow,          &As[0][tid * 8]);
  gload16(hrow + half_h, &As[0][(256 + tid) * 8]);
  if (tid < 64) gload16(brow, &Bs[0][tid * 8]);
  __syncthreads();

  for (int t = 0; t < nst; ++t) {
    const int cur = t & 1;
    if (t + 1 < nst) {
      const int nxt = cur ^ 1;
      const size_t ko = (size_t)(t + 1) * 32;
      gload16(hrow + ko,          &As[nxt][tid * 8]);
      gload16(hrow + ko + half_h, &As[nxt][(256 + tid) * 8]);
      if (tid < 64) gload16(brow + ko, &Bs[nxt][tid * 8]);
    }
    s16x8 bv = *(const s16x8*)&Bs[cur][lr * 32 + lk];
    #pragma unroll
    for (int i = 0; i < 2; ++i) {
      s16x8 av = *(const s16x8*)&As[cur][(w * 32 + i * 16 + lr) * 32 + lk];
      acc[i] = __builtin_amdgcn_mfma_f32_16x16x32_bf16(av, bv, acc[i], 0, 0, 0);
    }
    __syncthreads();
  }

  const int rb = (lane >> 4) * 4;
  #pragma unroll
  for (int i = 0; i < 2; ++i)
    #pragma unroll
    for (int r = 0; r < 4; ++r)
      part[(size_t)blockIdx.y * M_ * 16 +
           (size_t)(m0 + w * 32 + i * 16 + rb + r) * 16 + lr] = acc[i][r];
}

// ---------------- reduce partials -> tmp2b bf16 [M,32] ----------------
__global__ __launch_bounds__(256)
void reduce_dp(const float* __restrict__ part, const float* __restrict__ d2,
               u16* __restrict__ tmp2b, const int* __restrict__ nbp)
{
  const int idx = blockIdx.x * 256 + threadIdx.x;   // m*16 + r
  const int m = idx >> 4, r = idx & 15;
  const int nb = *nbp;
  float s = 0.f;
  #pragma unroll
  for (int ks = 0; ks < 8; ++ks) s += part[(size_t)ks * M_ * 16 + idx];
  if ((m % S_) >= nb) s *= d2[r];
  tmp2b[(size_t)m * 32 + r] = f2b(s);
  tmp2b[(size_t)m * 32 + 16 + r] = 0;
}

// ---------------- MFMA flash attention (R8 structure + T13 defer-max) ----------------
// Swapped QK^T (q lane-local), K dbuf via global_load_lds, V reg->LDS dbuf,
// v_perm P pack -> wave-private swizzled LDS. One barrier per tile.
__global__ __launch_bounds__(256)
void attn_mfma(const u16* __restrict__ qkv, const float* __restrict__ mask,
               u16* __restrict__ o)
{
  __shared__ u16 Kl[2][128 * 64];   // row k, col d, swz col^((k&7)<<3)
  __shared__ u16 Vt[2][64 * 128];   // row d, col k, swz k^(((d&7)^((d>>3)&7))<<3)
  __shared__ uint32_t Pl[4][1024];  // per-wave P rows [16][64 u32]; prologue: Q overlay

  const int tid  = threadIdx.x;
  const int lane = tid & 63;
  const int wq   = tid >> 6;
  const int lr   = lane & 15;
  const int hi   = lane >> 4;
  const int lin = blockIdx.x;
  const int vsw = (lin & 7) * 192 + (lin >> 3);
  const int qb  = vsw & 15;
  const int bh  = vsw >> 4;
  const int b    = bh / H_;
  const int h    = bh % H_;
  const size_t tok0 = (size_t)b * S_ + (size_t)qb * 64;
  const size_t colh = (size_t)h * HD_;

  const int va  = tid >> 3;
  const int vc8 = (tid & 7) * 8;
  u16* qstage = (u16*)&Pl[0][0];

  #pragma unroll
  for (int u = 0; u < 2; ++u) {
    const int li = u * 256 + tid;
    const int r  = li >> 3;
    const int cb = ((li & 7) ^ (r & 7)) * 8;
    gload16(qkv + (tok0 + r) * QLD + colh + cb, &qstage[li * 8]);
  }
  {
    const size_t ktok = (size_t)b * S_;
    #pragma unroll
    for (int u = 0; u < 4; ++u) {
      const int li = u * 256 + tid;
      const int r  = li >> 3;
      const int cb = ((li & 7) ^ (r & 7)) * 8;
      gload16(qkv + (ktok + r) * QLD + D_ + colh + cb, &Kl[0][li * 8]);
    }
    const u16* vp = qkv + (ktok + 4 * va) * QLD + 2 * D_ + colh + vc8;
    s16x8 w0 = *(const s16x8*)vp;
    s16x8 w1 = *(const s16x8*)(vp + QLD);
    s16x8 w2 = *(const s16x8*)(vp + 2 * QLD);
    s16x8 w3 = *(const s16x8*)(vp + 3 * QLD);
    #pragma unroll
    for (int jj = 0; jj < 8; ++jj) {
      const int d  = vc8 + jj;
      const int sw = ((d & 7) ^ ((d >> 3) & 7)) << 3;
      const int cp = (4 * va) ^ sw;
      *(uint32_t*)&Vt[0][d * 128 + cp] =
          (uint32_t)(u16)w0[jj] | ((uint32_t)(u16)w1[jj] << 16);
      *(uint32_t*)&Vt[0][d * 128 + cp + 2] =
          (uint32_t)(u16)w2[jj] | ((uint32_t)(u16)w3[jj] << 16);
    }
  }
  __syncthreads();

  s16x8 qa[2];
  {
    const int qrow = wq * 16 + lr;
    #pragma unroll
    for (int ks = 0; ks < 2; ++ks)
      qa[ks] = *(const s16x8*)&qstage[qrow * 64 + ((ks * 32 + hi * 8) ^ ((qrow & 7) << 3))];
  }
  __syncthreads();   // all qa reads done before any P overwrite of Pl

  const fx4 zero = {0.f, 0.f, 0.f, 0.f};
  fx4 oacc[4];
  #pragma unroll
  for (int dj = 0; dj < 4; ++dj) oacc[dj] = zero;
  float mreg = -3.0e38f, lreg = 0.f;

  const int NT = S_ / KBLK;   // 8
  for (int kt = 0; kt < NT; ++kt) {
    const int cur = kt & 1;
    const int nxt = cur ^ 1;

    s16x8 w0, w1, w2, w3;
    if (kt + 1 < NT) {
      const size_t ktokn = (size_t)b * S_ + (size_t)(kt + 1) * KBLK;
      #pragma unroll
      for (int u = 0; u < 4; ++u) {
        const int li = u * 256 + tid;
        const int r  = li >> 3;
        const int cb = ((li & 7) ^ (r & 7)) * 8;
        gload16(qkv + (ktokn + r) * QLD + D_ + colh + cb, &Kl[nxt][li * 8]);
      }
      const u16* vp = qkv + (ktokn + 4 * va) * QLD + 2 * D_ + colh + vc8;
      w0 = *(const s16x8*)vp;
      w1 = *(const s16x8*)(vp + QLD);
      w2 = *(const s16x8*)(vp + 2 * QLD);
      w3 = *(const s16x8*)(vp + 3 * QLD);
    }

    float val[8][4];
    #pragma unroll
    for (int jh = 0; jh < 2; ++jh) {
      s16x8 kb2[4][2];
      #pragma unroll
      for (int j = 0; j < 4; ++j) {
        const int n = (jh * 4 + j) * 16 + lr;
        #pragma unroll
        for (int ks = 0; ks < 2; ++ks)
          kb2[j][ks] = *(const s16x8*)&Kl[cur][n * 64 + ((ks * 32 + hi * 8) ^ ((n & 7) << 3))];
      }
      fx4 m4[4];
      {
        const float* mp = mask + (size_t)(qb * 64 + wq * 16 + lr) * S_
                        + (size_t)kt * KBLK + jh * 64 + 4 * hi;
        #pragma unroll
        for (int j = 0; j < 4; ++j)
          m4[j] = *(const fx4*)(mp + j * 16);
      }
      fx4 sf[4];
      #pragma unroll
      for (int j = 0; j < 4; ++j) sf[j] = zero;
      __builtin_amdgcn_s_setprio(1);
      #pragma unroll
      for (int ks = 0; ks < 2; ++ks)
        #pragma unroll
        for (int j = 0; j < 4; ++j)
          sf[j] = __builtin_amdgcn_mfma_f32_16x16x32_bf16(kb2[j][ks], qa[ks], sf[j], 0, 0, 0);
      __builtin_amdgcn_s_setprio(0);
      #pragma unroll
      for (int j = 0; j < 4; ++j)
        #pragma unroll
        for (int r = 0; r < 4; ++r)
          val[jh * 4 + j][r] = sf[j][r] * 0.125f + m4[j][r];
    }

    // ---- online softmax (lane-local rows) + T13 defer-max ----
    {
      float mk[8];
      #pragma unroll
      for (int kg = 0; kg < 8; ++kg)
        mk[kg] = fmaxf(fmaxf(val[kg][0], val[kg][1]), fmaxf(val[kg][2], val[kg][3]));
      float mx = fmaxf(fmaxf(fmaxf(mk[0], mk[1]), fmaxf(mk[2], mk[3])),
                       fmaxf(fmaxf(mk[4], mk[5]), fmaxf(mk[6], mk[7])));
      mx = fmaxf(mx, __shfl_xor(mx, 16));
      mx = fmaxf(mx, __shfl_xor(mx, 32));
      const bool noresc = (bool)__all(mx <= mreg + 8.f);
      float fac = 1.f;
      if (!noresc) {
        const float mn = fmaxf(mreg, mx);
        fac = __expf(mreg - mn);
        mreg = mn;
      }
      float sk[8];
      #pragma unroll
      for (int kg = 0; kg < 8; ++kg) {
        #pragma unroll
        for (int r = 0; r < 4; ++r) val[kg][r] = __expf(val[kg][r] - mreg);
        sk[kg] = (val[kg][0] + val[kg][1]) + (val[kg][2] + val[kg][3]);
      }
      float rs = ((sk[0] + sk[1]) + (sk[2] + sk[3])) + ((sk[4] + sk[5]) + (sk[6] + sk[7]));
      rs += __shfl_xor(rs, 16);
      rs += __shfl_xor(rs, 32);
      lreg = lreg * fac + rs;
      if (!noresc) {
        float facr[4];
        #pragma unroll
        for (int r = 0; r < 4; ++r) facr[r] = __shfl(fac, hi * 4 + r);
        #pragma unroll
        for (int dj = 0; dj < 4; ++dj)
          #pragma unroll
          for (int r = 0; r < 4; ++r) oacc[dj][r] *= facr[r];
      }
    }

    // ---- P pack (v_perm trunc) -> wave-private swizzled LDS, 8x b64 ----
    {
      uint32_t* prow = &Pl[wq][lr * 64];
      #pragma unroll
      for (int kg = 0; kg < 8; ++kg) {
        const uint32_t p0 = __builtin_amdgcn_perm(
            __float_as_uint(val[kg][1]), __float_as_uint(val[kg][0]), 0x07060302u);
        const uint32_t p1 = __builtin_amdgcn_perm(
            __float_as_uint(val[kg][3]), __float_as_uint(val[kg][2]), 0x07060302u);
        const int i0 = (8 * kg + 2 * hi) ^ ((lr & 7) << 3);
        uint2 pk; pk.x = p0; pk.y = p1;
        *(uint2*)&prow[i0] = pk;
      }
    }

    // ---- write next-tile V (regs -> LDS, opposite buffer) ----
    if (kt + 1 < NT) {
      #pragma unroll
      for (int jj = 0; jj < 8; ++jj) {
        const int d  = vc8 + jj;
        const int sw = ((d & 7) ^ ((d >> 3) & 7)) << 3;
        const int cp = (4 * va) ^ sw;
        *(uint32_t*)&Vt[nxt][d * 128 + cp] =
            (uint32_t)(u16)w0[jj] | ((uint32_t)(u16)w1[jj] << 16);
        *(uint32_t*)&Vt[nxt][d * 128 + cp + 2] =
            (uint32_t)(u16)w2[jj] | ((uint32_t)(u16)w3[jj] << 16);
      }
    }

    // ---- PV from Vt[cur]: 4 K-slices of 32 ----
    #pragma unroll
    for (int ks = 0; ks < 4; ++ks) {
      const int pbase = (16 * ks + 4 * hi) ^ ((lr & 7) << 3);
      s16x8 pa = *(const s16x8*)&Pl[wq][lr * 64 + pbase];
      s16x8 bv2[4];
      #pragma unroll
      for (int dj = 0; dj < 4; ++dj) {
        const int n  = dj * 16 + lr;
        const int sw = ((n & 7) ^ ((n >> 3) & 7)) << 3;
        bv2[dj] = *(const s16x8*)&Vt[cur][n * 128 + ((ks * 32 + hi * 8) ^ sw)];
      }
      __builtin_amdgcn_s_setprio(1);
      #pragma unroll
      for (int dj = 0; dj < 4; ++dj)
        oacc[dj] = __builtin_amdgcn_mfma_f32_16x16x32_bf16(pa, bv2[dj], oacc[dj], 0, 0, 0);
      __builtin_amdgcn_s_setprio(0);
    }

    __syncthreads();
  }

  {
    const float linv = 1.f / lreg;
    float invr[4];
    #pragma unroll
    for (int r = 0; r < 4; ++r) invr[r] = __shfl(linv, hi * 4 + r);
    #pragma unroll
    for (int r = 0; r < 4; ++r) {
      const size_t grow = (tok0 + wq * 16 + hi * 4 + r) * D_ + colh;
      #pragma unroll
      for (int dj = 0; dj < 4; ++dj)
        o[grow + dj * 16 + lr] = f2b(oacc[dj][r] * invr[r]);
    }
  }
}

extern "C" void kernel_launch(void* const* d_in, const int* in_sizes, int n_in,
                              void* d_out, int out_size, void* d_ws, size_t ws_size,
                              hipStream_t stream)
{
  const float* x      = (const float*)d_in[0];
  const float* mask   = (const float*)d_in[1];
  const float* n1g    = (const float*)d_in[2];
  const float* n1b    = (const float*)d_in[3];
  const float* q_w    = (const float*)d_in[4];
  const float* q_bv   = (const float*)d_in[5];
  const float* k_w    = (const float*)d_in[6];
  const float* k_bv   = (const float*)d_in[7];
  const float* v_w    = (const float*)d_in[8];
  const float* v_bv   = (const float*)d_in[9];
  const float* o_w    = (const float*)d_in[10];
  const float* o_bv   = (const float*)d_in[11];
  const float* n2g    = (const float*)d_in[12];
  const float* n2b    = (const float*)d_in[13];
  const float* fc1_w  = (const float*)d_in[14];
  const float* fc1_bv = (const float*)d_in[15];
  const float* fc2_w  = (const float*)d_in[16];
  const float* fc2_bv = (const float*)d_in[17];
  const float* lora1A = (const float*)d_in[18];
  const float* lora1B = (const float*)d_in[19];
  const float* lora2A = (const float*)d_in[20];
  const float* lora2B = (const float*)d_in[21];
  const float* vera1A = (const float*)d_in[22];
  const float* vera1B = (const float*)d_in[23];
  const float* vera2A = (const float*)d_in[24];
  const float* vera2B = (const float*)d_in[25];
  const float* e1d    = (const float*)d_in[26];
  const float* e1b    = (const float*)d_in[27];
  const float* e2d    = (const float*)d_in[28];
  const float* e2b    = (const float*)d_in[29];
  const int*   nbp    = (const int*)d_in[30];

  char* wsb = (char*)d_ws;
  u16* h1    = (u16*)wsb; wsb += (size_t)M_ * D_ * 2;       // 12.6 MB
  u16* qkv   = (u16*)wsb; wsb += (size_t)M_ * QLD * 2;      // 37.7 MB
  u16* attno = (u16*)wsb; wsb += (size_t)M_ * D_ * 2;
  u16* oproj = (u16*)wsb; wsb += (size_t)M_ * D_ * 2;
  u16* n2    = (u16*)wsb; wsb += (size_t)M_ * D_ * 2;
  u16* wqkv  = (u16*)wsb; wsb += (size_t)QLD * D_ * 2;
  u16* wo    = (u16*)wsb; wsb += (size_t)D_ * D_ * 2;
  u16* wfc1  = (u16*)wsb; wsb += (size_t)FF_ * D_ * 2;
  u16* wfc2  = (u16*)wsb; wsb += (size_t)D_ * FF_ * 2;
  u16* tmp1b = (u16*)wsb; wsb += (size_t)M_ * 32 * 2;
  u16* tmp2b = (u16*)wsb; wsb += (size_t)M_ * 32 * 2;
  u16* up1L  = (u16*)wsb; wsb += (size_t)FF_ * 32 * 2;
  u16* up1V  = (u16*)wsb; wsb += (size_t)FF_ * 32 * 2;
  u16* up2L  = (u16*)wsb; wsb += (size_t)D_ * 32 * 2;
  u16* up2V  = (u16*)wsb; wsb += (size_t)D_ * 32 * 2;
  u16* a2tL  = (u16*)wsb; wsb += (size_t)16 * FF_ * 2;
  u16* a2tV  = (u16*)wsb; wsb += (size_t)16 * FF_ * 2;
  float* qkvb = (float*)wsb; wsb += (size_t)QLD * 4;
  float* part = (float*)wsb; wsb += (size_t)8 * M_ * 16 * 4; // 4 MB
  u16* hidb = h1;   // [M,FF] bf16 aliases h1+qkv (both dead by fc1)

  const int totq = (4 * D_ * D_ + 2 * FF_ * D_) / 4;
  cvt_prep<<<totq / 256, 256, 0, stream>>>(q_w, k_w, v_w, o_w, fc1_w, fc2_w,
                                           wqkv, wo, wfc1, wfc2,
                                           q_bv, k_bv, v_bv, qkvb,
                                           lora1B, vera1B, e1b, up1L, up1V,
                                           lora2B, vera2B, e2b, up2L, up2V,
                                           lora2A, vera2A, a2tL, a2tV);

  ln_k<false><<<M_, 256, 0, stream>>>(x, nullptr, n1g, n1b, h1, nullptr,
                                      nullptr, nullptr, nullptr, nullptr, nullptr);
  gemm_bt<0><<<(M_/128) * (QLD/128), 256, 0, stream>>>(
      h1, wqkv, qkvb, qkv, nullptr, nullptr, nullptr, nullptr, nullptr, nullptr,
      M_, QLD, D_);
  attn_mfma<<<(S_/64) * (B_*H_), 256, 0, stream>>>(qkv, mask, attno);
  gemm_bt<0><<<(M_/128) * (D_/128), 256, 0, stream>>>(
      attno, wo, o_bv, oproj, nullptr, nullptr, nullptr, nullptr, nullptr, nullptr,
      M_, D_, D_);

  ln_k<true><<<M_, 256, 0, stream>>>(x, oproj, n2g, n2b, n2, (float*)d_out,
                                     lora1A, vera1A, e1d, tmp1b, nbp);

  gemm_bt<1><<<(M_/128) * (FF_/128), 256, 0, stream>>>(
      n2, wfc1, fc1_bv, hidb, nullptr, nullptr, tmp1b, up1L, up1V, nbp,
      M_, FF_, D_);

  downproj<<<dim3(M_/128, 8), 256, 0, stream>>>(hidb, a2tL, a2tV, part, nbp);
  reduce_dp<<<M_*16/256, 256, 0, stream>>>(part, e2d, tmp2b, nbp);

  gemm_bt<2><<<(M_/128) * (D_/128), 256, 0, stream>>>(
      hidb, wfc2, fc2_bv, nullptr, (float*)d_out, (const float*)d_out,
      tmp2b, up2L, up2V, nbp, M_, D_, FF_);
}

// Round 12
// 347.748 us; speedup vs baseline: 1.2232x; 1.0490x over previous
//
#include <hip/hip_runtime.h>
#include <stdint.h>

#define B_  8
#define S_  1024
#define D_  768
#define H_  12
#define HD_ 64
#define FF_ 3072
#define M_  (B_*S_)   // 8192 tokens
#define R_  16
#define QLD 2304      // packed QKV row stride
#define KBLK 128

typedef unsigned short u16;
typedef short s16x8 __attribute__((ext_vector_type(8)));   // 8 bf16 (4 VGPRs)
typedef float fx4  __attribute__((ext_vector_type(4)));    // 4 fp32 acc

__device__ __forceinline__ float b2f(u16 u) {
  union { unsigned int i; float f; } c; c.i = ((unsigned int)u) << 16; return c.f;
}
__device__ __forceinline__ u16 f2b(float f) {   // RNE f32->bf16
  union { float f; unsigned int i; } c; c.f = f;
  unsigned int x = c.i;
  x += 0x7FFFu + ((x >> 16) & 1u);
  return (u16)(x >> 16);
}
__device__ __forceinline__ float gelu_f(float x) {  // jax.nn.gelu approximate=True (tanh)
  float u = 0.7978845608028654f * (x + 0.044715f * x * x * x);
  float e = __expf(2.f * u);
  float t = 1.f - 2.f / (e + 1.f);
  return 0.5f * x * (1.f + t);
}
__device__ __forceinline__ void gload16(const u16* gsrc, u16* ldst) {
  __builtin_amdgcn_global_load_lds(
      (__attribute__((address_space(1))) void*)(gsrc),
      (__attribute__((address_space(3))) void*)(ldst), 16, 0, 0);
}

// ---------------- weights f32->bf16 + all small preps, ONE kernel ----------------
__global__ __launch_bounds__(256)
void cvt_prep(const float* __restrict__ q_w, const float* __restrict__ k_w,
              const float* __restrict__ v_w, const float* __restrict__ o_w,
              const float* __restrict__ fc1_w, const float* __restrict__ fc2_w,
              u16* __restrict__ wqkv, u16* __restrict__ wo,
              u16* __restrict__ wfc1, u16* __restrict__ wfc2,
              const float* __restrict__ q_bv, const float* __restrict__ k_bv,
              const float* __restrict__ v_bv, float* __restrict__ qkvb,
              const float* __restrict__ lora1B, const float* __restrict__ vera1B,
              const float* __restrict__ e1b, u16* __restrict__ up1L, u16* __restrict__ up1V,
              const float* __restrict__ lora2B, const float* __restrict__ vera2B,
              const float* __restrict__ e2b, u16* __restrict__ up2L, u16* __restrict__ up2V,
              const float* __restrict__ lora2A, const float* __restrict__ vera2A,
              u16* __restrict__ a2tL, u16* __restrict__ a2tV)
{
  const int i = blockIdx.x * 256 + threadIdx.x;   // quad index
  const int q1  = D_ * D_ / 4;
  const int fd4 = FF_ * D_ / 4;
  {
    const float* s; u16* d; int j;
    if      (i <     q1)       { s = q_w;   d = wqkv;            j = i; }
    else if (i < 2 * q1)       { s = k_w;   d = wqkv + D_*D_;    j = i - q1; }
    else if (i < 3 * q1)       { s = v_w;   d = wqkv + 2*D_*D_;  j = i - 2*q1; }
    else if (i < 4 * q1)       { s = o_w;   d = wo;              j = i - 3*q1; }
    else if (i < 4 * q1 + fd4) { s = fc1_w; d = wfc1;            j = i - 4*q1; }
    else                       { s = fc2_w; d = wfc2;            j = i - 4*q1 - fd4; }
    const float4 f = ((const float4*)s)[j];
    ushort4 o4; o4.x = f2b(f.x); o4.y = f2b(f.y); o4.z = f2b(f.z); o4.w = f2b(f.w);
    ((ushort4*)d)[j] = o4;
  }
  if (i < FF_) {
    const int f = i;
    if (f < QLD)
      qkvb[f] = (f < D_) ? q_bv[f] : (f < 2 * D_) ? k_bv[f - D_] : v_bv[f - 2 * D_];
    {
      const float ev = e1b[f];
      #pragma unroll
      for (int r = 0; r < 16; ++r) {
        up1L[(size_t)f * 32 + r] = f2b(lora1B[(size_t)r * FF_ + f]);
        up1V[(size_t)f * 32 + r] = f2b(vera1B[(size_t)r * FF_ + f] * ev);
        up1L[(size_t)f * 32 + 16 + r] = 0;
        up1V[(size_t)f * 32 + 16 + r] = 0;
      }
    }
    {
      const float4* apl = (const float4*)(lora2A + (size_t)f * 16);
      const float4* apv = (const float4*)(vera2A + (size_t)f * 16);
      #pragma unroll
      for (int q4 = 0; q4 < 4; ++q4) {
        const float4 l4 = apl[q4], v4 = apv[q4];
        a2tL[(size_t)(q4*4+0) * FF_ + f] = f2b(l4.x);
        a2tL[(size_t)(q4*4+1) * FF_ + f] = f2b(l4.y);
        a2tL[(size_t)(q4*4+2) * FF_ + f] = f2b(l4.z);
        a2tL[(size_t)(q4*4+3) * FF_ + f] = f2b(l4.w);
        a2tV[(size_t)(q4*4+0) * FF_ + f] = f2b(v4.x);
        a2tV[(size_t)(q4*4+1) * FF_ + f] = f2b(v4.y);
        a2tV[(size_t)(q4*4+2) * FF_ + f] = f2b(v4.z);
        a2tV[(size_t)(q4*4+3) * FF_ + f] = f2b(v4.w);
      }
    }
    if (f < D_) {
      const float ev = e2b[f];
      #pragma unroll
      for (int r = 0; r < 16; ++r) {
        up2L[(size_t)f * 32 + r] = f2b(lora2B[(size_t)r * D_ + f]);
        up2V[(size_t)f * 32 + r] = f2b(vera2B[(size_t)r * D_ + f] * ev);
        up2L[(size_t)f * 32 + 16 + r] = 0;
        up2V[(size_t)f * 32 + 16 + r] = 0;
      }
    }
  }
}

// ---------------- LayerNorm (+residual add, + fused rank-16 down-projection) ----------------
template<bool ADD>
__global__ __launch_bounds__(256)
void ln_k(const float* __restrict__ x, const u16* __restrict__ add,
          const float* __restrict__ g, const float* __restrict__ beta,
          u16* __restrict__ outb, float* __restrict__ xsum,
          const float* __restrict__ Alora, const float* __restrict__ Avera,
          const float* __restrict__ dvec, u16* __restrict__ tmp1b,
          const int* __restrict__ nbp)
{
  const int row = blockIdx.x;
  const size_t base = (size_t)row * D_;
  float v0[3]; float s = 0.f, sq = 0.f;
  #pragma unroll
  for (int i = 0; i < 3; ++i) {
    const int d = threadIdx.x + i * 256;
    float val = x[base + d];
    if (ADD) { val += b2f(add[base + d]); xsum[base + d] = val; }
    v0[i] = val; s += val; sq += val * val;
  }
  #pragma unroll
  for (int mm = 32; mm >= 1; mm >>= 1) { s += __shfl_xor(s, mm); sq += __shfl_xor(sq, mm); }
  __shared__ float ss[4], s2[4];
  if ((threadIdx.x & 63) == 0) { ss[threadIdx.x >> 6] = s; s2[threadIdx.x >> 6] = sq; }
  __syncthreads();
  s  = ss[0] + ss[1] + ss[2] + ss[3];
  sq = s2[0] + s2[1] + s2[2] + s2[3];
  const float mean = s * (1.f / D_);
  const float var  = sq * (1.f / D_) - mean * mean;
  const float rs   = rsqrtf(var + 1e-6f);
  float nv[3];
  #pragma unroll
  for (int i = 0; i < 3; ++i) {
    const int d = threadIdx.x + i * 256;
    nv[i] = (v0[i] - mean) * rs * g[d] + beta[d];
    outb[base + d] = f2b(nv[i]);
  }

  if (ADD) {
    const int nb = *nbp;
    const bool ex = (row % S_) >= nb;
    const float* Am = ex ? Avera : Alora;
    float p[16];
    #pragma unroll
    for (int r = 0; r < 16; ++r) p[r] = 0.f;
    #pragma unroll
    for (int i = 0; i < 3; ++i) {
      const int d = threadIdx.x + i * 256;
      const float4* ap = (const float4*)(Am + (size_t)d * R_);
      const float4 a0 = ap[0], a1 = ap[1], a2 = ap[2], a3 = ap[3];
      const float vv = nv[i];
      p[0]  += vv * a0.x; p[1]  += vv * a0.y; p[2]  += vv * a0.z; p[3]  += vv * a0.w;
      p[4]  += vv * a1.x; p[5]  += vv * a1.y; p[6]  += vv * a1.z; p[7]  += vv * a1.w;
      p[8]  += vv * a2.x; p[9]  += vv * a2.y; p[10] += vv * a2.z; p[11] += vv * a2.w;
      p[12] += vv * a3.x; p[13] += vv * a3.y; p[14] += vv * a3.z; p[15] += vv * a3.w;
    }
    #pragma unroll
    for (int st = 1; st < 16; st <<= 1)
      #pragma unroll
      for (int r = 0; r < 16; ++r) p[r] += __shfl_xor(p[r], st);
    __shared__ float sred[16][16];
    const int grp = threadIdx.x >> 4;
    if ((threadIdx.x & 15) == 0) {
      #pragma unroll
      for (int r = 0; r < 16; ++r) sred[grp][r] = p[r];
    }
    __syncthreads();
    if (threadIdx.x < 16) {
      float v = 0.f;
      #pragma unroll
      for (int gg = 0; gg < 16; ++gg) v += sred[gg][threadIdx.x];
      if (ex) v *= dvec[threadIdx.x];
      tmp1b[(size_t)row * 32 + threadIdx.x] = f2b(v);
      tmp1b[(size_t)row * 32 + 16 + threadIdx.x] = 0;
    }
  }
}

// ---------------- bf16 MFMA GEMM: BK=64, single raw-barrier K-tile pipeline ----------------
// Per K-tile: issue next tile's 8 global_load_lds FIRST (pre-swizzled source ->
// linear LDS; reads use k8^(row&7) XOR swizzle, 2-way conflicts), then 16
// ds_read_b128 + 32 MFMA from current buffer, then vmcnt(0)+raw s_barrier (drain
// covered by the whole tile's compute). Adapter K=32 step staged into the free
// buffer during the last K-tile (MODE>=1).
template<int MODE>
__global__ __launch_bounds__(256)
void gemm_bt(const u16* __restrict__ A, const u16* __restrict__ W,
             const float* __restrict__ bias, u16* __restrict__ Cb,
             float* __restrict__ Cf, const float* __restrict__ resid,
             const u16* __restrict__ Aad, const u16* __restrict__ BadL,
             const u16* __restrict__ BadV, const int* __restrict__ nbp,
             int M, int N, int K)
{
  __shared__ u16 As[2][128 * 64];
  __shared__ u16 Bs[2][128 * 64];
  const int tid   = threadIdx.x;
  const int lane  = tid & 63;
  const int wid   = tid >> 6;
  const int wr    = wid >> 1;
  const int wc    = wid & 1;
  const int lr    = lane & 15;
  const int hi    = lane >> 4;
  const int gn    = N >> 7;
  const int nwg   = (M >> 7) * gn;
  const int chunk = nwg >> 3;
  const int lin   = blockIdx.x;
  const int swz   = (lin & 7) * chunk + (lin >> 3);
  const int m0    = (swz / gn) * 128;
  const int n0    = (swz % gn) * 128;

  const int nst = K >> 6;   // K-tiles of 64
  const u16* Bad = nullptr;
  if (MODE >= 1) Bad = ((m0 % S_) >= *nbp) ? BadV : BadL;

  // staging geometry (shared by all tiles): chunk li -> row r=li>>3, stored k8=li&7,
  // logical k8 = (li&7)^(r&7)  (pre-swizzled source, linear LDS dest)
  const int sr[4]  = { tid >> 3, (256 + tid) >> 3, (512 + tid) >> 3, (768 + tid) >> 3 };
  int scb[4];
  #pragma unroll
  for (int u = 0; u < 4; ++u) scb[u] = (((u * 256 + tid) & 7) ^ (sr[u] & 7)) * 8;

  fx4 acc[4][4];
  const fx4 zero = {0.f, 0.f, 0.f, 0.f};
  #pragma unroll
  for (int i = 0; i < 4; ++i)
    #pragma unroll
    for (int j = 0; j < 4; ++j) acc[i][j] = zero;

  // prologue: stage K-tile 0 into buf 0
  #pragma unroll
  for (int u = 0; u < 4; ++u) {
    gload16(A + (size_t)(m0 + sr[u]) * K + scb[u], &As[0][(u * 256 + tid) * 8]);
    gload16(W + (size_t)(n0 + sr[u]) * K + scb[u], &Bs[0][(u * 256 + tid) * 8]);
  }
  __syncthreads();

  for (int kt = 0; kt < nst; ++kt) {
    const int c = kt & 1;
    const bool more = (kt + 1 < nst);
    // ---- issue next-tile staging first ----
    if (more) {
      const int ko = (kt + 1) << 6;
      #pragma unroll
      for (int u = 0; u < 4; ++u) {
        gload16(A + (size_t)(m0 + sr[u]) * K + ko + scb[u], &As[c ^ 1][(u * 256 + tid) * 8]);
        gload16(W + (size_t)(n0 + sr[u]) * K + ko + scb[u], &Bs[c ^ 1][(u * 256 + tid) * 8]);
      }
    } else if (MODE >= 1) {
      // stage adapter tile (K=32, linear 32-wide layout) into free buffer
      #pragma unroll
      for (int u = 0; u < 2; ++u) {
        const int li = u * 256 + tid;           // 0..511
        const int r  = li >> 2;                 // 0..127
        const int cg = (li & 3) * 8;
        gload16(Aad + (size_t)(m0 + r) * 32 + cg, &As[c ^ 1][li * 8]);
        gload16(Bad + (size_t)(n0 + r) * 32 + cg, &Bs[c ^ 1][li * 8]);
      }
    }
    __builtin_amdgcn_sched_barrier(0);

    // ---- consume buf c (swizzled reads) ----
    s16x8 av[4][2], bv[4][2];
    #pragma unroll
    for (int i = 0; i < 4; ++i) {
      const int row = wr * 64 + i * 16 + lr;
      const int rb7 = row & 7;
      #pragma unroll
      for (int ks = 0; ks < 2; ++ks)
        av[i][ks] = *(const s16x8*)&As[c][row * 64 + (((ks * 4 + hi) ^ rb7) * 8)];
    }
    #pragma unroll
    for (int j = 0; j < 4; ++j) {
      const int row = wc * 64 + j * 16 + lr;
      const int rb7 = row & 7;
      #pragma unroll
      for (int ks = 0; ks < 2; ++ks)
        bv[j][ks] = *(const s16x8*)&Bs[c][row * 64 + (((ks * 4 + hi) ^ rb7) * 8)];
    }
    __builtin_amdgcn_s_setprio(1);
    #pragma unroll
    for (int ks = 0; ks < 2; ++ks)
      #pragma unroll
      for (int i = 0; i < 4; ++i)
        #pragma unroll
        for (int j = 0; j < 4; ++j)
          acc[i][j] = __builtin_amdgcn_mfma_f32_16x16x32_bf16(av[i][ks], bv[j][ks], acc[i][j], 0, 0, 0);
    __builtin_amdgcn_s_setprio(0);

    if (more || MODE >= 1) {
      __builtin_amdgcn_sched_barrier(0);
      asm volatile("s_waitcnt vmcnt(0) lgkmcnt(0)" ::: "memory");
      __builtin_amdgcn_s_barrier();
      __builtin_amdgcn_sched_barrier(0);
    }
  }

  if (MODE >= 1) {
    // adapter K=32 step from buf nst&1 (linear 32-wide layout)
    const int ad = nst & 1;
    s16x8 aav[4], abv[4];
    #pragma unroll
    for (int i = 0; i < 4; ++i)
      aav[i] = *(const s16x8*)&As[ad][(wr * 64 + i * 16 + lr) * 32 + hi * 8];
    #pragma unroll
    for (int j = 0; j < 4; ++j)
      abv[j] = *(const s16x8*)&Bs[ad][(wc * 64 + j * 16 + lr) * 32 + hi * 8];
    #pragma unroll
    for (int i = 0; i < 4; ++i)
      #pragma unroll
      for (int j = 0; j < 4; ++j)
        acc[i][j] = __builtin_amdgcn_mfma_f32_16x16x32_bf16(aav[i], abv[j], acc[i][j], 0, 0, 0);
  }

  const int rb = hi * 4;
  #pragma unroll
  for (int j = 0; j < 4; ++j) {
    const int col = n0 + wc * 64 + j * 16 + lr;
    const float bj = bias ? bias[col] : 0.f;
    #pragma unroll
    for (int i = 0; i < 4; ++i) {
      const int row = m0 + wr * 64 + i * 16 + rb;
      #pragma unroll
      for (int r = 0; r < 4; ++r) {
        const float val = acc[i][j][r] + bj;
        const size_t idx = (size_t)(row + r) * N + col;
        if (MODE == 1)      Cb[idx] = f2b(gelu_f(val));
        else if (MODE == 2) Cf[idx] = resid[idx] + val;
        else                Cb[idx] = f2b(val);
      }
    }
  }
}

// ---------------- skinny down-projection (2-phase dbuf): part[ks][M][16] ----------------
__global__ __launch_bounds__(256)
void downproj(const u16* __restrict__ hid, const u16* __restrict__ A2tL,
              const u16* __restrict__ A2tV, float* __restrict__ part,
              const int* __restrict__ nbp)
{
  __shared__ u16 As[2][128 * 32];
  __shared__ u16 Bs[2][16 * 32];
  const int tid  = threadIdx.x;
  const int lane = tid & 63;
  const int w    = tid >> 6;
  const int lr   = lane & 15;
  const int lk   = (lane >> 4) << 3;
  const int m0   = blockIdx.x * 128;
  const int kb   = blockIdx.y * (FF_ / 8);
  const int nb   = *nbp;
  const u16* A2t = ((m0 % S_) >= nb) ? A2tV : A2tL;
  const int kg    = (tid & 3) * 8;
  const int row_a = tid >> 2;

  const u16* hrow = hid + (size_t)(m0 + row_a) * FF_ + kb + kg;
  const size_t half_h = (size_t)64 * FF_;
  const u16* brow = A2t + (size_t)(tid >> 2) * FF_ + kb + kg;

  const fx4 zero = {0.f, 0.f, 0.f, 0.f};
  fx4 acc[2]; acc[0] = zero; acc[1] = zero;

  const int nst = (FF_ / 8) >> 5;   // 12
  gload16(hrow,          &As[0][tid * 8]);
  gload16(hrow + half_h, &As[0][(256 + tid) * 8]);
  if (tid < 64) gload16(brow, &Bs[0][tid * 8]);
  __syncthreads();

  for (int t = 0; t < nst; ++t) {
    const int cur = t & 1;
    if (t + 1 < nst) {
      const int nxt = cur ^ 1;
      const size_t ko = (size_t)(t + 1) * 32;
      gload16(hrow + ko,          &As[nxt][tid * 8]);
      gload16(hrow + ko + half_h, &As[nxt][(256 + tid) * 8]);
      if (tid < 64) gload16(brow + ko, &Bs[nxt][tid * 8]);
    }
    s16x8 bv = *(const s16x8*)&Bs[cur][lr * 32 + lk];
    #pragma unroll
    for (int i = 0; i < 2; ++i) {
      s16x8 av = *(const s16x8*)&As[cur][(w * 32 + i * 16 + lr) * 32 + lk];
      acc[i] = __builtin_amdgcn_mfma_f32_16x16x32_bf16(av, bv, acc[i], 0, 0, 0);
    }
    __syncthreads();
  }

  const int rb = (lane >> 4) * 4;
  #pragma unroll
  for (int i = 0; i < 2; ++i)
    #pragma unroll
    for (int r = 0; r < 4; ++r)
      part[(size_t)blockIdx.y * M_ * 16 +
           (size_t)(m0 + w * 32 + i * 16 + rb + r) * 16 + lr] = acc[i][r];
}

// ---------------- reduce partials -> tmp2b bf16 [M,32] ----------------
__global__ __launch_bounds__(256)
void reduce_dp(const float* __restrict__ part, const float* __restrict__ d2,
               u16* __restrict__ tmp2b, const int* __restrict__ nbp)
{
  const int idx = blockIdx.x * 256 + threadIdx.x;   // m*16 + r
  const int m = idx >> 4, r = idx & 15;
  const int nb = *nbp;
  float s = 0.f;
  #pragma unroll
  for (int ks = 0; ks < 8; ++ks) s += part[(size_t)ks * M_ * 16 + idx];
  if ((m % S_) >= nb) s *= d2[r];
  tmp2b[(size_t)m * 32 + r] = f2b(s);
  tmp2b[(size_t)m * 32 + 16 + r] = 0;
}

// ---------------- MFMA flash attention (R8 structure + T13 defer-max) ----------------
__global__ __launch_bounds__(256)
void attn_mfma(const u16* __restrict__ qkv, const float* __restrict__ mask,
               u16* __restrict__ o)
{
  __shared__ u16 Kl[2][128 * 64];   // row k, col d, swz col^((k&7)<<3)
  __shared__ u16 Vt[2][64 * 128];   // row d, col k, swz k^(((d&7)^((d>>3)&7))<<3)
  __shared__ uint32_t Pl[4][1024];  // per-wave P rows [16][64 u32]; prologue: Q overlay

  const int tid  = threadIdx.x;
  const int lane = tid & 63;
  const int wq   = tid >> 6;
  const int lr   = lane & 15;
  const int hi   = lane >> 4;
  const int lin = blockIdx.x;
  const int vsw = (lin & 7) * 192 + (lin >> 3);
  const int qb  = vsw & 15;
  const int bh  = vsw >> 4;
  const int b    = bh / H_;
  const int h    = bh % H_;
  const size_t tok0 = (size_t)b * S_ + (size_t)qb * 64;
  const size_t colh = (size_t)h * HD_;

  const int va  = tid >> 3;
  const int vc8 = (tid & 7) * 8;
  u16* qstage = (u16*)&Pl[0][0];

  #pragma unroll
  for (int u = 0; u < 2; ++u) {
    const int li = u * 256 + tid;
    const int r  = li >> 3;
    const int cb = ((li & 7) ^ (r & 7)) * 8;
    gload16(qkv + (tok0 + r) * QLD + colh + cb, &qstage[li * 8]);
  }
  {
    const size_t ktok = (size_t)b * S_;
    #pragma unroll
    for (int u = 0; u < 4; ++u) {
      const int li = u * 256 + tid;
      const int r  = li >> 3;
      const int cb = ((li & 7) ^ (r & 7)) * 8;
      gload16(qkv + (ktok + r) * QLD + D_ + colh + cb, &Kl[0][li * 8]);
    }
    const u16* vp = qkv + (ktok + 4 * va) * QLD + 2 * D_ + colh + vc8;
    s16x8 w0 = *(const s16x8*)vp;
    s16x8 w1 = *(const s16x8*)(vp + QLD);
    s16x8 w2 = *(const s16x8*)(vp + 2 * QLD);
    s16x8 w3 = *(const s16x8*)(vp + 3 * QLD);
    #pragma unroll
    for (int jj = 0; jj < 8; ++jj) {
      const int d  = vc8 + jj;
      const int sw = ((d & 7) ^ ((d >> 3) & 7)) << 3;
      const int cp = (4 * va) ^ sw;
      *(uint32_t*)&Vt[0][d * 128 + cp] =
          (uint32_t)(u16)w0[jj] | ((uint32_t)(u16)w1[jj] << 16);
      *(uint32_t*)&Vt[0][d * 128 + cp + 2] =
          (uint32_t)(u16)w2[jj] | ((uint32_t)(u16)w3[jj] << 16);
    }
  }
  __syncthreads();

  s16x8 qa[2];
  {
    const int qrow = wq * 16 + lr;
    #pragma unroll
    for (int ks = 0; ks < 2; ++ks)
      qa[ks] = *(const s16x8*)&qstage[qrow * 64 + ((ks * 32 + hi * 8) ^ ((qrow & 7) << 3))];
  }
  __syncthreads();   // all qa reads done before any P overwrite of Pl

  const fx4 zero = {0.f, 0.f, 0.f, 0.f};
  fx4 oacc[4];
  #pragma unroll
  for (int dj = 0; dj < 4; ++dj) oacc[dj] = zero;
  float mreg = -3.0e38f, lreg = 0.f;

  const int NT = S_ / KBLK;   // 8
  for (int kt = 0; kt < NT; ++kt) {
    const int cur = kt & 1;
    const int nxt = cur ^ 1;

    s16x8 w0, w1, w2, w3;
    if (kt + 1 < NT) {
      const size_t ktokn = (size_t)b * S_ + (size_t)(kt + 1) * KBLK;
      #pragma unroll
      for (int u = 0; u < 4; ++u) {
        const int li = u * 256 + tid;
        const int r  = li >> 3;
        const int cb = ((li & 7) ^ (r & 7)) * 8;
        gload16(qkv + (ktokn + r) * QLD + D_ + colh + cb, &Kl[nxt][li * 8]);
      }
      const u16* vp = qkv + (ktokn + 4 * va) * QLD + 2 * D_ + colh + vc8;
      w0 = *(const s16x8*)vp;
      w1 = *(const s16x8*)(vp + QLD);
      w2 = *(const s16x8*)(vp + 2 * QLD);
      w3 = *(const s16x8*)(vp + 3 * QLD);
    }

    float val[8][4];
    #pragma unroll
    for (int jh = 0; jh < 2; ++jh) {
      s16x8 kb2[4][2];
      #pragma unroll
      for (int j = 0; j < 4; ++j) {
        const int n = (jh * 4 + j) * 16 + lr;
        #pragma unroll
        for (int ks = 0; ks < 2; ++ks)
          kb2[j][ks] = *(const s16x8*)&Kl[cur][n * 64 + ((ks * 32 + hi * 8) ^ ((n & 7) << 3))];
      }
      fx4 m4[4];
      {
        const float* mp = mask + (size_t)(qb * 64 + wq * 16 + lr) * S_
                        + (size_t)kt * KBLK + jh * 64 + 4 * hi;
        #pragma unroll
        for (int j = 0; j < 4; ++j)
          m4[j] = *(const fx4*)(mp + j * 16);
      }
      fx4 sf[4];
      #pragma unroll
      for (int j = 0; j < 4; ++j) sf[j] = zero;
      __builtin_amdgcn_s_setprio(1);
      #pragma unroll
      for (int ks = 0; ks < 2; ++ks)
        #pragma unroll
        for (int j = 0; j < 4; ++j)
          sf[j] = __builtin_amdgcn_mfma_f32_16x16x32_bf16(kb2[j][ks], qa[ks], sf[j], 0, 0, 0);
      __builtin_amdgcn_s_setprio(0);
      #pragma unroll
      for (int j = 0; j < 4; ++j)
        #pragma unroll
        for (int r = 0; r < 4; ++r)
          val[jh * 4 + j][r] = sf[j][r] * 0.125f + m4[j][r];
    }

    {
      float mk[8];
      #pragma unroll
      for (int kg = 0; kg < 8; ++kg)
        mk[kg] = fmaxf(fmaxf(val[kg][0], val[kg][1]), fmaxf(val[kg][2], val[kg][3]));
      float mx = fmaxf(fmaxf(fmaxf(mk[0], mk[1]), fmaxf(mk[2], mk[3])),
                       fmaxf(fmaxf(mk[4], mk[5]), fmaxf(mk[6], mk[7])));
      mx = fmaxf(mx, __shfl_xor(mx, 16));
      mx = fmaxf(mx, __shfl_xor(mx, 32));
      const bool noresc = (bool)__all(mx <= mreg + 8.f);
      float fac = 1.f;
      if (!noresc) {
        const float mn = fmaxf(mreg, mx);
        fac = __expf(mreg - mn);
        mreg = mn;
      }
      float sk[8];
      #pragma unroll
      for (int kg = 0; kg < 8; ++kg) {
        #pragma unroll
        for (int r = 0; r < 4; ++r) val[kg][r] = __expf(val[kg][r] - mreg);
        sk[kg] = (val[kg][0] + val[kg][1]) + (val[kg][2] + val[kg][3]);
      }
      float rs = ((sk[0] + sk[1]) + (sk[2] + sk[3])) + ((sk[4] + sk[5]) + (sk[6] + sk[7]));
      rs += __shfl_xor(rs, 16);
      rs += __shfl_xor(rs, 32);
      lreg = lreg * fac + rs;
      if (!noresc) {
        float facr[4];
        #pragma unroll
        for (int r = 0; r < 4; ++r) facr[r] = __shfl(fac, hi * 4 + r);
        #pragma unroll
        for (int dj = 0; dj < 4; ++dj)
          #pragma unroll
          for (int r = 0; r < 4; ++r) oacc[dj][r] *= facr[r];
      }
    }

    {
      uint32_t* prow = &Pl[wq][lr * 64];
      #pragma unroll
      for (int kg = 0; kg < 8; ++kg) {
        const uint32_t p0 = __builtin_amdgcn_perm(
            __float_as_uint(val[kg][1]), __float_as_uint(val[kg][0]), 0x07060302u);
        const uint32_t p1 = __builtin_amdgcn_perm(
            __float_as_uint(val[kg][3]), __float_as_uint(val[kg][2]), 0x07060302u);
        const int i0 = (8 * kg + 2 * hi) ^ ((lr & 7) << 3);
        uint2 pk; pk.x = p0; pk.y = p1;
        *(uint2*)&prow[i0] = pk;
      }
    }

    if (kt + 1 < NT) {
      #pragma unroll
      for (int jj = 0; jj < 8; ++jj) {
        const int d  = vc8 + jj;
        const int sw = ((d & 7) ^ ((d >> 3) & 7)) << 3;
        const int cp = (4 * va) ^ sw;
        *(uint32_t*)&Vt[nxt][d * 128 + cp] =
            (uint32_t)(u16)w0[jj] | ((uint32_t)(u16)w1[jj] << 16);
        *(uint32_t*)&Vt[nxt][d * 128 + cp + 2] =
            (uint32_t)(u16)w2[jj] | ((uint32_t)(u16)w3[jj] << 16);
      }
    }

    #pragma unroll
    for (int ks = 0; ks < 4; ++ks) {
      const int pbase = (16 * ks + 4 * hi) ^ ((lr & 7) << 3);
      s16x8 pa = *(const s16x8*)&Pl[wq][lr * 64 + pbase];
      s16x8 bv2[4];
      #pragma unroll
      for (int dj = 0; dj < 4; ++dj) {
        const int n  = dj * 16 + lr;
        const int sw = ((n & 7) ^ ((n >> 3) & 7)) << 3;
        bv2[dj] = *(const s16x8*)&Vt[cur][n * 128 + ((ks * 32 + hi * 8) ^ sw)];
      }
      __builtin_amdgcn_s_setprio(1);
      #pragma unroll
      for (int dj = 0; dj < 4; ++dj)
        oacc[dj] = __builtin_amdgcn_mfma_f32_16x16x32_bf16(pa, bv2[dj], oacc[dj], 0, 0, 0);
      __builtin_amdgcn_s_setprio(0);
    }

    __syncthreads();
  }

  {
    const float linv = 1.f / lreg;
    float invr[4];
    #pragma unroll
    for (int r = 0; r < 4; ++r) invr[r] = __shfl(linv, hi * 4 + r);
    #pragma unroll
    for (int r = 0; r < 4; ++r) {
      const size_t grow = (tok0 + wq * 16 + hi * 4 + r) * D_ + colh;
      #pragma unroll
      for (int dj = 0; dj < 4; ++dj)
        o[grow + dj * 16 + lr] = f2b(oacc[dj][r] * invr[r]);
    }
  }
}

extern "C" void kernel_launch(void* const* d_in, const int* in_sizes, int n_in,
                              void* d_out, int out_size, void* d_ws, size_t ws_size,
                              hipStream_t stream)
{
  const float* x      = (const float*)d_in[0];
  const float* mask   = (const float*)d_in[1];
  const float* n1g    = (const float*)d_in[2];
  const float* n1b    = (const float*)d_in[3];
  const float* q_w    = (const float*)d_in[4];
  const float* q_bv   = (const float*)d_in[5];
  const float* k_w    = (const float*)d_in[6];
  const float* k_bv   = (const float*)d_in[7];
  const float* v_w    = (const float*)d_in[8];
  const float* v_bv   = (const float*)d_in[9];
  const float* o_w    = (const float*)d_in[10];
  const float* o_bv   = (const float*)d_in[11];
  const float* n2g    = (const float*)d_in[12];
  const float* n2b    = (const float*)d_in[13];
  const float* fc1_w  = (const float*)d_in[14];
  const float* fc1_bv = (const float*)d_in[15];
  const float* fc2_w  = (const float*)d_in[16];
  const float* fc2_bv = (const float*)d_in[17];
  const float* lora1A = (const float*)d_in[18];
  const float* lora1B = (const float*)d_in[19];
  const float* lora2A = (const float*)d_in[20];
  const float* lora2B = (const float*)d_in[21];
  const float* vera1A = (const float*)d_in[22];
  const float* vera1B = (const float*)d_in[23];
  const float* vera2A = (const float*)d_in[24];
  const float* vera2B = (const float*)d_in[25];
  const float* e1d    = (const float*)d_in[26];
  const float* e1b    = (const float*)d_in[27];
  const float* e2d    = (const float*)d_in[28];
  const float* e2b    = (const float*)d_in[29];
  const int*   nbp    = (const int*)d_in[30];

  char* wsb = (char*)d_ws;
  u16* h1    = (u16*)wsb; wsb += (size_t)M_ * D_ * 2;       // 12.6 MB
  u16* qkv   = (u16*)wsb; wsb += (size_t)M_ * QLD * 2;      // 37.7 MB
  u16* attno = (u16*)wsb; wsb += (size_t)M_ * D_ * 2;
  u16* oproj = (u16*)wsb; wsb += (size_t)M_ * D_ * 2;
  u16* n2    = (u16*)wsb; wsb += (size_t)M_ * D_ * 2;
  u16* wqkv  = (u16*)wsb; wsb += (size_t)QLD * D_ * 2;
  u16* wo    = (u16*)wsb; wsb += (size_t)D_ * D_ * 2;
  u16* wfc1  = (u16*)wsb; wsb += (size_t)FF_ * D_ * 2;
  u16* wfc2  = (u16*)wsb; wsb += (size_t)D_ * FF_ * 2;
  u16* tmp1b = (u16*)wsb; wsb += (size_t)M_ * 32 * 2;
  u16* tmp2b = (u16*)wsb; wsb += (size_t)M_ * 32 * 2;
  u16* up1L  = (u16*)wsb; wsb += (size_t)FF_ * 32 * 2;
  u16* up1V  = (u16*)wsb; wsb += (size_t)FF_ * 32 * 2;
  u16* up2L  = (u16*)wsb; wsb += (size_t)D_ * 32 * 2;
  u16* up2V  = (u16*)wsb; wsb += (size_t)D_ * 32 * 2;
  u16* a2tL  = (u16*)wsb; wsb += (size_t)16 * FF_ * 2;
  u16* a2tV  = (u16*)wsb; wsb += (size_t)16 * FF_ * 2;
  float* qkvb = (float*)wsb; wsb += (size_t)QLD * 4;
  float* part = (float*)wsb; wsb += (size_t)8 * M_ * 16 * 4; // 4 MB
  u16* hidb = h1;   // [M,FF] bf16 aliases h1+qkv (both dead by fc1)

  const int totq = (4 * D_ * D_ + 2 * FF_ * D_) / 4;
  cvt_prep<<<totq / 256, 256, 0, stream>>>(q_w, k_w, v_w, o_w, fc1_w, fc2_w,
                                           wqkv, wo, wfc1, wfc2,
                                           q_bv, k_bv, v_bv, qkvb,
                                           lora1B, vera1B, e1b, up1L, up1V,
                                           lora2B, vera2B, e2b, up2L, up2V,
                                           lora2A, vera2A, a2tL, a2tV);

  ln_k<false><<<M_, 256, 0, stream>>>(x, nullptr, n1g, n1b, h1, nullptr,
                                      nullptr, nullptr, nullptr, nullptr, nullptr);
  gemm_bt<0><<<(M_/128) * (QLD/128), 256, 0, stream>>>(
      h1, wqkv, qkvb, qkv, nullptr, nullptr, nullptr, nullptr, nullptr, nullptr,
      M_, QLD, D_);
  attn_mfma<<<(S_/64) * (B_*H_), 256, 0, stream>>>(qkv, mask, attno);
  gemm_bt<0><<<(M_/128) * (D_/128), 256, 0, stream>>>(
      attno, wo, o_bv, oproj, nullptr, nullptr, nullptr, nullptr, nullptr, nullptr,
      M_, D_, D_);

  ln_k<true><<<M_, 256, 0, stream>>>(x, oproj, n2g, n2b, n2, (float*)d_out,
                                     lora1A, vera1A, e1d, tmp1b, nbp);

  gemm_bt<1><<<(M_/128) * (FF_/128), 256, 0, stream>>>(
      n2, wfc1, fc1_bv, hidb, nullptr, nullptr, tmp1b, up1L, up1V, nbp,
      M_, FF_, D_);

  downproj<<<dim3(M_/128, 8), 256, 0, stream>>>(hidb, a2tL, a2tV, part, nbp);
  reduce_dp<<<M_*16/256, 256, 0, stream>>>(part, e2d, tmp2b, nbp);

  gemm_bt<2><<<(M_/128) * (D_/128), 256, 0, stream>>>(
      hidb, wfc2, fc2_bv, nullptr, (float*)d_out, (const float*)d_out,
      tmp2b, up2L, up2V, nbp, M_, D_, FF_);
}

// Round 13
// 345.560 us; speedup vs baseline: 1.2309x; 1.0063x over previous
//
#include <hip/hip_runtime.h>
#include <stdint.h>

#define B_  8
#define S_  1024
#define D_  768
#define H_  12
#define HD_ 64
#define FF_ 3072
#define M_  (B_*S_)   // 8192 tokens
#define R_  16
#define QLD 2304      // packed QKV row stride
#define KBLK 64

typedef unsigned short u16;
typedef short s16x8 __attribute__((ext_vector_type(8)));   // 8 bf16 (4 VGPRs)
typedef float fx4  __attribute__((ext_vector_type(4)));    // 4 fp32 acc

__device__ __forceinline__ float b2f(u16 u) {
  union { unsigned int i; float f; } c; c.i = ((unsigned int)u) << 16; return c.f;
}
__device__ __forceinline__ u16 f2b(float f) {   // RNE f32->bf16
  union { float f; unsigned int i; } c; c.f = f;
  unsigned int x = c.i;
  x += 0x7FFFu + ((x >> 16) & 1u);
  return (u16)(x >> 16);
}
__device__ __forceinline__ float gelu_f(float x) {  // jax.nn.gelu approximate=True (tanh)
  float u = 0.7978845608028654f * (x + 0.044715f * x * x * x);
  float e = __expf(2.f * u);
  float t = 1.f - 2.f / (e + 1.f);
  return 0.5f * x * (1.f + t);
}
__device__ __forceinline__ void gload16(const u16* gsrc, u16* ldst) {
  __builtin_amdgcn_global_load_lds(
      (__attribute__((address_space(1))) void*)(gsrc),
      (__attribute__((address_space(3))) void*)(ldst), 16, 0, 0);
}

// ---------------- weights f32->bf16 + all small preps, ONE kernel ----------------
__global__ __launch_bounds__(256)
void cvt_prep(const float* __restrict__ q_w, const float* __restrict__ k_w,
              const float* __restrict__ v_w, const float* __restrict__ o_w,
              const float* __restrict__ fc1_w, const float* __restrict__ fc2_w,
              u16* __restrict__ wqkv, u16* __restrict__ wo,
              u16* __restrict__ wfc1, u16* __restrict__ wfc2,
              const float* __restrict__ q_bv, const float* __restrict__ k_bv,
              const float* __restrict__ v_bv, float* __restrict__ qkvb,
              const float* __restrict__ lora1B, const float* __restrict__ vera1B,
              const float* __restrict__ e1b, u16* __restrict__ up1L, u16* __restrict__ up1V,
              const float* __restrict__ lora2B, const float* __restrict__ vera2B,
              const float* __restrict__ e2b, u16* __restrict__ up2L, u16* __restrict__ up2V,
              const float* __restrict__ lora2A, const float* __restrict__ vera2A,
              u16* __restrict__ a2tL, u16* __restrict__ a2tV)
{
  const int i = blockIdx.x * 256 + threadIdx.x;   // quad index
  const int q1  = D_ * D_ / 4;
  const int fd4 = FF_ * D_ / 4;
  {
    const float* s; u16* d; int j;
    if      (i <     q1)       { s = q_w;   d = wqkv;            j = i; }
    else if (i < 2 * q1)       { s = k_w;   d = wqkv + D_*D_;    j = i - q1; }
    else if (i < 3 * q1)       { s = v_w;   d = wqkv + 2*D_*D_;  j = i - 2*q1; }
    else if (i < 4 * q1)       { s = o_w;   d = wo;              j = i - 3*q1; }
    else if (i < 4 * q1 + fd4) { s = fc1_w; d = wfc1;            j = i - 4*q1; }
    else                       { s = fc2_w; d = wfc2;            j = i - 4*q1 - fd4; }
    const float4 f = ((const float4*)s)[j];
    ushort4 o4; o4.x = f2b(f.x); o4.y = f2b(f.y); o4.z = f2b(f.z); o4.w = f2b(f.w);
    ((ushort4*)d)[j] = o4;
  }
  if (i < FF_) {
    const int f = i;
    if (f < QLD)
      qkvb[f] = (f < D_) ? q_bv[f] : (f < 2 * D_) ? k_bv[f - D_] : v_bv[f - 2 * D_];
    {
      const float ev = e1b[f];
      #pragma unroll
      for (int r = 0; r < 16; ++r) {
        up1L[(size_t)f * 32 + r] = f2b(lora1B[(size_t)r * FF_ + f]);
        up1V[(size_t)f * 32 + r] = f2b(vera1B[(size_t)r * FF_ + f] * ev);
        up1L[(size_t)f * 32 + 16 + r] = 0;
        up1V[(size_t)f * 32 + 16 + r] = 0;
      }
    }
    {
      const float4* apl = (const float4*)(lora2A + (size_t)f * 16);
      const float4* apv = (const float4*)(vera2A + (size_t)f * 16);
      #pragma unroll
      for (int q4 = 0; q4 < 4; ++q4) {
        const float4 l4 = apl[q4], v4 = apv[q4];
        a2tL[(size_t)(q4*4+0) * FF_ + f] = f2b(l4.x);
        a2tL[(size_t)(q4*4+1) * FF_ + f] = f2b(l4.y);
        a2tL[(size_t)(q4*4+2) * FF_ + f] = f2b(l4.z);
        a2tL[(size_t)(q4*4+3) * FF_ + f] = f2b(l4.w);
        a2tV[(size_t)(q4*4+0) * FF_ + f] = f2b(v4.x);
        a2tV[(size_t)(q4*4+1) * FF_ + f] = f2b(v4.y);
        a2tV[(size_t)(q4*4+2) * FF_ + f] = f2b(v4.z);
        a2tV[(size_t)(q4*4+3) * FF_ + f] = f2b(v4.w);
      }
    }
    if (f < D_) {
      const float ev = e2b[f];
      #pragma unroll
      for (int r = 0; r < 16; ++r) {
        up2L[(size_t)f * 32 + r] = f2b(lora2B[(size_t)r * D_ + f]);
        up2V[(size_t)f * 32 + r] = f2b(vera2B[(size_t)r * D_ + f] * ev);
        up2L[(size_t)f * 32 + 16 + r] = 0;
        up2V[(size_t)f * 32 + 16 + r] = 0;
      }
    }
  }
}

// ---------------- LayerNorm (+residual add, + fused rank-16 down-projection) ----------------
template<bool ADD>
__global__ __launch_bounds__(256)
void ln_k(const float* __restrict__ x, const u16* __restrict__ add,
          const float* __restrict__ g, const float* __restrict__ beta,
          u16* __restrict__ outb, float* __restrict__ xsum,
          const float* __restrict__ Alora, const float* __restrict__ Avera,
          const float* __restrict__ dvec, u16* __restrict__ tmp1b,
          const int* __restrict__ nbp)
{
  const int row = blockIdx.x;
  const size_t base = (size_t)row * D_;
  float v0[3]; float s = 0.f, sq = 0.f;
  #pragma unroll
  for (int i = 0; i < 3; ++i) {
    const int d = threadIdx.x + i * 256;
    float val = x[base + d];
    if (ADD) { val += b2f(add[base + d]); xsum[base + d] = val; }
    v0[i] = val; s += val; sq += val * val;
  }
  #pragma unroll
  for (int mm = 32; mm >= 1; mm >>= 1) { s += __shfl_xor(s, mm); sq += __shfl_xor(sq, mm); }
  __shared__ float ss[4], s2[4];
  if ((threadIdx.x & 63) == 0) { ss[threadIdx.x >> 6] = s; s2[threadIdx.x >> 6] = sq; }
  __syncthreads();
  s  = ss[0] + ss[1] + ss[2] + ss[3];
  sq = s2[0] + s2[1] + s2[2] + s2[3];
  const float mean = s * (1.f / D_);
  const float var  = sq * (1.f / D_) - mean * mean;
  const float rs   = rsqrtf(var + 1e-6f);
  float nv[3];
  #pragma unroll
  for (int i = 0; i < 3; ++i) {
    const int d = threadIdx.x + i * 256;
    nv[i] = (v0[i] - mean) * rs * g[d] + beta[d];
    outb[base + d] = f2b(nv[i]);
  }

  if (ADD) {
    const int nb = *nbp;
    const bool ex = (row % S_) >= nb;
    const float* Am = ex ? Avera : Alora;
    float p[16];
    #pragma unroll
    for (int r = 0; r < 16; ++r) p[r] = 0.f;
    #pragma unroll
    for (int i = 0; i < 3; ++i) {
      const int d = threadIdx.x + i * 256;
      const float4* ap = (const float4*)(Am + (size_t)d * R_);
      const float4 a0 = ap[0], a1 = ap[1], a2 = ap[2], a3 = ap[3];
      const float vv = nv[i];
      p[0]  += vv * a0.x; p[1]  += vv * a0.y; p[2]  += vv * a0.z; p[3]  += vv * a0.w;
      p[4]  += vv * a1.x; p[5]  += vv * a1.y; p[6]  += vv * a1.z; p[7]  += vv * a1.w;
      p[8]  += vv * a2.x; p[9]  += vv * a2.y; p[10] += vv * a2.z; p[11] += vv * a2.w;
      p[12] += vv * a3.x; p[13] += vv * a3.y; p[14] += vv * a3.z; p[15] += vv * a3.w;
    }
    #pragma unroll
    for (int st = 1; st < 16; st <<= 1)
      #pragma unroll
      for (int r = 0; r < 16; ++r) p[r] += __shfl_xor(p[r], st);
    __shared__ float sred[16][16];
    const int grp = threadIdx.x >> 4;
    if ((threadIdx.x & 15) == 0) {
      #pragma unroll
      for (int r = 0; r < 16; ++r) sred[grp][r] = p[r];
    }
    __syncthreads();
    if (threadIdx.x < 16) {
      float v = 0.f;
      #pragma unroll
      for (int gg = 0; gg < 16; ++gg) v += sred[gg][threadIdx.x];
      if (ex) v *= dvec[threadIdx.x];
      tmp1b[(size_t)row * 32 + threadIdx.x] = f2b(v);
      tmp1b[(size_t)row * 32 + 16 + threadIdx.x] = 0;
    }
  }
}

// ---------------- bf16 MFMA GEMM: BK=64, single raw-barrier K-tile pipeline ----------------
template<int MODE>
__global__ __launch_bounds__(256)
void gemm_bt(const u16* __restrict__ A, const u16* __restrict__ W,
             const float* __restrict__ bias, u16* __restrict__ Cb,
             float* __restrict__ Cf, const float* __restrict__ resid,
             const u16* __restrict__ Aad, const u16* __restrict__ BadL,
             const u16* __restrict__ BadV, const int* __restrict__ nbp,
             int M, int N, int K)
{
  __shared__ u16 As[2][128 * 64];
  __shared__ u16 Bs[2][128 * 64];
  const int tid   = threadIdx.x;
  const int lane  = tid & 63;
  const int wid   = tid >> 6;
  const int wr    = wid >> 1;
  const int wc    = wid & 1;
  const int lr    = lane & 15;
  const int hi    = lane >> 4;
  const int gn    = N >> 7;
  const int nwg   = (M >> 7) * gn;
  const int chunk = nwg >> 3;
  const int lin   = blockIdx.x;
  const int swz   = (lin & 7) * chunk + (lin >> 3);
  const int m0    = (swz / gn) * 128;
  const int n0    = (swz % gn) * 128;

  const int nst = K >> 6;   // K-tiles of 64
  const u16* Bad = nullptr;
  if (MODE >= 1) Bad = ((m0 % S_) >= *nbp) ? BadV : BadL;

  const int sr[4]  = { tid >> 3, (256 + tid) >> 3, (512 + tid) >> 3, (768 + tid) >> 3 };
  int scb[4];
  #pragma unroll
  for (int u = 0; u < 4; ++u) scb[u] = (((u * 256 + tid) & 7) ^ (sr[u] & 7)) * 8;

  fx4 acc[4][4];
  const fx4 zero = {0.f, 0.f, 0.f, 0.f};
  #pragma unroll
  for (int i = 0; i < 4; ++i)
    #pragma unroll
    for (int j = 0; j < 4; ++j) acc[i][j] = zero;

  #pragma unroll
  for (int u = 0; u < 4; ++u) {
    gload16(A + (size_t)(m0 + sr[u]) * K + scb[u], &As[0][(u * 256 + tid) * 8]);
    gload16(W + (size_t)(n0 + sr[u]) * K + scb[u], &Bs[0][(u * 256 + tid) * 8]);
  }
  __syncthreads();

  for (int kt = 0; kt < nst; ++kt) {
    const int c = kt & 1;
    const bool more = (kt + 1 < nst);
    if (more) {
      const int ko = (kt + 1) << 6;
      #pragma unroll
      for (int u = 0; u < 4; ++u) {
        gload16(A + (size_t)(m0 + sr[u]) * K + ko + scb[u], &As[c ^ 1][(u * 256 + tid) * 8]);
        gload16(W + (size_t)(n0 + sr[u]) * K + ko + scb[u], &Bs[c ^ 1][(u * 256 + tid) * 8]);
      }
    } else if (MODE >= 1) {
      #pragma unroll
      for (int u = 0; u < 2; ++u) {
        const int li = u * 256 + tid;
        const int r  = li >> 2;
        const int cg = (li & 3) * 8;
        gload16(Aad + (size_t)(m0 + r) * 32 + cg, &As[c ^ 1][li * 8]);
        gload16(Bad + (size_t)(n0 + r) * 32 + cg, &Bs[c ^ 1][li * 8]);
      }
    }
    __builtin_amdgcn_sched_barrier(0);

    s16x8 av[4][2], bv[4][2];
    #pragma unroll
    for (int i = 0; i < 4; ++i) {
      const int row = wr * 64 + i * 16 + lr;
      const int rb7 = row & 7;
      #pragma unroll
      for (int ks = 0; ks < 2; ++ks)
        av[i][ks] = *(const s16x8*)&As[c][row * 64 + (((ks * 4 + hi) ^ rb7) * 8)];
    }
    #pragma unroll
    for (int j = 0; j < 4; ++j) {
      const int row = wc * 64 + j * 16 + lr;
      const int rb7 = row & 7;
      #pragma unroll
      for (int ks = 0; ks < 2; ++ks)
        bv[j][ks] = *(const s16x8*)&Bs[c][row * 64 + (((ks * 4 + hi) ^ rb7) * 8)];
    }
    __builtin_amdgcn_s_setprio(1);
    #pragma unroll
    for (int ks = 0; ks < 2; ++ks)
      #pragma unroll
      for (int i = 0; i < 4; ++i)
        #pragma unroll
        for (int j = 0; j < 4; ++j)
          acc[i][j] = __builtin_amdgcn_mfma_f32_16x16x32_bf16(av[i][ks], bv[j][ks], acc[i][j], 0, 0, 0);
    __builtin_amdgcn_s_setprio(0);

    if (more || MODE >= 1) {
      __builtin_amdgcn_sched_barrier(0);
      asm volatile("s_waitcnt vmcnt(0) lgkmcnt(0)" ::: "memory");
      __builtin_amdgcn_s_barrier();
      __builtin_amdgcn_sched_barrier(0);
    }
  }

  if (MODE >= 1) {
    const int ad = nst & 1;
    s16x8 aav[4], abv[4];
    #pragma unroll
    for (int i = 0; i < 4; ++i)
      aav[i] = *(const s16x8*)&As[ad][(wr * 64 + i * 16 + lr) * 32 + hi * 8];
    #pragma unroll
    for (int j = 0; j < 4; ++j)
      abv[j] = *(const s16x8*)&Bs[ad][(wc * 64 + j * 16 + lr) * 32 + hi * 8];
    #pragma unroll
    for (int i = 0; i < 4; ++i)
      #pragma unroll
      for (int j = 0; j < 4; ++j)
        acc[i][j] = __builtin_amdgcn_mfma_f32_16x16x32_bf16(aav[i], abv[j], acc[i][j], 0, 0, 0);
  }

  const int rb = hi * 4;
  #pragma unroll
  for (int j = 0; j < 4; ++j) {
    const int col = n0 + wc * 64 + j * 16 + lr;
    const float bj = bias ? bias[col] : 0.f;
    #pragma unroll
    for (int i = 0; i < 4; ++i) {
      const int row = m0 + wr * 64 + i * 16 + rb;
      #pragma unroll
      for (int r = 0; r < 4; ++r) {
        const float val = acc[i][j][r] + bj;
        const size_t idx = (size_t)(row + r) * N + col;
        if (MODE == 1)      Cb[idx] = f2b(gelu_f(val));
        else if (MODE == 2) Cf[idx] = resid[idx] + val;
        else                Cb[idx] = f2b(val);
      }
    }
  }
}

// ---------------- skinny down-projection (2-phase dbuf): part[ks][M][16] ----------------
__global__ __launch_bounds__(256)
void downproj(const u16* __restrict__ hid, const u16* __restrict__ A2tL,
              const u16* __restrict__ A2tV, float* __restrict__ part,
              const int* __restrict__ nbp)
{
  __shared__ u16 As[2][128 * 32];
  __shared__ u16 Bs[2][16 * 32];
  const int tid  = threadIdx.x;
  const int lane = tid & 63;
  const int w    = tid >> 6;
  const int lr   = lane & 15;
  const int lk   = (lane >> 4) << 3;
  const int m0   = blockIdx.x * 128;
  const int kb   = blockIdx.y * (FF_ / 8);
  const int nb   = *nbp;
  const u16* A2t = ((m0 % S_) >= nb) ? A2tV : A2tL;
  const int kg    = (tid & 3) * 8;
  const int row_a = tid >> 2;

  const u16* hrow = hid + (size_t)(m0 + row_a) * FF_ + kb + kg;
  const size_t half_h = (size_t)64 * FF_;
  const u16* brow = A2t + (size_t)(tid >> 2) * FF_ + kb + kg;

  const fx4 zero = {0.f, 0.f, 0.f, 0.f};
  fx4 acc[2]; acc[0] = zero; acc[1] = zero;

  const int nst = (FF_ / 8) >> 5;   // 12
  gload16(hrow,          &As[0][tid * 8]);
  gload16(hrow + half_h, &As[0][(256 + tid) * 8]);
  if (tid < 64) gload16(brow, &Bs[0][tid * 8]);
  __syncthreads();

  for (int t = 0; t < nst; ++t) {
    const int cur = t & 1;
    if (t + 1 < nst) {
      const int nxt = cur ^ 1;
      const size_t ko = (size_t)(t + 1) * 32;
      gload16(hrow + ko,          &As[nxt][tid * 8]);
      gload16(hrow + ko + half_h, &As[nxt][(256 + tid) * 8]);
      if (tid < 64) gload16(brow + ko, &Bs[nxt][tid * 8]);
    }
    s16x8 bv = *(const s16x8*)&Bs[cur][lr * 32 + lk];
    #pragma unroll
    for (int i = 0; i < 2; ++i) {
      s16x8 av = *(const s16x8*)&As[cur][(w * 32 + i * 16 + lr) * 32 + lk];
      acc[i] = __builtin_amdgcn_mfma_f32_16x16x32_bf16(av, bv, acc[i], 0, 0, 0);
    }
    __syncthreads();
  }

  const int rb = (lane >> 4) * 4;
  #pragma unroll
  for (int i = 0; i < 2; ++i)
    #pragma unroll
    for (int r = 0; r < 4; ++r)
      part[(size_t)blockIdx.y * M_ * 16 +
           (size_t)(m0 + w * 32 + i * 16 + rb + r) * 16 + lr] = acc[i][r];
}

// ---------------- reduce partials -> tmp2b bf16 [M,32] ----------------
__global__ __launch_bounds__(256)
void reduce_dp(const float* __restrict__ part, const float* __restrict__ d2,
               u16* __restrict__ tmp2b, const int* __restrict__ nbp)
{
  const int idx = blockIdx.x * 256 + threadIdx.x;   // m*16 + r
  const int m = idx >> 4, r = idx & 15;
  const int nb = *nbp;
  float s = 0.f;
  #pragma unroll
  for (int ks = 0; ks < 8; ++ks) s += part[(size_t)ks * M_ * 16 + idx];
  if ((m % S_) >= nb) s *= d2[r];
  tmp2b[(size_t)m * 32 + r] = f2b(s);
  tmp2b[(size_t)m * 32 + 16 + r] = 0;
}

// ---------------- MFMA flash attention: KBLK=64, 48KB LDS (3 blocks/CU) ----------------
// R8 pipeline at half tile width: K dbuf via global_load_lds, V reg->LDS dbuf,
// swapped QK^T (q lane-local), v_perm P pack into 64-u32-stride rows (same bank
// patterns as R8), T13 defer-max. 16 tiles, one barrier each.
__global__ __launch_bounds__(256)
void attn_mfma(const u16* __restrict__ qkv, const float* __restrict__ mask,
               u16* __restrict__ o)
{
  __shared__ u16 Kl[2][KBLK * 64];   // row k, col d, swz col^((k&7)<<3)   (8KB each)
  __shared__ u16 Vt[2][64 * KBLK];   // row d, col k, swz k^(((d&7)^((d>>3)&7))<<3)
  __shared__ uint32_t Pl[4][1024];   // per-wave P rows [16][64 u32]; prologue: Q overlay

  const int tid  = threadIdx.x;
  const int lane = tid & 63;
  const int wq   = tid >> 6;
  const int lr   = lane & 15;
  const int hi   = lane >> 4;
  const int lin = blockIdx.x;
  const int vsw = (lin & 7) * 192 + (lin >> 3);
  const int qb  = vsw & 15;
  const int bh  = vsw >> 4;
  const int b    = bh / H_;
  const int h    = bh % H_;
  const size_t tok0 = (size_t)b * S_ + (size_t)qb * 64;
  const size_t colh = (size_t)h * HD_;

  const int va  = tid >> 3;          // V staging: k-rows 2*va, 2*va+1 (0..63)
  const int vc8 = (tid & 7) * 8;     // V staging: d cols vc8..+7
  u16* qstage = (u16*)&Pl[0][0];

  // ---- prologue: Q -> Pl overlay, K0 -> Kl[0], V0 -> regs -> Vt[0] ----
  #pragma unroll
  for (int u = 0; u < 2; ++u) {
    const int li = u * 256 + tid;
    const int r  = li >> 3;
    const int cb = ((li & 7) ^ (r & 7)) * 8;
    gload16(qkv + (tok0 + r) * QLD + colh + cb, &qstage[li * 8]);
  }
  {
    const size_t ktok = (size_t)b * S_;
    #pragma unroll
    for (int u = 0; u < 2; ++u) {
      const int li = u * 256 + tid;
      const int r  = li >> 3;          // 0..63
      const int cb = ((li & 7) ^ (r & 7)) * 8;
      gload16(qkv + (ktok + r) * QLD + D_ + colh + cb, &Kl[0][li * 8]);
    }
    const u16* vp = qkv + (ktok + 2 * va) * QLD + 2 * D_ + colh + vc8;
    s16x8 w0 = *(const s16x8*)vp;
    s16x8 w1 = *(const s16x8*)(vp + QLD);
    #pragma unroll
    for (int jj = 0; jj < 8; ++jj) {
      const int d  = vc8 + jj;
      const int sw = ((d & 7) ^ ((d >> 3) & 7)) << 3;
      const int cp = (2 * va) ^ sw;
      *(uint32_t*)&Vt[0][d * KBLK + cp] =
          (uint32_t)(u16)w0[jj] | ((uint32_t)(u16)w1[jj] << 16);
    }
  }
  __syncthreads();

  s16x8 qa[2];
  {
    const int qrow = wq * 16 + lr;
    #pragma unroll
    for (int ks = 0; ks < 2; ++ks)
      qa[ks] = *(const s16x8*)&qstage[qrow * 64 + ((ks * 32 + hi * 8) ^ ((qrow & 7) << 3))];
  }
  __syncthreads();   // all qa reads done before any P overwrite of Pl

  const fx4 zero = {0.f, 0.f, 0.f, 0.f};
  fx4 oacc[4];
  #pragma unroll
  for (int dj = 0; dj < 4; ++dj) oacc[dj] = zero;
  float mreg = -3.0e38f, lreg = 0.f;   // per-lane: q-row = wq*16 + lr

  const int NT = S_ / KBLK;   // 16
  for (int kt = 0; kt < NT; ++kt) {
    const int cur = kt & 1;
    const int nxt = cur ^ 1;

    // ---- issue next-tile staging (K -> LDS direct, V -> regs) ----
    s16x8 w0, w1;
    if (kt + 1 < NT) {
      const size_t ktokn = (size_t)b * S_ + (size_t)(kt + 1) * KBLK;
      #pragma unroll
      for (int u = 0; u < 2; ++u) {
        const int li = u * 256 + tid;
        const int r  = li >> 3;
        const int cb = ((li & 7) ^ (r & 7)) * 8;
        gload16(qkv + (ktokn + r) * QLD + D_ + colh + cb, &Kl[nxt][li * 8]);
      }
      const u16* vp = qkv + (ktokn + 2 * va) * QLD + 2 * D_ + colh + vc8;
      w0 = *(const s16x8*)vp;
      w1 = *(const s16x8*)(vp + QLD);
    }

    // ---- QK^T SWAPPED: val[j][r] = S[k=16j+4hi+r][q=wq*16+lr] ----
    float val[4][4];
    {
      s16x8 kb2[4][2];
      #pragma unroll
      for (int j = 0; j < 4; ++j) {
        const int n = j * 16 + lr;
        #pragma unroll
        for (int ks = 0; ks < 2; ++ks)
          kb2[j][ks] = *(const s16x8*)&Kl[cur][n * 64 + ((ks * 32 + hi * 8) ^ ((n & 7) << 3))];
      }
      fx4 m4[4];
      {
        const float* mp = mask + (size_t)(qb * 64 + wq * 16 + lr) * S_
                        + (size_t)kt * KBLK + 4 * hi;
        #pragma unroll
        for (int j = 0; j < 4; ++j)
          m4[j] = *(const fx4*)(mp + j * 16);
      }
      fx4 sf[4];
      #pragma unroll
      for (int j = 0; j < 4; ++j) sf[j] = zero;
      __builtin_amdgcn_s_setprio(1);
      #pragma unroll
      for (int ks = 0; ks < 2; ++ks)
        #pragma unroll
        for (int j = 0; j < 4; ++j)
          sf[j] = __builtin_amdgcn_mfma_f32_16x16x32_bf16(kb2[j][ks], qa[ks], sf[j], 0, 0, 0);
      __builtin_amdgcn_s_setprio(0);
      #pragma unroll
      for (int j = 0; j < 4; ++j)
        #pragma unroll
        for (int r = 0; r < 4; ++r)
          val[j][r] = sf[j][r] * 0.125f + m4[j][r];
    }

    // ---- online softmax (lane-local rows) + T13 defer-max ----
    {
      float mk[4];
      #pragma unroll
      for (int kg = 0; kg < 4; ++kg)
        mk[kg] = fmaxf(fmaxf(val[kg][0], val[kg][1]), fmaxf(val[kg][2], val[kg][3]));
      float mx = fmaxf(fmaxf(mk[0], mk[1]), fmaxf(mk[2], mk[3]));
      mx = fmaxf(mx, __shfl_xor(mx, 16));
      mx = fmaxf(mx, __shfl_xor(mx, 32));
      const bool noresc = (bool)__all(mx <= mreg + 8.f);
      float fac = 1.f;
      if (!noresc) {
        const float mn = fmaxf(mreg, mx);
        fac = __expf(mreg - mn);
        mreg = mn;
      }
      float sk[4];
      #pragma unroll
      for (int kg = 0; kg < 4; ++kg) {
        #pragma unroll
        for (int r = 0; r < 4; ++r) val[kg][r] = __expf(val[kg][r] - mreg);
        sk[kg] = (val[kg][0] + val[kg][1]) + (val[kg][2] + val[kg][3]);
      }
      float rs = (sk[0] + sk[1]) + (sk[2] + sk[3]);
      rs += __shfl_xor(rs, 16);
      rs += __shfl_xor(rs, 32);
      lreg = lreg * fac + rs;
      if (!noresc) {
        float facr[4];
        #pragma unroll
        for (int r = 0; r < 4; ++r) facr[r] = __shfl(fac, hi * 4 + r);
        #pragma unroll
        for (int dj = 0; dj < 4; ++dj)
          #pragma unroll
          for (int r = 0; r < 4; ++r) oacc[dj][r] *= facr[r];
      }
    }

    // ---- P pack (v_perm trunc) -> wave-private swizzled LDS, 4x b64 ----
    {
      uint32_t* prow = &Pl[wq][lr * 64];
      #pragma unroll
      for (int kg = 0; kg < 4; ++kg) {
        const uint32_t p0 = __builtin_amdgcn_perm(
            __float_as_uint(val[kg][1]), __float_as_uint(val[kg][0]), 0x07060302u);
        const uint32_t p1 = __builtin_amdgcn_perm(
            __float_as_uint(val[kg][3]), __float_as_uint(val[kg][2]), 0x07060302u);
        const int i0 = (8 * kg + 2 * hi) ^ ((lr & 7) << 3);
        uint2 pk; pk.x = p0; pk.y = p1;
        *(uint2*)&prow[i0] = pk;
      }
    }

    // ---- write next-tile V (regs -> LDS, opposite buffer) ----
    if (kt + 1 < NT) {
      #pragma unroll
      for (int jj = 0; jj < 8; ++jj) {
        const int d  = vc8 + jj;
        const int sw = ((d & 7) ^ ((d >> 3) & 7)) << 3;
        const int cp = (2 * va) ^ sw;
        *(uint32_t*)&Vt[nxt][d * KBLK + cp] =
            (uint32_t)(u16)w0[jj] | ((uint32_t)(u16)w1[jj] << 16);
      }
    }

    // ---- PV from Vt[cur]: 2 K-slices of 32 ----
    #pragma unroll
    for (int ks = 0; ks < 2; ++ks) {
      const int pbase = (16 * ks + 4 * hi) ^ ((lr & 7) << 3);
      s16x8 pa = *(const s16x8*)&Pl[wq][lr * 64 + pbase];
      s16x8 bv2[4];
      #pragma unroll
      for (int dj = 0; dj < 4; ++dj) {
        const int n  = dj * 16 + lr;
        const int sw = ((n & 7) ^ ((n >> 3) & 7)) << 3;
        bv2[dj] = *(const s16x8*)&Vt[cur][n * KBLK + ((ks * 32 + hi * 8) ^ sw)];
      }
      __builtin_amdgcn_s_setprio(1);
      #pragma unroll
      for (int dj = 0; dj < 4; ++dj)
        oacc[dj] = __builtin_amdgcn_mfma_f32_16x16x32_bf16(pa, bv2[dj], oacc[dj], 0, 0, 0);
      __builtin_amdgcn_s_setprio(0);
    }

    __syncthreads();   // staged K(t+1)/V(t+1) visible; Vt[cur]/Kl[cur] reads done
  }

  // ---- epilogue: O /= l (per-row inv redistributed), write ----
  {
    const float linv = 1.f / lreg;
    float invr[4];
    #pragma unroll
    for (int r = 0; r < 4; ++r) invr[r] = __shfl(linv, hi * 4 + r);
    #pragma unroll
    for (int r = 0; r < 4; ++r) {
      const size_t grow = (tok0 + wq * 16 + hi * 4 + r) * D_ + colh;
      #pragma unroll
      for (int dj = 0; dj < 4; ++dj)
        o[grow + dj * 16 + lr] = f2b(oacc[dj][r] * invr[r]);
    }
  }
}

extern "C" void kernel_launch(void* const* d_in, const int* in_sizes, int n_in,
                              void* d_out, int out_size, void* d_ws, size_t ws_size,
                              hipStream_t stream)
{
  const float* x      = (const float*)d_in[0];
  const float* mask   = (const float*)d_in[1];
  const float* n1g    = (const float*)d_in[2];
  const float* n1b    = (const float*)d_in[3];
  const float* q_w    = (const float*)d_in[4];
  const float* q_bv   = (const float*)d_in[5];
  const float* k_w    = (const float*)d_in[6];
  const float* k_bv   = (const float*)d_in[7];
  const float* v_w    = (const float*)d_in[8];
  const float* v_bv   = (const float*)d_in[9];
  const float* o_w    = (const float*)d_in[10];
  const float* o_bv   = (const float*)d_in[11];
  const float* n2g    = (const float*)d_in[12];
  const float* n2b    = (const float*)d_in[13];
  const float* fc1_w  = (const float*)d_in[14];
  const float* fc1_bv = (const float*)d_in[15];
  const float* fc2_w  = (const float*)d_in[16];
  const float* fc2_bv = (const float*)d_in[17];
  const float* lora1A = (const float*)d_in[18];
  const float* lora1B = (const float*)d_in[19];
  const float* lora2A = (const float*)d_in[20];
  const float* lora2B = (const float*)d_in[21];
  const float* vera1A = (const float*)d_in[22];
  const float* vera1B = (const float*)d_in[23];
  const float* vera2A = (const float*)d_in[24];
  const float* vera2B = (const float*)d_in[25];
  const float* e1d    = (const float*)d_in[26];
  const float* e1b    = (const float*)d_in[27];
  const float* e2d    = (const float*)d_in[28];
  const float* e2b    = (const float*)d_in[29];
  const int*   nbp    = (const int*)d_in[30];

  char* wsb = (char*)d_ws;
  u16* h1    = (u16*)wsb; wsb += (size_t)M_ * D_ * 2;       // 12.6 MB
  u16* qkv   = (u16*)wsb; wsb += (size_t)M_ * QLD * 2;      // 37.7 MB
  u16* attno = (u16*)wsb; wsb += (size_t)M_ * D_ * 2;
  u16* oproj = (u16*)wsb; wsb += (size_t)M_ * D_ * 2;
  u16* n2    = (u16*)wsb; wsb += (size_t)M_ * D_ * 2;
  u16* wqkv  = (u16*)wsb; wsb += (size_t)QLD * D_ * 2;
  u16* wo    = (u16*)wsb; wsb += (size_t)D_ * D_ * 2;
  u16* wfc1  = (u16*)wsb; wsb += (size_t)FF_ * D_ * 2;
  u16* wfc2  = (u16*)wsb; wsb += (size_t)D_ * FF_ * 2;
  u16* tmp1b = (u16*)wsb; wsb += (size_t)M_ * 32 * 2;
  u16* tmp2b = (u16*)wsb; wsb += (size_t)M_ * 32 * 2;
  u16* up1L  = (u16*)wsb; wsb += (size_t)FF_ * 32 * 2;
  u16* up1V  = (u16*)wsb; wsb += (size_t)FF_ * 32 * 2;
  u16* up2L  = (u16*)wsb; wsb += (size_t)D_ * 32 * 2;
  u16* up2V  = (u16*)wsb; wsb += (size_t)D_ * 32 * 2;
  u16* a2tL  = (u16*)wsb; wsb += (size_t)16 * FF_ * 2;
  u16* a2tV  = (u16*)wsb; wsb += (size_t)16 * FF_ * 2;
  float* qkvb = (float*)wsb; wsb += (size_t)QLD * 4;
  float* part = (float*)wsb; wsb += (size_t)8 * M_ * 16 * 4; // 4 MB
  u16* hidb = h1;   // [M,FF] bf16 aliases h1+qkv (both dead by fc1)

  const int totq = (4 * D_ * D_ + 2 * FF_ * D_) / 4;
  cvt_prep<<<totq / 256, 256, 0, stream>>>(q_w, k_w, v_w, o_w, fc1_w, fc2_w,
                                           wqkv, wo, wfc1, wfc2,
                                           q_bv, k_bv, v_bv, qkvb,
                                           lora1B, vera1B, e1b, up1L, up1V,
                                           lora2B, vera2B, e2b, up2L, up2V,
                                           lora2A, vera2A, a2tL, a2tV);

  ln_k<false><<<M_, 256, 0, stream>>>(x, nullptr, n1g, n1b, h1, nullptr,
                                      nullptr, nullptr, nullptr, nullptr, nullptr);
  gemm_bt<0><<<(M_/128) * (QLD/128), 256, 0, stream>>>(
      h1, wqkv, qkvb, qkv, nullptr, nullptr, nullptr, nullptr, nullptr, nullptr,
      M_, QLD, D_);
  attn_mfma<<<(S_/64) * (B_*H_), 256, 0, stream>>>(qkv, mask, attno);
  gemm_bt<0><<<(M_/128) * (D_/128), 256, 0, stream>>>(
      attno, wo, o_bv, oproj, nullptr, nullptr, nullptr, nullptr, nullptr, nullptr,
      M_, D_, D_);

  ln_k<true><<<M_, 256, 0, stream>>>(x, oproj, n2g, n2b, n2, (float*)d_out,
                                     lora1A, vera1A, e1d, tmp1b, nbp);

  gemm_bt<1><<<(M_/128) * (FF_/128), 256, 0, stream>>>(
      n2, wfc1, fc1_bv, hidb, nullptr, nullptr, tmp1b, up1L, up1V, nbp,
      M_, FF_, D_);

  downproj<<<dim3(M_/128, 8), 256, 0, stream>>>(hidb, a2tL, a2tV, part, nbp);
  reduce_dp<<<M_*16/256, 256, 0, stream>>>(part, e2d, tmp2b, nbp);

  gemm_bt<2><<<(M_/128) * (D_/128), 256, 0, stream>>>(
      hidb, wfc2, fc2_bv, nullptr, (float*)d_out, (const float*)d_out,
      tmp2b, up2L, up2V, nbp, M_, D_, FF_);
}

// Round 14
// 345.162 us; speedup vs baseline: 1.2323x; 1.0012x over previous
//
#include <hip/hip_runtime.h>
#include <stdint.h>

#define B_  8
#define S_  1024
#define D_  768
#define H_  12
#define HD_ 64
#define FF_ 3072
#define M_  (B_*S_)   // 8192 tokens
#define R_  16
#define QLD 2304      // packed QKV row stride
#define KBLK 64

typedef unsigned short u16;
typedef short s16x8 __attribute__((ext_vector_type(8)));   // 8 bf16 (4 VGPRs)
typedef float fx4  __attribute__((ext_vector_type(4)));    // 4 fp32 acc

__device__ __forceinline__ float b2f(u16 u) {
  union { unsigned int i; float f; } c; c.i = ((unsigned int)u) << 16; return c.f;
}
__device__ __forceinline__ u16 f2b(float f) {   // RNE f32->bf16
  union { float f; unsigned int i; } c; c.f = f;
  unsigned int x = c.i;
  x += 0x7FFFu + ((x >> 16) & 1u);
  return (u16)(x >> 16);
}
__device__ __forceinline__ float gelu_f(float x) {  // jax.nn.gelu approximate=True (tanh)
  float u = 0.7978845608028654f * (x + 0.044715f * x * x * x);
  float e = __expf(2.f * u);
  float t = 1.f - 2.f / (e + 1.f);
  return 0.5f * x * (1.f + t);
}
__device__ __forceinline__ void gload16(const u16* gsrc, u16* ldst) {
  __builtin_amdgcn_global_load_lds(
      (__attribute__((address_space(1))) void*)(gsrc),
      (__attribute__((address_space(3))) void*)(ldst), 16, 0, 0);
}

// ---------------- weights f32->bf16 + all small preps, ONE kernel ----------------
__global__ __launch_bounds__(256)
void cvt_prep(const float* __restrict__ q_w, const float* __restrict__ k_w,
              const float* __restrict__ v_w, const float* __restrict__ o_w,
              const float* __restrict__ fc1_w, const float* __restrict__ fc2_w,
              u16* __restrict__ wqkv, u16* __restrict__ wo,
              u16* __restrict__ wfc1, u16* __restrict__ wfc2,
              const float* __restrict__ q_bv, const float* __restrict__ k_bv,
              const float* __restrict__ v_bv, float* __restrict__ qkvb,
              const float* __restrict__ lora1B, const float* __restrict__ vera1B,
              const float* __restrict__ e1b, u16* __restrict__ up1L, u16* __restrict__ up1V,
              const float* __restrict__ lora2B, const float* __restrict__ vera2B,
              const float* __restrict__ e2b, u16* __restrict__ up2L, u16* __restrict__ up2V,
              const float* __restrict__ lora2A, const float* __restrict__ vera2A,
              u16* __restrict__ a2tL, u16* __restrict__ a2tV)
{
  const int i = blockIdx.x * 256 + threadIdx.x;   // quad index
  const int q1  = D_ * D_ / 4;
  const int fd4 = FF_ * D_ / 4;
  {
    const float* s; u16* d; int j;
    if      (i <     q1)       { s = q_w;   d = wqkv;            j = i; }
    else if (i < 2 * q1)       { s = k_w;   d = wqkv + D_*D_;    j = i - q1; }
    else if (i < 3 * q1)       { s = v_w;   d = wqkv + 2*D_*D_;  j = i - 2*q1; }
    else if (i < 4 * q1)       { s = o_w;   d = wo;              j = i - 3*q1; }
    else if (i < 4 * q1 + fd4) { s = fc1_w; d = wfc1;            j = i - 4*q1; }
    else                       { s = fc2_w; d = wfc2;            j = i - 4*q1 - fd4; }
    const float4 f = ((const float4*)s)[j];
    ushort4 o4; o4.x = f2b(f.x); o4.y = f2b(f.y); o4.z = f2b(f.z); o4.w = f2b(f.w);
    ((ushort4*)d)[j] = o4;
  }
  if (i < FF_) {
    const int f = i;
    if (f < QLD)
      qkvb[f] = (f < D_) ? q_bv[f] : (f < 2 * D_) ? k_bv[f - D_] : v_bv[f - 2 * D_];
    {
      const float ev = e1b[f];
      #pragma unroll
      for (int r = 0; r < 16; ++r) {
        up1L[(size_t)f * 32 + r] = f2b(lora1B[(size_t)r * FF_ + f]);
        up1V[(size_t)f * 32 + r] = f2b(vera1B[(size_t)r * FF_ + f] * ev);
        up1L[(size_t)f * 32 + 16 + r] = 0;
        up1V[(size_t)f * 32 + 16 + r] = 0;
      }
    }
    {
      const float4* apl = (const float4*)(lora2A + (size_t)f * 16);
      const float4* apv = (const float4*)(vera2A + (size_t)f * 16);
      #pragma unroll
      for (int q4 = 0; q4 < 4; ++q4) {
        const float4 l4 = apl[q4], v4 = apv[q4];
        a2tL[(size_t)(q4*4+0) * FF_ + f] = f2b(l4.x);
        a2tL[(size_t)(q4*4+1) * FF_ + f] = f2b(l4.y);
        a2tL[(size_t)(q4*4+2) * FF_ + f] = f2b(l4.z);
        a2tL[(size_t)(q4*4+3) * FF_ + f] = f2b(l4.w);
        a2tV[(size_t)(q4*4+0) * FF_ + f] = f2b(v4.x);
        a2tV[(size_t)(q4*4+1) * FF_ + f] = f2b(v4.y);
        a2tV[(size_t)(q4*4+2) * FF_ + f] = f2b(v4.z);
        a2tV[(size_t)(q4*4+3) * FF_ + f] = f2b(v4.w);
      }
    }
    if (f < D_) {
      const float ev = e2b[f];
      #pragma unroll
      for (int r = 0; r < 16; ++r) {
        up2L[(size_t)f * 32 + r] = f2b(lora2B[(size_t)r * D_ + f]);
        up2V[(size_t)f * 32 + r] = f2b(vera2B[(size_t)r * D_ + f] * ev);
        up2L[(size_t)f * 32 + 16 + r] = 0;
        up2V[(size_t)f * 32 + 16 + r] = 0;
      }
    }
  }
}

// ---------------- LayerNorm (+residual add, + fused rank-16 down-projection) ----------------
template<bool ADD>
__global__ __launch_bounds__(256)
void ln_k(const float* __restrict__ x, const u16* __restrict__ add,
          const float* __restrict__ g, const float* __restrict__ beta,
          u16* __restrict__ outb, float* __restrict__ xsum,
          const float* __restrict__ Alora, const float* __restrict__ Avera,
          const float* __restrict__ dvec, u16* __restrict__ tmp1b,
          const int* __restrict__ nbp)
{
  const int row = blockIdx.x;
  const size_t base = (size_t)row * D_;
  float v0[3]; float s = 0.f, sq = 0.f;
  #pragma unroll
  for (int i = 0; i < 3; ++i) {
    const int d = threadIdx.x + i * 256;
    float val = x[base + d];
    if (ADD) { val += b2f(add[base + d]); xsum[base + d] = val; }
    v0[i] = val; s += val; sq += val * val;
  }
  #pragma unroll
  for (int mm = 32; mm >= 1; mm >>= 1) { s += __shfl_xor(s, mm); sq += __shfl_xor(sq, mm); }
  __shared__ float ss[4], s2[4];
  if ((threadIdx.x & 63) == 0) { ss[threadIdx.x >> 6] = s; s2[threadIdx.x >> 6] = sq; }
  __syncthreads();
  s  = ss[0] + ss[1] + ss[2] + ss[3];
  sq = s2[0] + s2[1] + s2[2] + s2[3];
  const float mean = s * (1.f / D_);
  const float var  = sq * (1.f / D_) - mean * mean;
  const float rs   = rsqrtf(var + 1e-6f);
  float nv[3];
  #pragma unroll
  for (int i = 0; i < 3; ++i) {
    const int d = threadIdx.x + i * 256;
    nv[i] = (v0[i] - mean) * rs * g[d] + beta[d];
    outb[base + d] = f2b(nv[i]);
  }

  if (ADD) {
    const int nb = *nbp;
    const bool ex = (row % S_) >= nb;
    const float* Am = ex ? Avera : Alora;
    float p[16];
    #pragma unroll
    for (int r = 0; r < 16; ++r) p[r] = 0.f;
    #pragma unroll
    for (int i = 0; i < 3; ++i) {
      const int d = threadIdx.x + i * 256;
      const float4* ap = (const float4*)(Am + (size_t)d * R_);
      const float4 a0 = ap[0], a1 = ap[1], a2 = ap[2], a3 = ap[3];
      const float vv = nv[i];
      p[0]  += vv * a0.x; p[1]  += vv * a0.y; p[2]  += vv * a0.z; p[3]  += vv * a0.w;
      p[4]  += vv * a1.x; p[5]  += vv * a1.y; p[6]  += vv * a1.z; p[7]  += vv * a1.w;
      p[8]  += vv * a2.x; p[9]  += vv * a2.y; p[10] += vv * a2.z; p[11] += vv * a2.w;
      p[12] += vv * a3.x; p[13] += vv * a3.y; p[14] += vv * a3.z; p[15] += vv * a3.w;
    }
    #pragma unroll
    for (int st = 1; st < 16; st <<= 1)
      #pragma unroll
      for (int r = 0; r < 16; ++r) p[r] += __shfl_xor(p[r], st);
    __shared__ float sred[16][16];
    const int grp = threadIdx.x >> 4;
    if ((threadIdx.x & 15) == 0) {
      #pragma unroll
      for (int r = 0; r < 16; ++r) sred[grp][r] = p[r];
    }
    __syncthreads();
    if (threadIdx.x < 16) {
      float v = 0.f;
      #pragma unroll
      for (int gg = 0; gg < 16; ++gg) v += sred[gg][threadIdx.x];
      if (ex) v *= dvec[threadIdx.x];
      tmp1b[(size_t)row * 32 + threadIdx.x] = f2b(v);
      tmp1b[(size_t)row * 32 + 16 + threadIdx.x] = 0;
    }
  }
}

// ---------------- bf16 MFMA GEMM: BK=64, counted-vmcnt 2-deep pipeline (T3+T4) ----------------
// Prologue issues tiles 0,1. Per tile t: vmcnt(8) waits ONLY tile t's loads
// (tile t+1 stays in flight), raw barrier, ds_read+32 MFMA, raw barrier (reads
// done chip-wide), issue tile t+2 into the freed buffer. No vmcnt(0) drain in
// steady state. Adapter K=32 step = tile nst (4 loads -> vmcnt(4) boundary).
template<int MODE>
__global__ __launch_bounds__(256)
void gemm_bt(const u16* __restrict__ A, const u16* __restrict__ W,
             const float* __restrict__ bias, u16* __restrict__ Cb,
             float* __restrict__ Cf, const float* __restrict__ resid,
             const u16* __restrict__ Aad, const u16* __restrict__ BadL,
             const u16* __restrict__ BadV, const int* __restrict__ nbp,
             int M, int N, int K)
{
  __shared__ u16 As[2][128 * 64];
  __shared__ u16 Bs[2][128 * 64];
  const int tid   = threadIdx.x;
  const int lane  = tid & 63;
  const int wid   = tid >> 6;
  const int wr    = wid >> 1;
  const int wc    = wid & 1;
  const int lr    = lane & 15;
  const int hi    = lane >> 4;
  const int gn    = N >> 7;
  const int nwg   = (M >> 7) * gn;
  const int chunk = nwg >> 3;
  const int lin   = blockIdx.x;
  const int swz   = (lin & 7) * chunk + (lin >> 3);
  const int m0    = (swz / gn) * 128;
  const int n0    = (swz % gn) * 128;

  const int nst = K >> 6;   // main K-tiles of 64 (>= 12 for all our calls)
  const int tot = (MODE >= 1) ? nst + 1 : nst;
  const u16* Bad = nullptr;
  if (MODE >= 1) Bad = ((m0 % S_) >= *nbp) ? BadV : BadL;

  const int sr[4]  = { tid >> 3, (256 + tid) >> 3, (512 + tid) >> 3, (768 + tid) >> 3 };
  int scb[4];
  #pragma unroll
  for (int u = 0; u < 4; ++u) scb[u] = (((u * 256 + tid) & 7) ^ (sr[u] & 7)) * 8;

  fx4 acc[4][4];
  const fx4 zero = {0.f, 0.f, 0.f, 0.f};
  #pragma unroll
  for (int i = 0; i < 4; ++i)
    #pragma unroll
    for (int j = 0; j < 4; ++j) acc[i][j] = zero;

  // prologue: issue tiles 0 and 1 (both main; nst >= 2 for all call sites)
  #pragma unroll
  for (int u = 0; u < 4; ++u) {
    gload16(A + (size_t)(m0 + sr[u]) * K + scb[u], &As[0][(u * 256 + tid) * 8]);
    gload16(W + (size_t)(n0 + sr[u]) * K + scb[u], &Bs[0][(u * 256 + tid) * 8]);
  }
  #pragma unroll
  for (int u = 0; u < 4; ++u) {
    gload16(A + (size_t)(m0 + sr[u]) * K + 64 + scb[u], &As[1][(u * 256 + tid) * 8]);
    gload16(W + (size_t)(n0 + sr[u]) * K + 64 + scb[u], &Bs[1][(u * 256 + tid) * 8]);
  }

  for (int t = 0; t < tot; ++t) {
    const int c = t & 1;
    // wait tile t's loads only; leave tile t+1's in flight
    if (t + 1 >= tot) {
      asm volatile("s_waitcnt vmcnt(0)" ::: "memory");
    } else if (MODE >= 1 && t + 1 == nst) {
      asm volatile("s_waitcnt vmcnt(4)" ::: "memory");
    } else {
      asm volatile("s_waitcnt vmcnt(8)" ::: "memory");
    }
    __builtin_amdgcn_s_barrier();
    __builtin_amdgcn_sched_barrier(0);

    if (MODE >= 1 && t == nst) {
      // adapter consume (32-wide linear layout)
      s16x8 aav[4], abv[4];
      #pragma unroll
      for (int i = 0; i < 4; ++i)
        aav[i] = *(const s16x8*)&As[c][(wr * 64 + i * 16 + lr) * 32 + hi * 8];
      #pragma unroll
      for (int j = 0; j < 4; ++j)
        abv[j] = *(const s16x8*)&Bs[c][(wc * 64 + j * 16 + lr) * 32 + hi * 8];
      #pragma unroll
      for (int i = 0; i < 4; ++i)
        #pragma unroll
        for (int j = 0; j < 4; ++j)
          acc[i][j] = __builtin_amdgcn_mfma_f32_16x16x32_bf16(aav[i], abv[j], acc[i][j], 0, 0, 0);
    } else {
      // main consume (64-wide, XOR-swizzled reads)
      s16x8 av[4][2], bv[4][2];
      #pragma unroll
      for (int i = 0; i < 4; ++i) {
        const int row = wr * 64 + i * 16 + lr;
        const int rb7 = row & 7;
        #pragma unroll
        for (int ks = 0; ks < 2; ++ks)
          av[i][ks] = *(const s16x8*)&As[c][row * 64 + (((ks * 4 + hi) ^ rb7) * 8)];
      }
      #pragma unroll
      for (int j = 0; j < 4; ++j) {
        const int row = wc * 64 + j * 16 + lr;
        const int rb7 = row & 7;
        #pragma unroll
        for (int ks = 0; ks < 2; ++ks)
          bv[j][ks] = *(const s16x8*)&Bs[c][row * 64 + (((ks * 4 + hi) ^ rb7) * 8)];
      }
      __builtin_amdgcn_s_setprio(1);
      #pragma unroll
      for (int ks = 0; ks < 2; ++ks)
        #pragma unroll
        for (int i = 0; i < 4; ++i)
          #pragma unroll
          for (int j = 0; j < 4; ++j)
            acc[i][j] = __builtin_amdgcn_mfma_f32_16x16x32_bf16(av[i][ks], bv[j][ks], acc[i][j], 0, 0, 0);
      __builtin_amdgcn_s_setprio(0);
    }

    // issue tile t+2 into buf c (freed after all waves pass barrier#2)
    if (t + 2 <= tot - 1) {
      __builtin_amdgcn_sched_barrier(0);
      __builtin_amdgcn_s_barrier();
      __builtin_amdgcn_sched_barrier(0);
      if (MODE >= 1 && t + 2 == nst) {
        #pragma unroll
        for (int u = 0; u < 2; ++u) {
          const int li = u * 256 + tid;
          const int r  = li >> 2;
          const int cg = (li & 3) * 8;
          gload16(Aad + (size_t)(m0 + r) * 32 + cg, &As[c][li * 8]);
          gload16(Bad + (size_t)(n0 + r) * 32 + cg, &Bs[c][li * 8]);
        }
      } else {
        const int ko = (t + 2) << 6;
        #pragma unroll
        for (int u = 0; u < 4; ++u) {
          gload16(A + (size_t)(m0 + sr[u]) * K + ko + scb[u], &As[c][(u * 256 + tid) * 8]);
          gload16(W + (size_t)(n0 + sr[u]) * K + ko + scb[u], &Bs[c][(u * 256 + tid) * 8]);
        }
      }
    }
  }

  const int rb = hi * 4;
  #pragma unroll
  for (int j = 0; j < 4; ++j) {
    const int col = n0 + wc * 64 + j * 16 + lr;
    const float bj = bias ? bias[col] : 0.f;
    #pragma unroll
    for (int i = 0; i < 4; ++i) {
      const int row = m0 + wr * 64 + i * 16 + rb;
      #pragma unroll
      for (int r = 0; r < 4; ++r) {
        const float val = acc[i][j][r] + bj;
        const size_t idx = (size_t)(row + r) * N + col;
        if (MODE == 1)      Cb[idx] = f2b(gelu_f(val));
        else if (MODE == 2) Cf[idx] = resid[idx] + val;
        else                Cb[idx] = f2b(val);
      }
    }
  }
}

// ---------------- skinny down-projection (2-phase dbuf): part[ks][M][16] ----------------
__global__ __launch_bounds__(256)
void downproj(const u16* __restrict__ hid, const u16* __restrict__ A2tL,
              const u16* __restrict__ A2tV, float* __restrict__ part,
              const int* __restrict__ nbp)
{
  __shared__ u16 As[2][128 * 32];
  __shared__ u16 Bs[2][16 * 32];
  const int tid  = threadIdx.x;
  const int lane = tid & 63;
  const int w    = tid >> 6;
  const int lr   = lane & 15;
  const int lk   = (lane >> 4) << 3;
  const int m0   = blockIdx.x * 128;
  const int kb   = blockIdx.y * (FF_ / 8);
  const int nb   = *nbp;
  const u16* A2t = ((m0 % S_) >= nb) ? A2tV : A2tL;
  const int kg    = (tid & 3) * 8;
  const int row_a = tid >> 2;

  const u16* hrow = hid + (size_t)(m0 + row_a) * FF_ + kb + kg;
  const size_t half_h = (size_t)64 * FF_;
  const u16* brow = A2t + (size_t)(tid >> 2) * FF_ + kb + kg;

  const fx4 zero = {0.f, 0.f, 0.f, 0.f};
  fx4 acc[2]; acc[0] = zero; acc[1] = zero;

  const int nst = (FF_ / 8) >> 5;   // 12
  gload16(hrow,          &As[0][tid * 8]);
  gload16(hrow + half_h, &As[0][(256 + tid) * 8]);
  if (tid < 64) gload16(brow, &Bs[0][tid * 8]);
  __syncthreads();

  for (int t = 0; t < nst; ++t) {
    const int cur = t & 1;
    if (t + 1 < nst) {
      const int nxt = cur ^ 1;
      const size_t ko = (size_t)(t + 1) * 32;
      gload16(hrow + ko,          &As[nxt][tid * 8]);
      gload16(hrow + ko + half_h, &As[nxt][(256 + tid) * 8]);
      if (tid < 64) gload16(brow + ko, &Bs[nxt][tid * 8]);
    }
    s16x8 bv = *(const s16x8*)&Bs[cur][lr * 32 + lk];
    #pragma unroll
    for (int i = 0; i < 2; ++i) {
      s16x8 av = *(const s16x8*)&As[cur][(w * 32 + i * 16 + lr) * 32 + lk];
      acc[i] = __builtin_amdgcn_mfma_f32_16x16x32_bf16(av, bv, acc[i], 0, 0, 0);
    }
    __syncthreads();
  }

  const int rb = (lane >> 4) * 4;
  #pragma unroll
  for (int i = 0; i < 2; ++i)
    #pragma unroll
    for (int r = 0; r < 4; ++r)
      part[(size_t)blockIdx.y * M_ * 16 +
           (size_t)(m0 + w * 32 + i * 16 + rb + r) * 16 + lr] = acc[i][r];
}

// ---------------- reduce partials -> tmp2b bf16 [M,32] ----------------
__global__ __launch_bounds__(256)
void reduce_dp(const float* __restrict__ part, const float* __restrict__ d2,
               u16* __restrict__ tmp2b, const int* __restrict__ nbp)
{
  const int idx = blockIdx.x * 256 + threadIdx.x;   // m*16 + r
  const int m = idx >> 4, r = idx & 15;
  const int nb = *nbp;
  float s = 0.f;
  #pragma unroll
  for (int ks = 0; ks < 8; ++ks) s += part[(size_t)ks * M_ * 16 + idx];
  if ((m % S_) >= nb) s *= d2[r];
  tmp2b[(size_t)m * 32 + r] = f2b(s);
  tmp2b[(size_t)m * 32 + 16 + r] = 0;
}

// ---------------- MFMA flash attention: KBLK=64, 48KB LDS (3 blocks/CU) ----------------
__global__ __launch_bounds__(256)
void attn_mfma(const u16* __restrict__ qkv, const float* __restrict__ mask,
               u16* __restrict__ o)
{
  __shared__ u16 Kl[2][KBLK * 64];   // row k, col d, swz col^((k&7)<<3)
  __shared__ u16 Vt[2][64 * KBLK];   // row d, col k, swz k^(((d&7)^((d>>3)&7))<<3)
  __shared__ uint32_t Pl[4][1024];   // per-wave P rows [16][64 u32]; prologue: Q overlay

  const int tid  = threadIdx.x;
  const int lane = tid & 63;
  const int wq   = tid >> 6;
  const int lr   = lane & 15;
  const int hi   = lane >> 4;
  const int lin = blockIdx.x;
  const int vsw = (lin & 7) * 192 + (lin >> 3);
  const int qb  = vsw & 15;
  const int bh  = vsw >> 4;
  const int b    = bh / H_;
  const int h    = bh % H_;
  const size_t tok0 = (size_t)b * S_ + (size_t)qb * 64;
  const size_t colh = (size_t)h * HD_;

  const int va  = tid >> 3;
  const int vc8 = (tid & 7) * 8;
  u16* qstage = (u16*)&Pl[0][0];

  #pragma unroll
  for (int u = 0; u < 2; ++u) {
    const int li = u * 256 + tid;
    const int r  = li >> 3;
    const int cb = ((li & 7) ^ (r & 7)) * 8;
    gload16(qkv + (tok0 + r) * QLD + colh + cb, &qstage[li * 8]);
  }
  {
    const size_t ktok = (size_t)b * S_;
    #pragma unroll
    for (int u = 0; u < 2; ++u) {
      const int li = u * 256 + tid;
      const int r  = li >> 3;
      const int cb = ((li & 7) ^ (r & 7)) * 8;
      gload16(qkv + (ktok + r) * QLD + D_ + colh + cb, &Kl[0][li * 8]);
    }
    const u16* vp = qkv + (ktok + 2 * va) * QLD + 2 * D_ + colh + vc8;
    s16x8 w0 = *(const s16x8*)vp;
    s16x8 w1 = *(const s16x8*)(vp + QLD);
    #pragma unroll
    for (int jj = 0; jj < 8; ++jj) {
      const int d  = vc8 + jj;
      const int sw = ((d & 7) ^ ((d >> 3) & 7)) << 3;
      const int cp = (2 * va) ^ sw;
      *(uint32_t*)&Vt[0][d * KBLK + cp] =
          (uint32_t)(u16)w0[jj] | ((uint32_t)(u16)w1[jj] << 16);
    }
  }
  __syncthreads();

  s16x8 qa[2];
  {
    const int qrow = wq * 16 + lr;
    #pragma unroll
    for (int ks = 0; ks < 2; ++ks)
      qa[ks] = *(const s16x8*)&qstage[qrow * 64 + ((ks * 32 + hi * 8) ^ ((qrow & 7) << 3))];
  }
  __syncthreads();   // all qa reads done before any P overwrite of Pl

  const fx4 zero = {0.f, 0.f, 0.f, 0.f};
  fx4 oacc[4];
  #pragma unroll
  for (int dj = 0; dj < 4; ++dj) oacc[dj] = zero;
  float mreg = -3.0e38f, lreg = 0.f;

  const int NT = S_ / KBLK;   // 16
  for (int kt = 0; kt < NT; ++kt) {
    const int cur = kt & 1;
    const int nxt = cur ^ 1;

    s16x8 w0, w1;
    if (kt + 1 < NT) {
      const size_t ktokn = (size_t)b * S_ + (size_t)(kt + 1) * KBLK;
      #pragma unroll
      for (int u = 0; u < 2; ++u) {
        const int li = u * 256 + tid;
        const int r  = li >> 3;
        const int cb = ((li & 7) ^ (r & 7)) * 8;
        gload16(qkv + (ktokn + r) * QLD + D_ + colh + cb, &Kl[nxt][li * 8]);
      }
      const u16* vp = qkv + (ktokn + 2 * va) * QLD + 2 * D_ + colh + vc8;
      w0 = *(const s16x8*)vp;
      w1 = *(const s16x8*)(vp + QLD);
    }

    float val[4][4];
    {
      s16x8 kb2[4][2];
      #pragma unroll
      for (int j = 0; j < 4; ++j) {
        const int n = j * 16 + lr;
        #pragma unroll
        for (int ks = 0; ks < 2; ++ks)
          kb2[j][ks] = *(const s16x8*)&Kl[cur][n * 64 + ((ks * 32 + hi * 8) ^ ((n & 7) << 3))];
      }
      fx4 m4[4];
      {
        const float* mp = mask + (size_t)(qb * 64 + wq * 16 + lr) * S_
                        + (size_t)kt * KBLK + 4 * hi;
        #pragma unroll
        for (int j = 0; j < 4; ++j)
          m4[j] = *(const fx4*)(mp + j * 16);
      }
      fx4 sf[4];
      #pragma unroll
      for (int j = 0; j < 4; ++j) sf[j] = zero;
      __builtin_amdgcn_s_setprio(1);
      #pragma unroll
      for (int ks = 0; ks < 2; ++ks)
        #pragma unroll
        for (int j = 0; j < 4; ++j)
          sf[j] = __builtin_amdgcn_mfma_f32_16x16x32_bf16(kb2[j][ks], qa[ks], sf[j], 0, 0, 0);
      __builtin_amdgcn_s_setprio(0);
      #pragma unroll
      for (int j = 0; j < 4; ++j)
        #pragma unroll
        for (int r = 0; r < 4; ++r)
          val[j][r] = sf[j][r] * 0.125f + m4[j][r];
    }

    {
      float mk[4];
      #pragma unroll
      for (int kg = 0; kg < 4; ++kg)
        mk[kg] = fmaxf(fmaxf(val[kg][0], val[kg][1]), fmaxf(val[kg][2], val[kg][3]));
      float mx = fmaxf(fmaxf(mk[0], mk[1]), fmaxf(mk[2], mk[3]));
      mx = fmaxf(mx, __shfl_xor(mx, 16));
      mx = fmaxf(mx, __shfl_xor(mx, 32));
      const bool noresc = (bool)__all(mx <= mreg + 8.f);
      float fac = 1.f;
      if (!noresc) {
        const float mn = fmaxf(mreg, mx);
        fac = __expf(mreg - mn);
        mreg = mn;
      }
      float sk[4];
      #pragma unroll
      for (int kg = 0; kg < 4; ++kg) {
        #pragma unroll
        for (int r = 0; r < 4; ++r) val[kg][r] = __expf(val[kg][r] - mreg);
        sk[kg] = (val[kg][0] + val[kg][1]) + (val[kg][2] + val[kg][3]);
      }
      float rs = (sk[0] + sk[1]) + (sk[2] + sk[3]);
      rs += __shfl_xor(rs, 16);
      rs += __shfl_xor(rs, 32);
      lreg = lreg * fac + rs;
      if (!noresc) {
        float facr[4];
        #pragma unroll
        for (int r = 0; r < 4; ++r) facr[r] = __shfl(fac, hi * 4 + r);
        #pragma unroll
        for (int dj = 0; dj < 4; ++dj)
          #pragma unroll
          for (int r = 0; r < 4; ++r) oacc[dj][r] *= facr[r];
      }
    }

    {
      uint32_t* prow = &Pl[wq][lr * 64];
      #pragma unroll
      for (int kg = 0; kg < 4; ++kg) {
        const uint32_t p0 = __builtin_amdgcn_perm(
            __float_as_uint(val[kg][1]), __float_as_uint(val[kg][0]), 0x07060302u);
        const uint32_t p1 = __builtin_amdgcn_perm(
            __float_as_uint(val[kg][3]), __float_as_uint(val[kg][2]), 0x07060302u);
        const int i0 = (8 * kg + 2 * hi) ^ ((lr & 7) << 3);
        uint2 pk; pk.x = p0; pk.y = p1;
        *(uint2*)&prow[i0] = pk;
      }
    }

    if (kt + 1 < NT) {
      #pragma unroll
      for (int jj = 0; jj < 8; ++jj) {
        const int d  = vc8 + jj;
        const int sw = ((d & 7) ^ ((d >> 3) & 7)) << 3;
        const int cp = (2 * va) ^ sw;
        *(uint32_t*)&Vt[nxt][d * KBLK + cp] =
            (uint32_t)(u16)w0[jj] | ((uint32_t)(u16)w1[jj] << 16);
      }
    }

    #pragma unroll
    for (int ks = 0; ks < 2; ++ks) {
      const int pbase = (16 * ks + 4 * hi) ^ ((lr & 7) << 3);
      s16x8 pa = *(const s16x8*)&Pl[wq][lr * 64 + pbase];
      s16x8 bv2[4];
      #pragma unroll
      for (int dj = 0; dj < 4; ++dj) {
        const int n  = dj * 16 + lr;
        const int sw = ((n & 7) ^ ((n >> 3) & 7)) << 3;
        bv2[dj] = *(const s16x8*)&Vt[cur][n * KBLK + ((ks * 32 + hi * 8) ^ sw)];
      }
      __builtin_amdgcn_s_setprio(1);
      #pragma unroll
      for (int dj = 0; dj < 4; ++dj)
        oacc[dj] = __builtin_amdgcn_mfma_f32_16x16x32_bf16(pa, bv2[dj], oacc[dj], 0, 0, 0);
      __builtin_amdgcn_s_setprio(0);
    }

    __syncthreads();
  }

  {
    const float linv = 1.f / lreg;
    float invr[4];
    #pragma unroll
    for (int r = 0; r < 4; ++r) invr[r] = __shfl(linv, hi * 4 + r);
    #pragma unroll
    for (int r = 0; r < 4; ++r) {
      const size_t grow = (tok0 + wq * 16 + hi * 4 + r) * D_ + colh;
      #pragma unroll
      for (int dj = 0; dj < 4; ++dj)
        o[grow + dj * 16 + lr] = f2b(oacc[dj][r] * invr[r]);
    }
  }
}

extern "C" void kernel_launch(void* const* d_in, const int* in_sizes, int n_in,
                              void* d_out, int out_size, void* d_ws, size_t ws_size,
                              hipStream_t stream)
{
  const float* x      = (const float*)d_in[0];
  const float* mask   = (const float*)d_in[1];
  const float* n1g    = (const float*)d_in[2];
  const float* n1b    = (const float*)d_in[3];
  const float* q_w    = (const float*)d_in[4];
  const float* q_bv   = (const float*)d_in[5];
  const float* k_w    = (const float*)d_in[6];
  const float* k_bv   = (const float*)d_in[7];
  const float* v_w    = (const float*)d_in[8];
  const float* v_bv   = (const float*)d_in[9];
  const float* o_w    = (const float*)d_in[10];
  const float* o_bv   = (const float*)d_in[11];
  const float* n2g    = (const float*)d_in[12];
  const float* n2b    = (const float*)d_in[13];
  const float* fc1_w  = (const float*)d_in[14];
  const float* fc1_bv = (const float*)d_in[15];
  const float* fc2_w  = (const float*)d_in[16];
  const float* fc2_bv = (const float*)d_in[17];
  const float* lora1A = (const float*)d_in[18];
  const float* lora1B = (const float*)d_in[19];
  const float* lora2A = (const float*)d_in[20];
  const float* lora2B = (const float*)d_in[21];
  const float* vera1A = (const float*)d_in[22];
  const float* vera1B = (const float*)d_in[23];
  const float* vera2A = (const float*)d_in[24];
  const float* vera2B = (const float*)d_in[25];
  const float* e1d    = (const float*)d_in[26];
  const float* e1b    = (const float*)d_in[27];
  const float* e2d    = (const float*)d_in[28];
  const float* e2b    = (const float*)d_in[29];
  const int*   nbp    = (const int*)d_in[30];

  char* wsb = (char*)d_ws;
  u16* h1    = (u16*)wsb; wsb += (size_t)M_ * D_ * 2;       // 12.6 MB
  u16* qkv   = (u16*)wsb; wsb += (size_t)M_ * QLD * 2;      // 37.7 MB
  u16* attno = (u16*)wsb; wsb += (size_t)M_ * D_ * 2;
  u16* oproj = (u16*)wsb; wsb += (size_t)M_ * D_ * 2;
  u16* n2    = (u16*)wsb; wsb += (size_t)M_ * D_ * 2;
  u16* wqkv  = (u16*)wsb; wsb += (size_t)QLD * D_ * 2;
  u16* wo    = (u16*)wsb; wsb += (size_t)D_ * D_ * 2;
  u16* wfc1  = (u16*)wsb; wsb += (size_t)FF_ * D_ * 2;
  u16* wfc2  = (u16*)wsb; wsb += (size_t)D_ * FF_ * 2;
  u16* tmp1b = (u16*)wsb; wsb += (size_t)M_ * 32 * 2;
  u16* tmp2b = (u16*)wsb; wsb += (size_t)M_ * 32 * 2;
  u16* up1L  = (u16*)wsb; wsb += (size_t)FF_ * 32 * 2;
  u16* up1V  = (u16*)wsb; wsb += (size_t)FF_ * 32 * 2;
  u16* up2L  = (u16*)wsb; wsb += (size_t)D_ * 32 * 2;
  u16* up2V  = (u16*)wsb; wsb += (size_t)D_ * 32 * 2;
  u16* a2tL  = (u16*)wsb; wsb += (size_t)16 * FF_ * 2;
  u16* a2tV  = (u16*)wsb; wsb += (size_t)16 * FF_ * 2;
  float* qkvb = (float*)wsb; wsb += (size_t)QLD * 4;
  float* part = (float*)wsb; wsb += (size_t)8 * M_ * 16 * 4; // 4 MB
  u16* hidb = h1;   // [M,FF] bf16 aliases h1+qkv (both dead by fc1)

  const int totq = (4 * D_ * D_ + 2 * FF_ * D_) / 4;
  cvt_prep<<<totq / 256, 256, 0, stream>>>(q_w, k_w, v_w, o_w, fc1_w, fc2_w,
                                           wqkv, wo, wfc1, wfc2,
                                           q_bv, k_bv, v_bv, qkvb,
                                           lora1B, vera1B, e1b, up1L, up1V,
                                           lora2B, vera2B, e2b, up2L, up2V,
                                           lora2A, vera2A, a2tL, a2tV);

  ln_k<false><<<M_, 256, 0, stream>>>(x, nullptr, n1g, n1b, h1, nullptr,
                                      nullptr, nullptr, nullptr, nullptr, nullptr);
  gemm_bt<0><<<(M_/128) * (QLD/128), 256, 0, stream>>>(
      h1, wqkv, qkvb, qkv, nullptr, nullptr, nullptr, nullptr, nullptr, nullptr,
      M_, QLD, D_);
  attn_mfma<<<(S_/64) * (B_*H_), 256, 0, stream>>>(qkv, mask, attno);
  gemm_bt<0><<<(M_/128) * (D_/128), 256, 0, stream>>>(
      attno, wo, o_bv, oproj, nullptr, nullptr, nullptr, nullptr, nullptr, nullptr,
      M_, D_, D_);

  ln_k<true><<<M_, 256, 0, stream>>>(x, oproj, n2g, n2b, n2, (float*)d_out,
                                     lora1A, vera1A, e1d, tmp1b, nbp);

  gemm_bt<1><<<(M_/128) * (FF_/128), 256, 0, stream>>>(
      n2, wfc1, fc1_bv, hidb, nullptr, nullptr, tmp1b, up1L, up1V, nbp,
      M_, FF_, D_);

  downproj<<<dim3(M_/128, 8), 256, 0, stream>>>(hidb, a2tL, a2tV, part, nbp);
  reduce_dp<<<M_*16/256, 256, 0, stream>>>(part, e2d, tmp2b, nbp);

  gemm_bt<2><<<(M_/128) * (D_/128), 256, 0, stream>>>(
      hidb, wfc2, fc2_bv, nullptr, (float*)d_out, (const float*)d_out,
      tmp2b, up2L, up2V, nbp, M_, D_, FF_);
}

// Round 15
// 343.403 us; speedup vs baseline: 1.2387x; 1.0051x over previous
//
#include <hip/hip_runtime.h>
#include <stdint.h>

#define B_  8
#define S_  1024
#define D_  768
#define H_  12
#define HD_ 64
#define FF_ 3072
#define M_  (B_*S_)   // 8192 tokens
#define R_  16
#define QLD 2304      // packed QKV row stride
#define KBLK 64

typedef unsigned short u16;
typedef short s16x8 __attribute__((ext_vector_type(8)));   // 8 bf16 (4 VGPRs)
typedef float fx4  __attribute__((ext_vector_type(4)));    // 4 fp32 acc

__device__ __forceinline__ float b2f(u16 u) {
  union { unsigned int i; float f; } c; c.i = ((unsigned int)u) << 16; return c.f;
}
__device__ __forceinline__ u16 f2b(float f) {   // RNE f32->bf16
  union { float f; unsigned int i; } c; c.f = f;
  unsigned int x = c.i;
  x += 0x7FFFu + ((x >> 16) & 1u);
  return (u16)(x >> 16);
}
__device__ __forceinline__ float gelu_f(float x) {  // jax.nn.gelu approximate=True (tanh)
  float u = 0.7978845608028654f * (x + 0.044715f * x * x * x);
  float e = __expf(2.f * u);
  float t = 1.f - 2.f / (e + 1.f);
  return 0.5f * x * (1.f + t);
}
__device__ __forceinline__ void gload16(const u16* gsrc, u16* ldst) {
  __builtin_amdgcn_global_load_lds(
      (__attribute__((address_space(1))) void*)(gsrc),
      (__attribute__((address_space(3))) void*)(ldst), 16, 0, 0);
}

// ---------------- weights f32->bf16 + all small preps, ONE kernel ----------------
__global__ __launch_bounds__(256)
void cvt_prep(const float* __restrict__ q_w, const float* __restrict__ k_w,
              const float* __restrict__ v_w, const float* __restrict__ o_w,
              const float* __restrict__ fc1_w, const float* __restrict__ fc2_w,
              u16* __restrict__ wqkv, u16* __restrict__ wo,
              u16* __restrict__ wfc1, u16* __restrict__ wfc2,
              const float* __restrict__ q_bv, const float* __restrict__ k_bv,
              const float* __restrict__ v_bv, float* __restrict__ qkvb,
              const float* __restrict__ lora1B, const float* __restrict__ vera1B,
              const float* __restrict__ e1b, u16* __restrict__ up1L, u16* __restrict__ up1V,
              const float* __restrict__ lora2B, const float* __restrict__ vera2B,
              const float* __restrict__ e2b, u16* __restrict__ up2L, u16* __restrict__ up2V,
              const float* __restrict__ lora2A, const float* __restrict__ vera2A,
              u16* __restrict__ a2tL, u16* __restrict__ a2tV)
{
  const int i = blockIdx.x * 256 + threadIdx.x;   // quad index
  const int q1  = D_ * D_ / 4;
  const int fd4 = FF_ * D_ / 4;
  {
    const float* s; u16* d; int j;
    if      (i <     q1)       { s = q_w;   d = wqkv;            j = i; }
    else if (i < 2 * q1)       { s = k_w;   d = wqkv + D_*D_;    j = i - q1; }
    else if (i < 3 * q1)       { s = v_w;   d = wqkv + 2*D_*D_;  j = i - 2*q1; }
    else if (i < 4 * q1)       { s = o_w;   d = wo;              j = i - 3*q1; }
    else if (i < 4 * q1 + fd4) { s = fc1_w; d = wfc1;            j = i - 4*q1; }
    else                       { s = fc2_w; d = wfc2;            j = i - 4*q1 - fd4; }
    const float4 f = ((const float4*)s)[j];
    ushort4 o4; o4.x = f2b(f.x); o4.y = f2b(f.y); o4.z = f2b(f.z); o4.w = f2b(f.w);
    ((ushort4*)d)[j] = o4;
  }
  if (i < FF_) {
    const int f = i;
    if (f < QLD)
      qkvb[f] = (f < D_) ? q_bv[f] : (f < 2 * D_) ? k_bv[f - D_] : v_bv[f - 2 * D_];
    {
      const float ev = e1b[f];
      #pragma unroll
      for (int r = 0; r < 16; ++r) {
        up1L[(size_t)f * 32 + r] = f2b(lora1B[(size_t)r * FF_ + f]);
        up1V[(size_t)f * 32 + r] = f2b(vera1B[(size_t)r * FF_ + f] * ev);
        up1L[(size_t)f * 32 + 16 + r] = 0;
        up1V[(size_t)f * 32 + 16 + r] = 0;
      }
    }
    {
      const float4* apl = (const float4*)(lora2A + (size_t)f * 16);
      const float4* apv = (const float4*)(vera2A + (size_t)f * 16);
      #pragma unroll
      for (int q4 = 0; q4 < 4; ++q4) {
        const float4 l4 = apl[q4], v4 = apv[q4];
        a2tL[(size_t)(q4*4+0) * FF_ + f] = f2b(l4.x);
        a2tL[(size_t)(q4*4+1) * FF_ + f] = f2b(l4.y);
        a2tL[(size_t)(q4*4+2) * FF_ + f] = f2b(l4.z);
        a2tL[(size_t)(q4*4+3) * FF_ + f] = f2b(l4.w);
        a2tV[(size_t)(q4*4+0) * FF_ + f] = f2b(v4.x);
        a2tV[(size_t)(q4*4+1) * FF_ + f] = f2b(v4.y);
        a2tV[(size_t)(q4*4+2) * FF_ + f] = f2b(v4.z);
        a2tV[(size_t)(q4*4+3) * FF_ + f] = f2b(v4.w);
      }
    }
    if (f < D_) {
      const float ev = e2b[f];
      #pragma unroll
      for (int r = 0; r < 16; ++r) {
        up2L[(size_t)f * 32 + r] = f2b(lora2B[(size_t)r * D_ + f]);
        up2V[(size_t)f * 32 + r] = f2b(vera2B[(size_t)r * D_ + f] * ev);
        up2L[(size_t)f * 32 + 16 + r] = 0;
        up2V[(size_t)f * 32 + 16 + r] = 0;
      }
    }
  }
}

// ---------------- LayerNorm (+residual add, + fused rank-16 down-projection) ----------------
template<bool ADD>
__global__ __launch_bounds__(256)
void ln_k(const float* __restrict__ x, const u16* __restrict__ add,
          const float* __restrict__ g, const float* __restrict__ beta,
          u16* __restrict__ outb, float* __restrict__ xsum,
          const float* __restrict__ Alora, const float* __restrict__ Avera,
          const float* __restrict__ dvec, u16* __restrict__ tmp1b,
          const int* __restrict__ nbp)
{
  const int row = blockIdx.x;
  const size_t base = (size_t)row * D_;
  float v0[3]; float s = 0.f, sq = 0.f;
  #pragma unroll
  for (int i = 0; i < 3; ++i) {
    const int d = threadIdx.x + i * 256;
    float val = x[base + d];
    if (ADD) { val += b2f(add[base + d]); xsum[base + d] = val; }
    v0[i] = val; s += val; sq += val * val;
  }
  #pragma unroll
  for (int mm = 32; mm >= 1; mm >>= 1) { s += __shfl_xor(s, mm); sq += __shfl_xor(sq, mm); }
  __shared__ float ss[4], s2[4];
  if ((threadIdx.x & 63) == 0) { ss[threadIdx.x >> 6] = s; s2[threadIdx.x >> 6] = sq; }
  __syncthreads();
  s  = ss[0] + ss[1] + ss[2] + ss[3];
  sq = s2[0] + s2[1] + s2[2] + s2[3];
  const float mean = s * (1.f / D_);
  const float var  = sq * (1.f / D_) - mean * mean;
  const float rs   = rsqrtf(var + 1e-6f);
  float nv[3];
  #pragma unroll
  for (int i = 0; i < 3; ++i) {
    const int d = threadIdx.x + i * 256;
    nv[i] = (v0[i] - mean) * rs * g[d] + beta[d];
    outb[base + d] = f2b(nv[i]);
  }

  if (ADD) {
    const int nb = *nbp;
    const bool ex = (row % S_) >= nb;
    const float* Am = ex ? Avera : Alora;
    float p[16];
    #pragma unroll
    for (int r = 0; r < 16; ++r) p[r] = 0.f;
    #pragma unroll
    for (int i = 0; i < 3; ++i) {
      const int d = threadIdx.x + i * 256;
      const float4* ap = (const float4*)(Am + (size_t)d * R_);
      const float4 a0 = ap[0], a1 = ap[1], a2 = ap[2], a3 = ap[3];
      const float vv = nv[i];
      p[0]  += vv * a0.x; p[1]  += vv * a0.y; p[2]  += vv * a0.z; p[3]  += vv * a0.w;
      p[4]  += vv * a1.x; p[5]  += vv * a1.y; p[6]  += vv * a1.z; p[7]  += vv * a1.w;
      p[8]  += vv * a2.x; p[9]  += vv * a2.y; p[10] += vv * a2.z; p[11] += vv * a2.w;
      p[12] += vv * a3.x; p[13] += vv * a3.y; p[14] += vv * a3.z; p[15] += vv * a3.w;
    }
    #pragma unroll
    for (int st = 1; st < 16; st <<= 1)
      #pragma unroll
      for (int r = 0; r < 16; ++r) p[r] += __shfl_xor(p[r], st);
    __shared__ float sred[16][16];
    const int grp = threadIdx.x >> 4;
    if ((threadIdx.x & 15) == 0) {
      #pragma unroll
      for (int r = 0; r < 16; ++r) sred[grp][r] = p[r];
    }
    __syncthreads();
    if (threadIdx.x < 16) {
      float v = 0.f;
      #pragma unroll
      for (int gg = 0; gg < 16; ++gg) v += sred[gg][threadIdx.x];
      if (ex) v *= dvec[threadIdx.x];
      tmp1b[(size_t)row * 32 + threadIdx.x] = f2b(v);
      tmp1b[(size_t)row * 32 + 16 + threadIdx.x] = 0;
    }
  }
}

// ---------------- bf16 MFMA GEMM: BK=64, counted-vmcnt 2-deep pipeline (T3+T4) ----------------
template<int MODE>
__global__ __launch_bounds__(256)
void gemm_bt(const u16* __restrict__ A, const u16* __restrict__ W,
             const float* __restrict__ bias, u16* __restrict__ Cb,
             float* __restrict__ Cf, const float* __restrict__ resid,
             const u16* __restrict__ Aad, const u16* __restrict__ BadL,
             const u16* __restrict__ BadV, const int* __restrict__ nbp,
             int M, int N, int K)
{
  __shared__ u16 As[2][128 * 64];
  __shared__ u16 Bs[2][128 * 64];
  const int tid   = threadIdx.x;
  const int lane  = tid & 63;
  const int wid   = tid >> 6;
  const int wr    = wid >> 1;
  const int wc    = wid & 1;
  const int lr    = lane & 15;
  const int hi    = lane >> 4;
  const int gn    = N >> 7;
  const int nwg   = (M >> 7) * gn;
  const int chunk = nwg >> 3;
  const int lin   = blockIdx.x;
  const int swz   = (lin & 7) * chunk + (lin >> 3);
  const int m0    = (swz / gn) * 128;
  const int n0    = (swz % gn) * 128;

  const int nst = K >> 6;   // main K-tiles of 64
  const int tot = (MODE >= 1) ? nst + 1 : nst;
  const u16* Bad = nullptr;
  if (MODE >= 1) Bad = ((m0 % S_) >= *nbp) ? BadV : BadL;

  const int sr[4]  = { tid >> 3, (256 + tid) >> 3, (512 + tid) >> 3, (768 + tid) >> 3 };
  int scb[4];
  #pragma unroll
  for (int u = 0; u < 4; ++u) scb[u] = (((u * 256 + tid) & 7) ^ (sr[u] & 7)) * 8;

  fx4 acc[4][4];
  const fx4 zero = {0.f, 0.f, 0.f, 0.f};
  #pragma unroll
  for (int i = 0; i < 4; ++i)
    #pragma unroll
    for (int j = 0; j < 4; ++j) acc[i][j] = zero;

  #pragma unroll
  for (int u = 0; u < 4; ++u) {
    gload16(A + (size_t)(m0 + sr[u]) * K + scb[u], &As[0][(u * 256 + tid) * 8]);
    gload16(W + (size_t)(n0 + sr[u]) * K + scb[u], &Bs[0][(u * 256 + tid) * 8]);
  }
  #pragma unroll
  for (int u = 0; u < 4; ++u) {
    gload16(A + (size_t)(m0 + sr[u]) * K + 64 + scb[u], &As[1][(u * 256 + tid) * 8]);
    gload16(W + (size_t)(n0 + sr[u]) * K + 64 + scb[u], &Bs[1][(u * 256 + tid) * 8]);
  }

  for (int t = 0; t < tot; ++t) {
    const int c = t & 1;
    if (t + 1 >= tot) {
      asm volatile("s_waitcnt vmcnt(0)" ::: "memory");
    } else if (MODE >= 1 && t + 1 == nst) {
      asm volatile("s_waitcnt vmcnt(4)" ::: "memory");
    } else {
      asm volatile("s_waitcnt vmcnt(8)" ::: "memory");
    }
    __builtin_amdgcn_s_barrier();
    __builtin_amdgcn_sched_barrier(0);

    if (MODE >= 1 && t == nst) {
      s16x8 aav[4], abv[4];
      #pragma unroll
      for (int i = 0; i < 4; ++i)
        aav[i] = *(const s16x8*)&As[c][(wr * 64 + i * 16 + lr) * 32 + hi * 8];
      #pragma unroll
      for (int j = 0; j < 4; ++j)
        abv[j] = *(const s16x8*)&Bs[c][(wc * 64 + j * 16 + lr) * 32 + hi * 8];
      #pragma unroll
      for (int i = 0; i < 4; ++i)
        #pragma unroll
        for (int j = 0; j < 4; ++j)
          acc[i][j] = __builtin_amdgcn_mfma_f32_16x16x32_bf16(aav[i], abv[j], acc[i][j], 0, 0, 0);
    } else {
      s16x8 av[4][2], bv[4][2];
      #pragma unroll
      for (int i = 0; i < 4; ++i) {
        const int row = wr * 64 + i * 16 + lr;
        const int rb7 = row & 7;
        #pragma unroll
        for (int ks = 0; ks < 2; ++ks)
          av[i][ks] = *(const s16x8*)&As[c][row * 64 + (((ks * 4 + hi) ^ rb7) * 8)];
      }
      #pragma unroll
      for (int j = 0; j < 4; ++j) {
        const int row = wc * 64 + j * 16 + lr;
        const int rb7 = row & 7;
        #pragma unroll
        for (int ks = 0; ks < 2; ++ks)
          bv[j][ks] = *(const s16x8*)&Bs[c][row * 64 + (((ks * 4 + hi) ^ rb7) * 8)];
      }
      __builtin_amdgcn_s_setprio(1);
      #pragma unroll
      for (int ks = 0; ks < 2; ++ks)
        #pragma unroll
        for (int i = 0; i < 4; ++i)
          #pragma unroll
          for (int j = 0; j < 4; ++j)
            acc[i][j] = __builtin_amdgcn_mfma_f32_16x16x32_bf16(av[i][ks], bv[j][ks], acc[i][j], 0, 0, 0);
      __builtin_amdgcn_s_setprio(0);
    }

    if (t + 2 <= tot - 1) {
      __builtin_amdgcn_sched_barrier(0);
      __builtin_amdgcn_s_barrier();
      __builtin_amdgcn_sched_barrier(0);
      if (MODE >= 1 && t + 2 == nst) {
        #pragma unroll
        for (int u = 0; u < 2; ++u) {
          const int li = u * 256 + tid;
          const int r  = li >> 2;
          const int cg = (li & 3) * 8;
          gload16(Aad + (size_t)(m0 + r) * 32 + cg, &As[c][li * 8]);
          gload16(Bad + (size_t)(n0 + r) * 32 + cg, &Bs[c][li * 8]);
        }
      } else {
        const int ko = (t + 2) << 6;
        #pragma unroll
        for (int u = 0; u < 4; ++u) {
          gload16(A + (size_t)(m0 + sr[u]) * K + ko + scb[u], &As[c][(u * 256 + tid) * 8]);
          gload16(W + (size_t)(n0 + sr[u]) * K + ko + scb[u], &Bs[c][(u * 256 + tid) * 8]);
        }
      }
    }
  }

  const int rb = hi * 4;
  #pragma unroll
  for (int j = 0; j < 4; ++j) {
    const int col = n0 + wc * 64 + j * 16 + lr;
    const float bj = bias ? bias[col] : 0.f;
    #pragma unroll
    for (int i = 0; i < 4; ++i) {
      const int row = m0 + wr * 64 + i * 16 + rb;
      #pragma unroll
      for (int r = 0; r < 4; ++r) {
        const float val = acc[i][j][r] + bj;
        const size_t idx = (size_t)(row + r) * N + col;
        if (MODE == 1)      Cb[idx] = f2b(gelu_f(val));
        else if (MODE == 2) Cf[idx] = resid[idx] + val;
        else                Cb[idx] = f2b(val);
      }
    }
  }
}

// ---------------- skinny down-projection (2-phase dbuf): part[ks][M][16] ----------------
__global__ __launch_bounds__(256)
void downproj(const u16* __restrict__ hid, const u16* __restrict__ A2tL,
              const u16* __restrict__ A2tV, float* __restrict__ part,
              const int* __restrict__ nbp)
{
  __shared__ u16 As[2][128 * 32];
  __shared__ u16 Bs[2][16 * 32];
  const int tid  = threadIdx.x;
  const int lane = tid & 63;
  const int w    = tid >> 6;
  const int lr   = lane & 15;
  const int lk   = (lane >> 4) << 3;
  const int m0   = blockIdx.x * 128;
  const int kb   = blockIdx.y * (FF_ / 8);
  const int nb   = *nbp;
  const u16* A2t = ((m0 % S_) >= nb) ? A2tV : A2tL;
  const int kg    = (tid & 3) * 8;
  const int row_a = tid >> 2;

  const u16* hrow = hid + (size_t)(m0 + row_a) * FF_ + kb + kg;
  const size_t half_h = (size_t)64 * FF_;
  const u16* brow = A2t + (size_t)(tid >> 2) * FF_ + kb + kg;

  const fx4 zero = {0.f, 0.f, 0.f, 0.f};
  fx4 acc[2]; acc[0] = zero; acc[1] = zero;

  const int nst = (FF_ / 8) >> 5;   // 12
  gload16(hrow,          &As[0][tid * 8]);
  gload16(hrow + half_h, &As[0][(256 + tid) * 8]);
  if (tid < 64) gload16(brow, &Bs[0][tid * 8]);
  __syncthreads();

  for (int t = 0; t < nst; ++t) {
    const int cur = t & 1;
    if (t + 1 < nst) {
      const int nxt = cur ^ 1;
      const size_t ko = (size_t)(t + 1) * 32;
      gload16(hrow + ko,          &As[nxt][tid * 8]);
      gload16(hrow + ko + half_h, &As[nxt][(256 + tid) * 8]);
      if (tid < 64) gload16(brow + ko, &Bs[nxt][tid * 8]);
    }
    s16x8 bv = *(const s16x8*)&Bs[cur][lr * 32 + lk];
    #pragma unroll
    for (int i = 0; i < 2; ++i) {
      s16x8 av = *(const s16x8*)&As[cur][(w * 32 + i * 16 + lr) * 32 + lk];
      acc[i] = __builtin_amdgcn_mfma_f32_16x16x32_bf16(av, bv, acc[i], 0, 0, 0);
    }
    __syncthreads();
  }

  const int rb = (lane >> 4) * 4;
  #pragma unroll
  for (int i = 0; i < 2; ++i)
    #pragma unroll
    for (int r = 0; r < 4; ++r)
      part[(size_t)blockIdx.y * M_ * 16 +
           (size_t)(m0 + w * 32 + i * 16 + rb + r) * 16 + lr] = acc[i][r];
}

// ---------------- reduce partials -> tmp2b bf16 [M,32] ----------------
__global__ __launch_bounds__(256)
void reduce_dp(const float* __restrict__ part, const float* __restrict__ d2,
               u16* __restrict__ tmp2b, const int* __restrict__ nbp)
{
  const int idx = blockIdx.x * 256 + threadIdx.x;   // m*16 + r
  const int m = idx >> 4, r = idx & 15;
  const int nb = *nbp;
  float s = 0.f;
  #pragma unroll
  for (int ks = 0; ks < 8; ++ks) s += part[(size_t)ks * M_ * 16 + idx];
  if ((m % S_) >= nb) s *= d2[r];
  tmp2b[(size_t)m * 32 + r] = f2b(s);
  tmp2b[(size_t)m * 32 + 16 + r] = 0;
}

// ---------------- MFMA flash attention: KBLK=64, 40KB LDS (4 blocks/CU) ----------------
// R14 structure with compacted Pl: [4][512] u32 (stride 32, shift-2 XOR swizzle).
// slot s (un-XORed) holds k in {2s,2s+1}; write i0=(8kg+2hi)^((lr&7)<<2) b64-aligned,
// read pbase=(16ks+4hi)^((lr&7)<<2) b128-aligned; bank pattern unchanged.
__global__ __launch_bounds__(256)
void attn_mfma(const u16* __restrict__ qkv, const float* __restrict__ mask,
               u16* __restrict__ o)
{
  __shared__ u16 Kl[2][KBLK * 64];   // row k, col d, swz col^((k&7)<<3)
  __shared__ u16 Vt[2][64 * KBLK];   // row d, col k, swz k^(((d&7)^((d>>3)&7))<<3)
  __shared__ uint32_t Pl[4][512];    // per-wave P rows [16][32 u32]; prologue: Q overlay (8KB)

  const int tid  = threadIdx.x;
  const int lane = tid & 63;
  const int wq   = tid >> 6;
  const int lr   = lane & 15;
  const int hi   = lane >> 4;
  const int lin = blockIdx.x;
  const int vsw = (lin & 7) * 192 + (lin >> 3);
  const int qb  = vsw & 15;
  const int bh  = vsw >> 4;
  const int b    = bh / H_;
  const int h    = bh % H_;
  const size_t tok0 = (size_t)b * S_ + (size_t)qb * 64;
  const size_t colh = (size_t)h * HD_;

  const int va  = tid >> 3;
  const int vc8 = (tid & 7) * 8;
  u16* qstage = (u16*)&Pl[0][0];   // 64x64 u16 = 8KB, exactly Pl

  #pragma unroll
  for (int u = 0; u < 2; ++u) {
    const int li = u * 256 + tid;
    const int r  = li >> 3;
    const int cb = ((li & 7) ^ (r & 7)) * 8;
    gload16(qkv + (tok0 + r) * QLD + colh + cb, &qstage[li * 8]);
  }
  {
    const size_t ktok = (size_t)b * S_;
    #pragma unroll
    for (int u = 0; u < 2; ++u) {
      const int li = u * 256 + tid;
      const int r  = li >> 3;
      const int cb = ((li & 7) ^ (r & 7)) * 8;
      gload16(qkv + (ktok + r) * QLD + D_ + colh + cb, &Kl[0][li * 8]);
    }
    const u16* vp = qkv + (ktok + 2 * va) * QLD + 2 * D_ + colh + vc8;
    s16x8 w0 = *(const s16x8*)vp;
    s16x8 w1 = *(const s16x8*)(vp + QLD);
    #pragma unroll
    for (int jj = 0; jj < 8; ++jj) {
      const int d  = vc8 + jj;
      const int sw = ((d & 7) ^ ((d >> 3) & 7)) << 3;
      const int cp = (2 * va) ^ sw;
      *(uint32_t*)&Vt[0][d * KBLK + cp] =
          (uint32_t)(u16)w0[jj] | ((uint32_t)(u16)w1[jj] << 16);
    }
  }
  __syncthreads();

  s16x8 qa[2];
  {
    const int qrow = wq * 16 + lr;
    #pragma unroll
    for (int ks = 0; ks < 2; ++ks)
      qa[ks] = *(const s16x8*)&qstage[qrow * 64 + ((ks * 32 + hi * 8) ^ ((qrow & 7) << 3))];
  }
  __syncthreads();   // all qa reads done before any P overwrite of Pl

  const fx4 zero = {0.f, 0.f, 0.f, 0.f};
  fx4 oacc[4];
  #pragma unroll
  for (int dj = 0; dj < 4; ++dj) oacc[dj] = zero;
  float mreg = -3.0e38f, lreg = 0.f;

  const int NT = S_ / KBLK;   // 16
  for (int kt = 0; kt < NT; ++kt) {
    const int cur = kt & 1;
    const int nxt = cur ^ 1;

    s16x8 w0, w1;
    if (kt + 1 < NT) {
      const size_t ktokn = (size_t)b * S_ + (size_t)(kt + 1) * KBLK;
      #pragma unroll
      for (int u = 0; u < 2; ++u) {
        const int li = u * 256 + tid;
        const int r  = li >> 3;
        const int cb = ((li & 7) ^ (r & 7)) * 8;
        gload16(qkv + (ktokn + r) * QLD + D_ + colh + cb, &Kl[nxt][li * 8]);
      }
      const u16* vp = qkv + (ktokn + 2 * va) * QLD + 2 * D_ + colh + vc8;
      w0 = *(const s16x8*)vp;
      w1 = *(const s16x8*)(vp + QLD);
    }

    float val[4][4];
    {
      s16x8 kb2[4][2];
      #pragma unroll
      for (int j = 0; j < 4; ++j) {
        const int n = j * 16 + lr;
        #pragma unroll
        for (int ks = 0; ks < 2; ++ks)
          kb2[j][ks] = *(const s16x8*)&Kl[cur][n * 64 + ((ks * 32 + hi * 8) ^ ((n & 7) << 3))];
      }
      fx4 m4[4];
      {
        const float* mp = mask + (size_t)(qb * 64 + wq * 16 + lr) * S_
                        + (size_t)kt * KBLK + 4 * hi;
        #pragma unroll
        for (int j = 0; j < 4; ++j)
          m4[j] = *(const fx4*)(mp + j * 16);
      }
      fx4 sf[4];
      #pragma unroll
      for (int j = 0; j < 4; ++j) sf[j] = zero;
      __builtin_amdgcn_s_setprio(1);
      #pragma unroll
      for (int ks = 0; ks < 2; ++ks)
        #pragma unroll
        for (int j = 0; j < 4; ++j)
          sf[j] = __builtin_amdgcn_mfma_f32_16x16x32_bf16(kb2[j][ks], qa[ks], sf[j], 0, 0, 0);
      __builtin_amdgcn_s_setprio(0);
      #pragma unroll
      for (int j = 0; j < 4; ++j)
        #pragma unroll
        for (int r = 0; r < 4; ++r)
          val[j][r] = sf[j][r] * 0.125f + m4[j][r];
    }

    {
      float mk[4];
      #pragma unroll
      for (int kg = 0; kg < 4; ++kg)
        mk[kg] = fmaxf(fmaxf(val[kg][0], val[kg][1]), fmaxf(val[kg][2], val[kg][3]));
      float mx = fmaxf(fmaxf(mk[0], mk[1]), fmaxf(mk[2], mk[3]));
      mx = fmaxf(mx, __shfl_xor(mx, 16));
      mx = fmaxf(mx, __shfl_xor(mx, 32));
      const bool noresc = (bool)__all(mx <= mreg + 8.f);
      float fac = 1.f;
      if (!noresc) {
        const float mn = fmaxf(mreg, mx);
        fac = __expf(mreg - mn);
        mreg = mn;
      }
      float sk[4];
      #pragma unroll
      for (int kg = 0; kg < 4; ++kg) {
        #pragma unroll
        for (int r = 0; r < 4; ++r) val[kg][r] = __expf(val[kg][r] - mreg);
        sk[kg] = (val[kg][0] + val[kg][1]) + (val[kg][2] + val[kg][3]);
      }
      float rs = (sk[0] + sk[1]) + (sk[2] + sk[3]);
      rs += __shfl_xor(rs, 16);
      rs += __shfl_xor(rs, 32);
      lreg = lreg * fac + rs;
      if (!noresc) {
        float facr[4];
        #pragma unroll
        for (int r = 0; r < 4; ++r) facr[r] = __shfl(fac, hi * 4 + r);
        #pragma unroll
        for (int dj = 0; dj < 4; ++dj)
          #pragma unroll
          for (int r = 0; r < 4; ++r) oacc[dj][r] *= facr[r];
      }
    }

    // ---- P pack (v_perm trunc) -> compact wave-private swizzled LDS, 4x b64 ----
    {
      uint32_t* prow = &Pl[wq][lr * 32];
      #pragma unroll
      for (int kg = 0; kg < 4; ++kg) {
        const uint32_t p0 = __builtin_amdgcn_perm(
            __float_as_uint(val[kg][1]), __float_as_uint(val[kg][0]), 0x07060302u);
        const uint32_t p1 = __builtin_amdgcn_perm(
            __float_as_uint(val[kg][3]), __float_as_uint(val[kg][2]), 0x07060302u);
        const int i0 = (8 * kg + 2 * hi) ^ ((lr & 7) << 2);
        uint2 pk; pk.x = p0; pk.y = p1;
        *(uint2*)&prow[i0] = pk;
      }
    }

    if (kt + 1 < NT) {
      #pragma unroll
      for (int jj = 0; jj < 8; ++jj) {
        const int d  = vc8 + jj;
        const int sw = ((d & 7) ^ ((d >> 3) & 7)) << 3;
        const int cp = (2 * va) ^ sw;
        *(uint32_t*)&Vt[nxt][d * KBLK + cp] =
            (uint32_t)(u16)w0[jj] | ((uint32_t)(u16)w1[jj] << 16);
      }
    }

    #pragma unroll
    for (int ks = 0; ks < 2; ++ks) {
      const int pbase = (16 * ks + 4 * hi) ^ ((lr & 7) << 2);
      s16x8 pa = *(const s16x8*)&Pl[wq][lr * 32 + pbase];
      s16x8 bv2[4];
      #pragma unroll
      for (int dj = 0; dj < 4; ++dj) {
        const int n  = dj * 16 + lr;
        const int sw = ((n & 7) ^ ((n >> 3) & 7)) << 3;
        bv2[dj] = *(const s16x8*)&Vt[cur][n * KBLK + ((ks * 32 + hi * 8) ^ sw)];
      }
      __builtin_amdgcn_s_setprio(1);
      #pragma unroll
      for (int dj = 0; dj < 4; ++dj)
        oacc[dj] = __builtin_amdgcn_mfma_f32_16x16x32_bf16(pa, bv2[dj], oacc[dj], 0, 0, 0);
      __builtin_amdgcn_s_setprio(0);
    }

    __syncthreads();
  }

  {
    const float linv = 1.f / lreg;
    float invr[4];
    #pragma unroll
    for (int r = 0; r < 4; ++r) invr[r] = __shfl(linv, hi * 4 + r);
    #pragma unroll
    for (int r = 0; r < 4; ++r) {
      const size_t grow = (tok0 + wq * 16 + hi * 4 + r) * D_ + colh;
      #pragma unroll
      for (int dj = 0; dj < 4; ++dj)
        o[grow + dj * 16 + lr] = f2b(oacc[dj][r] * invr[r]);
    }
  }
}

extern "C" void kernel_launch(void* const* d_in, const int* in_sizes, int n_in,
                              void* d_out, int out_size, void* d_ws, size_t ws_size,
                              hipStream_t stream)
{
  const float* x      = (const float*)d_in[0];
  const float* mask   = (const float*)d_in[1];
  const float* n1g    = (const float*)d_in[2];
  const float* n1b    = (const float*)d_in[3];
  const float* q_w    = (const float*)d_in[4];
  const float* q_bv   = (const float*)d_in[5];
  const float* k_w    = (const float*)d_in[6];
  const float* k_bv   = (const float*)d_in[7];
  const float* v_w    = (const float*)d_in[8];
  const float* v_bv   = (const float*)d_in[9];
  const float* o_w    = (const float*)d_in[10];
  const float* o_bv   = (const float*)d_in[11];
  const float* n2g    = (const float*)d_in[12];
  const float* n2b    = (const float*)d_in[13];
  const float* fc1_w  = (const float*)d_in[14];
  const float* fc1_bv = (const float*)d_in[15];
  const float* fc2_w  = (const float*)d_in[16];
  const float* fc2_bv = (const float*)d_in[17];
  const float* lora1A = (const float*)d_in[18];
  const float* lora1B = (const float*)d_in[19];
  const float* lora2A = (const float*)d_in[20];
  const float* lora2B = (const float*)d_in[21];
  const float* vera1A = (const float*)d_in[22];
  const float* vera1B = (const float*)d_in[23];
  const float* vera2A = (const float*)d_in[24];
  const float* vera2B = (const float*)d_in[25];
  const float* e1d    = (const float*)d_in[26];
  const float* e1b    = (const float*)d_in[27];
  const float* e2d    = (const float*)d_in[28];
  const float* e2b    = (const float*)d_in[29];
  const int*   nbp    = (const int*)d_in[30];

  char* wsb = (char*)d_ws;
  u16* h1    = (u16*)wsb; wsb += (size_t)M_ * D_ * 2;       // 12.6 MB
  u16* qkv   = (u16*)wsb; wsb += (size_t)M_ * QLD * 2;      // 37.7 MB
  u16* attno = (u16*)wsb; wsb += (size_t)M_ * D_ * 2;
  u16* oproj = (u16*)wsb; wsb += (size_t)M_ * D_ * 2;
  u16* n2    = (u16*)wsb; wsb += (size_t)M_ * D_ * 2;
  u16* wqkv  = (u16*)wsb; wsb += (size_t)QLD * D_ * 2;
  u16* wo    = (u16*)wsb; wsb += (size_t)D_ * D_ * 2;
  u16* wfc1  = (u16*)wsb; wsb += (size_t)FF_ * D_ * 2;
  u16* wfc2  = (u16*)wsb; wsb += (size_t)D_ * FF_ * 2;
  u16* tmp1b = (u16*)wsb; wsb += (size_t)M_ * 32 * 2;
  u16* tmp2b = (u16*)wsb; wsb += (size_t)M_ * 32 * 2;
  u16* up1L  = (u16*)wsb; wsb += (size_t)FF_ * 32 * 2;
  u16* up1V  = (u16*)wsb; wsb += (size_t)FF_ * 32 * 2;
  u16* up2L  = (u16*)wsb; wsb += (size_t)D_ * 32 * 2;
  u16* up2V  = (u16*)wsb; wsb += (size_t)D_ * 32 * 2;
  u16* a2tL  = (u16*)wsb; wsb += (size_t)16 * FF_ * 2;
  u16* a2tV  = (u16*)wsb; wsb += (size_t)16 * FF_ * 2;
  float* qkvb = (float*)wsb; wsb += (size_t)QLD * 4;
  float* part = (float*)wsb; wsb += (size_t)8 * M_ * 16 * 4; // 4 MB
  u16* hidb = h1;   // [M,FF] bf16 aliases h1+qkv (both dead by fc1)

  const int totq = (4 * D_ * D_ + 2 * FF_ * D_) / 4;
  cvt_prep<<<totq / 256, 256, 0, stream>>>(q_w, k_w, v_w, o_w, fc1_w, fc2_w,
                                           wqkv, wo, wfc1, wfc2,
                                           q_bv, k_bv, v_bv, qkvb,
                                           lora1B, vera1B, e1b, up1L, up1V,
                                           lora2B, vera2B, e2b, up2L, up2V,
                                           lora2A, vera2A, a2tL, a2tV);

  ln_k<false><<<M_, 256, 0, stream>>>(x, nullptr, n1g, n1b, h1, nullptr,
                                      nullptr, nullptr, nullptr, nullptr, nullptr);
  gemm_bt<0><<<(M_/128) * (QLD/128), 256, 0, stream>>>(
      h1, wqkv, qkvb, qkv, nullptr, nullptr, nullptr, nullptr, nullptr, nullptr,
      M_, QLD, D_);
  attn_mfma<<<(S_/64) * (B_*H_), 256, 0, stream>>>(qkv, mask, attno);
  gemm_bt<0><<<(M_/128) * (D_/128), 256, 0, stream>>>(
      attno, wo, o_bv, oproj, nullptr, nullptr, nullptr, nullptr, nullptr, nullptr,
      M_, D_, D_);

  ln_k<true><<<M_, 256, 0, stream>>>(x, oproj, n2g, n2b, n2, (float*)d_out,
                                     lora1A, vera1A, e1d, tmp1b, nbp);

  gemm_bt<1><<<(M_/128) * (FF_/128), 256, 0, stream>>>(
      n2, wfc1, fc1_bv, hidb, nullptr, nullptr, tmp1b, up1L, up1V, nbp,
      M_, FF_, D_);

  downproj<<<dim3(M_/128, 8), 256, 0, stream>>>(hidb, a2tL, a2tV, part, nbp);
  reduce_dp<<<M_*16/256, 256, 0, stream>>>(part, e2d, tmp2b, nbp);

  gemm_bt<2><<<(M_/128) * (D_/128), 256, 0, stream>>>(
      hidb, wfc2, fc2_bv, nullptr, (float*)d_out, (const float*)d_out,
      tmp2b, up2L, up2V, nbp, M_, D_, FF_);
}